// Round 3
// baseline (15362.624 us; speedup 1.0000x reference)
//
#include <hip/hip_runtime.h>

typedef unsigned short ushort;
typedef unsigned int uint;

#define NTOT   65536
#define CH     64
#define NLAYER 4
#define NEDGE  1048576
#define EPSV   1e-5f

// staged-weight arena element offsets (order = d_in[3..32])
#define OW_EMB 0
#define OB_EMB 3072
#define OW_PE  3120
#define OB_PE  3376
#define OG_PEN 3392
#define OB_PEN 3408
#define OW_G1  3424
#define OB_G1  19808
#define OW_G2  20064
#define OB_G2  36448
#define OW_Q   36704
#define OB_Q   53088
#define OW_K   53344
#define OB_K   69728
#define OW_V   69984
#define OB_V   86368
#define OW_O   86624
#define OB_O   103008
#define ON1G   103264
#define ON1B   103520
#define ON2G   103776
#define ON2B   104032
#define ON3G   104288
#define ON3B   104544
#define OW_M1  104800
#define OB_M1  137568
#define OW_M2  138080
#define OB_M2  170848
#define OW_H   171104
#define OB_H   179296
#define TOTW   179424

__device__ __forceinline__ float bf2f(ushort u){ return __uint_as_float(((uint)u) << 16); }
__device__ __forceinline__ ushort f2bf(float f){
    uint u = __float_as_uint(f);
    uint r = (u + 0x7fffu + ((u >> 16) & 1u)) >> 16;
    return (ushort)r;
}
__device__ __forceinline__ float2 bfp2(uint w){
    return make_float2(__uint_as_float(w << 16), __uint_as_float(w & 0xffff0000u));
}

// ---------------- dtype probe: 1=bf16 inputs, 0=fp32 inputs ----------------
__global__ void detect_k(const uint* __restrict__ x, int* __restrict__ flag){
    int lane = threadIdx.x;                 // 64 lanes
    uint w = x[lane];
    uint e = (w >> 7) & 0xffu;              // exponent field of LOW bf16 half
    int ok = (e >= 100u && e <= 140u) ? 1 : 0;
    unsigned long long m = __ballot(ok);
    if (lane == 0) flag[0] = (__popcll(m) >= 48) ? 1 : 0;
}

// ---------------- convert/copy all weight tensors into bf16 arena ----------------
struct WPtrs { const void* p[30]; };

__global__ void convall_k(WPtrs ptrs, ushort* __restrict__ dst, const int* __restrict__ flag){
    const int offs[31] = {0,3072,3120,3376,3392,3408,3424,19808,20064,36448,36704,
                          53088,53344,69728,69984,86368,86624,103008,103264,103520,
                          103776,104032,104288,104544,104800,137568,138080,170848,
                          171104,179296,179424};
    int i = blockIdx.x * blockDim.x + threadIdx.x;
    if (i >= TOTW) return;
    int s = 0;
    while (s < 29 && i >= offs[s + 1]) ++s;
    int j = i - offs[s];
    if (*flag) dst[i] = ((const ushort*)ptrs.p[s])[j];
    else       dst[i] = f2bf(((const float*)ptrs.p[s])[j]);
}

// ---------------- BN stats over pe (dual dtype) ----------------
__global__ void pe_stats_k(const void* __restrict__ peraw, const int* __restrict__ flag,
                           float* __restrict__ stats){
    int bf = *flag;
    int t = threadIdx.x;
    int c = t & 15, rb = t >> 4;
    int row0 = blockIdx.x * 256;
    float s = 0.f, ss = 0.f;
    for (int i = 0; i < 16; ++i){
        int r = row0 + rb + 16 * i;
        size_t idx = (size_t)r * 16 + c;
        float v = bf ? bf2f(((const ushort*)peraw)[idx]) : ((const float*)peraw)[idx];
        s += v; ss += v * v;
    }
    __shared__ float red[256];
    red[t] = s; __syncthreads();
    if (t < 16){ float tot = 0.f; for (int j = 0; j < 16; ++j) tot += red[t + 16 * j]; atomicAdd(&stats[t], tot); }
    __syncthreads();
    red[t] = ss; __syncthreads();
    if (t < 16){ float tot = 0.f; for (int j = 0; j < 16; ++j) tot += red[t + 16 * j]; atomicAdd(&stats[64 + t], tot); }
}

__global__ void fin_k(const float* __restrict__ stats, const ushort* __restrict__ g,
                      const ushort* __restrict__ b, float* __restrict__ fin, int nch){
    int c = threadIdx.x;
    if (c >= nch) return;
    float mu  = stats[c] * (1.f / NTOT);
    float var = stats[64 + c] * (1.f / NTOT) - mu * mu;
    float a = rsqrtf(var + EPSV) * bf2f(g[c]);
    fin[c] = a;
    fin[64 + c] = bf2f(b[c]) - mu * a;
}

// ---------------- embedding (dual dtype readers for x, pe) ----------------
__global__ void embed_k(const void* __restrict__ xraw, const void* __restrict__ peraw,
                        const int* __restrict__ flag, const ushort* __restrict__ wsa,
                        const float* __restrict__ finpe, ushort* __restrict__ hout){
    __shared__ ushort xb[64 * 64];
    __shared__ float  pen[64 * 16];
    __shared__ ushort Wes[64 * 48];
    __shared__ ushort Wps[16 * 16];
    int bf = *flag;
    int t = threadIdx.x;
    int row0 = blockIdx.x * 64;
    uint* xd = (uint*)xb;
    if (bf){
        const uint* xsrc = (const uint*)((const ushort*)xraw + (size_t)row0 * 64);
        for (int i = t; i < 2048; i += 256) xd[i] = xsrc[i];
    } else {
        const float4* xsrc = (const float4*)((const float*)xraw + (size_t)row0 * 64);
        for (int i = t; i < 1024; i += 256){
            float4 f = xsrc[i];
            xd[2 * i]     = (uint)f2bf(f.x) | ((uint)f2bf(f.y) << 16);
            xd[2 * i + 1] = (uint)f2bf(f.z) | ((uint)f2bf(f.w) << 16);
        }
    }
    for (int i = t; i < 1024; i += 256){
        int r = i >> 4, k = i & 15;
        size_t idx = (size_t)(row0 + r) * 16 + k;
        float v = bf ? bf2f(((const ushort*)peraw)[idx]) : ((const float*)peraw)[idx];
        pen[i] = v * finpe[k] + finpe[64 + k];
    }
    for (int i = t; i < 3072; i += 256) Wes[i] = wsa[OW_EMB + i];
    Wps[t] = wsa[OW_PE + (t & 255)];
    __syncthreads();
    int c = t & 63, rb = t >> 6;
    if (c < 48){
        float bias = bf2f(wsa[OB_EMB + c]);
        for (int ii = 0; ii < 16; ++ii){
            int r = rb + 4 * ii; float a = bias;
            #pragma unroll
            for (int k = 0; k < 64; ++k) a += bf2f(xb[r * 64 + k]) * bf2f(Wes[k * 48 + c]);
            hout[(size_t)(row0 + r) * 64 + c] = f2bf(a);
        }
    } else {
        int cc = c - 48;
        float bias = bf2f(wsa[OB_PE + cc]);
        for (int ii = 0; ii < 16; ++ii){
            int r = rb + 4 * ii; float a = bias;
            #pragma unroll
            for (int k = 0; k < 16; ++k) a += pen[r * 16 + k] * bf2f(Wps[k * 16 + cc]);
            hout[(size_t)(row0 + r) * 64 + c] = f2bf(a);
        }
    }
}

// ---------------- CSR build ----------------
__global__ void hist_k(const int* __restrict__ dst, int* __restrict__ cnt){
    int stride = gridDim.x * blockDim.x;
    for (int e = blockIdx.x * blockDim.x + threadIdx.x; e < NEDGE; e += stride)
        atomicAdd(&cnt[dst[e]], 1);
}

__global__ void scan_k(const int* __restrict__ cnt, int* __restrict__ offs, int* __restrict__ cur){
    int t = threadIdx.x;           // 1024 threads, 64 counts each
    int base0 = t * 64;
    int s = 0;
    for (int i = 0; i < 64; ++i) s += cnt[base0 + i];
    __shared__ int pref[1024];
    pref[t] = s; __syncthreads();
    for (int off = 1; off < 1024; off <<= 1){
        int v = (t >= off) ? pref[t - off] : 0;
        __syncthreads();
        pref[t] += v;
        __syncthreads();
    }
    int run = pref[t] - s;  // exclusive prefix
    for (int i = 0; i < 64; ++i){
        offs[base0 + i] = run;
        cur[base0 + i]  = run;
        run += cnt[base0 + i];
    }
    if (t == 1023) offs[65536] = run;
}

__global__ void scatter_k(const int* __restrict__ src, const int* __restrict__ dst,
                          int* __restrict__ cur, int* __restrict__ csr){
    int stride = gridDim.x * blockDim.x;
    for (int e = blockIdx.x * blockDim.x + threadIdx.x; e < NEDGE; e += stride){
        int p = atomicAdd(&cur[dst[e]], 1);
        csr[p] = src[e];
    }
}

// ---------------- GIN aggregate: z = h + sum_in h[src] ----------------
__global__ void agg_k(const ushort* __restrict__ h, const int* __restrict__ offs,
                      const int* __restrict__ csr, ushort* __restrict__ z){
    int wave = threadIdx.x >> 6, lane = threadIdx.x & 63;
    int node = blockIdx.x * 4 + wave;
    int beg = offs[node], end = offs[node + 1];
    float s = bf2f(h[(size_t)node * CH + lane]);
    for (int i = beg; i < end; ++i){
        int sn = csr[i];
        s += bf2f(h[(size_t)sn * CH + lane]);
    }
    z[(size_t)node * CH + lane] = f2bf(s);
}

// ---------------- GIN MLP (fused 2 GEMMs) + residual + BN1 stats ----------------
__global__ void gin_k(const ushort* __restrict__ z, const ushort* __restrict__ h,
                      const ushort* __restrict__ W1, const ushort* __restrict__ b1,
                      const ushort* __restrict__ W2, const ushort* __restrict__ b2,
                      ushort* __restrict__ out, float* __restrict__ stats){
    __shared__ ushort zb[4096];
    __shared__ float  tb[4096];
    __shared__ ushort W1s[4096];
    __shared__ ushort W2s[4096];
    __shared__ float  red[256];
    int t = threadIdx.x;
    int row0 = blockIdx.x * 64;
    for (int i = t; i < 2048; i += 256){
        ((uint*)zb)[i]  = ((const uint*)(z + (size_t)row0 * 64))[i];
        ((uint*)W1s)[i] = ((const uint*)W1)[i];
        ((uint*)W2s)[i] = ((const uint*)W2)[i];
    }
    __syncthreads();
    int c = t & 63, rb = t >> 6;
    float bias1 = bf2f(b1[c]);
    for (int ii = 0; ii < 16; ++ii){
        int r = rb + 4 * ii; float a = bias1;
        #pragma unroll
        for (int k = 0; k < 64; ++k) a += bf2f(zb[r * 64 + k]) * bf2f(W1s[k * 64 + c]);
        tb[r * 64 + c] = fmaxf(a, 0.f);
    }
    __syncthreads();
    float bias2 = bf2f(b2[c]);
    float s = 0.f, ss = 0.f;
    for (int ii = 0; ii < 16; ++ii){
        int r = rb + 4 * ii; float a = bias2;
        #pragma unroll
        for (int k = 0; k < 64; ++k) a += tb[r * 64 + k] * bf2f(W2s[k * 64 + c]);
        a += bf2f(h[(size_t)(row0 + r) * 64 + c]);
        out[(size_t)(row0 + r) * 64 + c] = f2bf(a);
        s += a; ss += a * a;
    }
    red[t] = s; __syncthreads();
    if (t < 64) atomicAdd(&stats[t], red[t] + red[64 + t] + red[128 + t] + red[192 + t]);
    __syncthreads();
    red[t] = ss; __syncthreads();
    if (t < 64) atomicAdd(&stats[64 + t], red[t] + red[64 + t] + red[128 + t] + red[192 + t]);
}

// ---------------- fused QKV projections ----------------
__global__ void qkv_k(const ushort* __restrict__ h,
                      const ushort* __restrict__ Wq, const ushort* __restrict__ bq,
                      const ushort* __restrict__ Wk, const ushort* __restrict__ bk,
                      const ushort* __restrict__ Wv, const ushort* __restrict__ bv,
                      ushort* __restrict__ qo, ushort* __restrict__ ko, ushort* __restrict__ vo){
    __shared__ ushort hb[4096];
    __shared__ ushort Wqs[4096], Wks[4096], Wvs[4096];
    int t = threadIdx.x;
    int row0 = blockIdx.x * 64;
    for (int i = t; i < 2048; i += 256){
        ((uint*)hb)[i]  = ((const uint*)(h + (size_t)row0 * 64))[i];
        ((uint*)Wqs)[i] = ((const uint*)Wq)[i];
        ((uint*)Wks)[i] = ((const uint*)Wk)[i];
        ((uint*)Wvs)[i] = ((const uint*)Wv)[i];
    }
    __syncthreads();
    int c = t & 63, rb = t >> 6;
    float fbq = bf2f(bq[c]), fbk = bf2f(bk[c]), fbv = bf2f(bv[c]);
    for (int ii = 0; ii < 16; ++ii){
        int r = rb + 4 * ii;
        float aq = fbq, ak = fbk, av = fbv;
        #pragma unroll
        for (int k = 0; k < 64; ++k){
            float hv = bf2f(hb[r * 64 + k]);
            aq += hv * bf2f(Wqs[k * 64 + c]);
            ak += hv * bf2f(Wks[k * 64 + c]);
            av += hv * bf2f(Wvs[k * 64 + c]);
        }
        size_t o = (size_t)(row0 + r) * 64 + c;
        qo[o] = f2bf(aq); ko[o] = f2bf(ak); vo[o] = f2bf(av);
    }
}

// ---------------- dense per-(graph,head) attention; o written in-place over q ----------------
__global__ void attn_k(ushort* __restrict__ q, const ushort* __restrict__ k,
                       const ushort* __restrict__ v){
    __shared__ ushort Ks[512 * 18];   // stride 18 (36B rows) breaks bank conflicts
    __shared__ ushort Vs[512 * 18];
    int t = threadIdx.x;
    int g = blockIdx.x >> 2, head = blockIdx.x & 3;
    int base = g * 512;
    for (int i = t; i < 4096; i += 256){
        int n = i >> 3, u = i & 7;
        ((uint*)(Ks + n * 18))[u] = ((const uint*)(k + (size_t)(base + n) * 64 + head * 16))[u];
        ((uint*)(Vs + n * 18))[u] = ((const uint*)(v + (size_t)(base + n) * 64 + head * 16))[u];
    }
    __syncthreads();
    int wave = t >> 6, lane = t & 63;
    for (int qi = wave; qi < 512; qi += 4){
        const ushort* qp = q + (size_t)(base + qi) * 64 + head * 16;
        float qv[16];
        #pragma unroll
        for (int d = 0; d < 16; ++d) qv[d] = bf2f(qp[d]);
        float sv[8];
        #pragma unroll
        for (int jj = 0; jj < 8; ++jj){
            int j = lane + 64 * jj;
            const uint* kr = (const uint*)(Ks + j * 18);
            float acc = 0.f;
            #pragma unroll
            for (int u = 0; u < 8; ++u){
                float2 kv = bfp2(kr[u]);
                acc += qv[2 * u] * kv.x + qv[2 * u + 1] * kv.y;
            }
            sv[jj] = acc * 0.25f;     // 1/sqrt(16)
        }
        float m = sv[0];
        #pragma unroll
        for (int jj = 1; jj < 8; ++jj) m = fmaxf(m, sv[jj]);
        #pragma unroll
        for (int off = 32; off >= 1; off >>= 1) m = fmaxf(m, __shfl_xor(m, off, 64));
        float lsum = 0.f, pv[8];
        #pragma unroll
        for (int jj = 0; jj < 8; ++jj){ pv[jj] = __expf(sv[jj] - m); lsum += pv[jj]; }
        #pragma unroll
        for (int off = 32; off >= 1; off >>= 1) lsum += __shfl_xor(lsum, off, 64);
        float ov[16];
        #pragma unroll
        for (int d = 0; d < 16; ++d) ov[d] = 0.f;
        #pragma unroll
        for (int jj = 0; jj < 8; ++jj){
            int j = lane + 64 * jj;
            const uint* vr = (const uint*)(Vs + j * 18);
            float p = pv[jj];
            #pragma unroll
            for (int u = 0; u < 8; ++u){
                float2 vv = bfp2(vr[u]);
                ov[2 * u] += p * vv.x; ov[2 * u + 1] += p * vv.y;
            }
        }
        #pragma unroll
        for (int d = 0; d < 16; ++d){
            #pragma unroll
            for (int off = 32; off >= 1; off >>= 1) ov[d] += __shfl_xor(ov[d], off, 64);
        }
        if (lane == 0){
            float invl = 1.f / lsum;
            uint* op = (uint*)(q + (size_t)(base + qi) * 64 + head * 16);
            #pragma unroll
            for (int u = 0; u < 8; ++u)
                op[u] = (uint)f2bf(ov[2 * u] * invl) | ((uint)f2bf(ov[2 * u + 1] * invl) << 16);
        }
    }
}

// ---------------- attention output projection + residual + BN2 stats (in-place on o) ----------------
__global__ void oproj_k(ushort* __restrict__ o, const ushort* __restrict__ h,
                        const ushort* __restrict__ Wo, const ushort* __restrict__ bo,
                        float* __restrict__ stats){
    __shared__ ushort ob[4096];
    __shared__ ushort Wos[4096];
    __shared__ float  red[256];
    int t = threadIdx.x;
    int row0 = blockIdx.x * 64;
    for (int i = t; i < 2048; i += 256){
        ((uint*)ob)[i]  = ((const uint*)(o + (size_t)row0 * 64))[i];
        ((uint*)Wos)[i] = ((const uint*)Wo)[i];
    }
    __syncthreads();
    int c = t & 63, rb = t >> 6;
    float bias = bf2f(bo[c]);
    float s = 0.f, ss = 0.f;
    for (int ii = 0; ii < 16; ++ii){
        int r = rb + 4 * ii; float a = bias;
        #pragma unroll
        for (int k = 0; k < 64; ++k) a += bf2f(ob[r * 64 + k]) * bf2f(Wos[k * 64 + c]);
        a += bf2f(h[(size_t)(row0 + r) * 64 + c]);
        o[(size_t)(row0 + r) * 64 + c] = f2bf(a);
        s += a; ss += a * a;
    }
    red[t] = s; __syncthreads();
    if (t < 64) atomicAdd(&stats[t], red[t] + red[64 + t] + red[128 + t] + red[192 + t]);
    __syncthreads();
    red[t] = ss; __syncthreads();
    if (t < 64) atomicAdd(&stats[64 + t], red[t] + red[64 + t] + red[128 + t] + red[192 + t]);
}

// ---------------- out = bn1(hl)+bn2(ha); fused MLP; BN3 stats (in-place on hl) ----------------
__global__ void comb_k(ushort* __restrict__ hlpre, const ushort* __restrict__ hapre,
                       const float* __restrict__ fin1, const float* __restrict__ fin2,
                       const ushort* __restrict__ W1, const ushort* __restrict__ b1,
                       const ushort* __restrict__ W2, const ushort* __restrict__ b2,
                       float* __restrict__ stats){
    __shared__ float  outb[32 * 64];
    __shared__ float  hid[32 * 128];
    __shared__ ushort W1s[64 * 128];
    __shared__ ushort W2s[128 * 64];
    __shared__ float  red[256];
    int t = threadIdx.x;
    int row0 = blockIdx.x * 32;
    for (int i = t; i < 2048; i += 256){
        int r = i >> 6, cn = i & 63;
        size_t gi = (size_t)(row0 + r) * 64 + cn;
        outb[i] = bf2f(hlpre[gi]) * fin1[cn] + fin1[64 + cn]
                + bf2f(hapre[gi]) * fin2[cn] + fin2[64 + cn];
    }
    for (int i = t; i < 4096; i += 256){
        ((uint*)W1s)[i] = ((const uint*)W1)[i];
        ((uint*)W2s)[i] = ((const uint*)W2)[i];
    }
    __syncthreads();
    int cc = t & 127, rh = t >> 7;
    float bias1 = bf2f(b1[cc]);
    for (int ii = 0; ii < 16; ++ii){
        int r = rh + 2 * ii; float a = bias1;
        #pragma unroll
        for (int k = 0; k < 64; ++k) a += outb[r * 64 + k] * bf2f(W1s[k * 128 + cc]);
        hid[r * 128 + cc] = fmaxf(a, 0.f);
    }
    __syncthreads();
    int c = t & 63, rb = t >> 6;
    float bias2 = bf2f(b2[c]);
    float s = 0.f, ss = 0.f;
    for (int ii = 0; ii < 8; ++ii){
        int r = rb + 4 * ii; float a = bias2;
        #pragma unroll
        for (int k = 0; k < 128; ++k) a += hid[r * 128 + k] * bf2f(W2s[k * 64 + c]);
        a += outb[r * 64 + c];
        hlpre[(size_t)(row0 + r) * 64 + c] = f2bf(a);
        s += a; ss += a * a;
    }
    red[t] = s; __syncthreads();
    if (t < 64) atomicAdd(&stats[t], red[t] + red[64 + t] + red[128 + t] + red[192 + t]);
    __syncthreads();
    red[t] = ss; __syncthreads();
    if (t < 64) atomicAdd(&stats[64 + t], red[t] + red[64 + t] + red[128 + t] + red[192 + t]);
}

__global__ void bnapply_k(const ushort* __restrict__ in, const float* __restrict__ fin,
                          ushort* __restrict__ out){
    int stride = gridDim.x * blockDim.x;
    const uint* in2 = (const uint*)in;
    uint* out2 = (uint*)out;
    for (int i = blockIdx.x * blockDim.x + threadIdx.x; i < NTOT * CH / 2; i += stride){
        uint w = in2[i];
        float2 p = bfp2(w);
        int cu = (i & 31) * 2;
        float a = p.x * fin[cu] + fin[64 + cu];
        float b = p.y * fin[cu + 1] + fin[64 + cu + 1];
        out2[i] = (uint)f2bf(a) | ((uint)f2bf(b) << 16);
    }
}

// ---------------- mean pool + head GEMM (dual dtype output) ----------------
__global__ void pool_head_k(const ushort* __restrict__ h, const ushort* __restrict__ Wh,
                            const ushort* __restrict__ bh, const int* __restrict__ flag,
                            void* __restrict__ out){
    __shared__ float red[256];
    __shared__ float pooled[64];
    int t = threadIdx.x, g = blockIdx.x;
    int c = t & 63, rb = t >> 6;
    float s = 0.f;
    for (int ii = 0; ii < 128; ++ii){
        int r = rb + 4 * ii;
        s += bf2f(h[(size_t)(g * 512 + r) * 64 + c]);
    }
    red[t] = s; __syncthreads();
    if (t < 64) pooled[t] = (red[t] + red[64 + t] + red[128 + t] + red[192 + t]) * (1.f / 512.f);
    __syncthreads();
    if (t < 128){
        float a = bf2f(bh[t]);
        #pragma unroll
        for (int k = 0; k < 64; ++k) a += pooled[k] * bf2f(Wh[k * 128 + t]);
        if (*flag) ((ushort*)out)[(size_t)g * 128 + t] = f2bf(a);
        else       ((float*)out)[(size_t)g * 128 + t] = a;
    }
}

extern "C" void kernel_launch(void* const* d_in, const int* in_sizes, int n_in,
                              void* d_out, int out_size, void* d_ws, size_t ws_size,
                              hipStream_t stream){
    const void* x  = d_in[0];
    const void* pe = d_in[1];
    const int* eidx = (const int*)d_in[2];

    char* ws = (char*)d_ws;
    const size_t MB = 1024 * 1024;
    const size_t KB = 1024;
    ushort* h_buf = (ushort*)(ws);                 // 8 MB
    ushort* z_buf = (ushort*)(ws + 8 * MB);        // 8 MB (gin out -> comb out, in place)
    ushort* q_buf = (ushort*)(ws + 16 * MB);       // 8 MB (q -> attn o -> oproj out, in place)
    ushort* k_buf = (ushort*)(ws + 24 * MB);       // 8 MB
    ushort* v_buf = (ushort*)(ws + 32 * MB);       // 8 MB
    int* csr   = (int*)(ws + 40 * MB);             // 4 MB
    int* offs  = (int*)(ws + 44 * MB);             // 256 KB + 4
    int* cnt   = (int*)(ws + 44 * MB + 384 * KB);  // 256 KB
    int* cur   = (int*)(ws + 44 * MB + 640 * KB);  // 256 KB
    float* stats = (float*)(ws + 44 * MB + 896 * KB);  // 8 KB
    float* fin   = (float*)(ws + 44 * MB + 904 * KB);  // 8 KB
    int*   flag  = (int*)(ws + 44 * MB + 912 * KB);    // 4 B
    ushort* wsa  = (ushort*)(ws + 45 * MB);            // 360 KB weight arena

    hipMemsetAsync(stats, 0, 13 * 128 * sizeof(float), stream);
    hipMemsetAsync(cnt, 0, 65536 * sizeof(int), stream);

    detect_k<<<1, 64, 0, stream>>>((const uint*)x, flag);

    WPtrs wp;
    for (int i = 0; i < 30; ++i) wp.p[i] = d_in[3 + i];
    convall_k<<<(TOTW + 255) / 256, 256, 0, stream>>>(wp, wsa, flag);

    pe_stats_k<<<256, 256, 0, stream>>>(pe, flag, stats);
    fin_k<<<1, 64, 0, stream>>>(stats, wsa + OG_PEN, wsa + OB_PEN, fin, 16);
    embed_k<<<1024, 256, 0, stream>>>(x, pe, flag, wsa, fin, h_buf);
    hist_k<<<1024, 256, 0, stream>>>(eidx + NEDGE, cnt);
    scan_k<<<1, 1024, 0, stream>>>(cnt, offs, cur);
    scatter_k<<<1024, 256, 0, stream>>>(eidx, eidx + NEDGE, cur, csr);

    for (int l = 0; l < NLAYER; ++l){
        float* st1 = stats + (1 + 3 * l) * 128; float* fi1 = fin + (1 + 3 * l) * 128;
        float* st2 = stats + (2 + 3 * l) * 128; float* fi2 = fin + (2 + 3 * l) * 128;
        float* st3 = stats + (3 + 3 * l) * 128; float* fi3 = fin + (3 + 3 * l) * 128;

        agg_k<<<16384, 256, 0, stream>>>(h_buf, offs, csr, z_buf);
        gin_k<<<1024, 256, 0, stream>>>(z_buf, h_buf, wsa + OW_G1 + l * 4096, wsa + OB_G1 + l * 64,
                                        wsa + OW_G2 + l * 4096, wsa + OB_G2 + l * 64, z_buf, st1);
        fin_k<<<1, 64, 0, stream>>>(st1, wsa + ON1G + l * 64, wsa + ON1B + l * 64, fi1, 64);
        qkv_k<<<1024, 256, 0, stream>>>(h_buf,
                                        wsa + OW_Q + l * 4096, wsa + OB_Q + l * 64,
                                        wsa + OW_K + l * 4096, wsa + OB_K + l * 64,
                                        wsa + OW_V + l * 4096, wsa + OB_V + l * 64,
                                        q_buf, k_buf, v_buf);
        attn_k<<<512, 256, 0, stream>>>(q_buf, k_buf, v_buf);
        oproj_k<<<1024, 256, 0, stream>>>(q_buf, h_buf, wsa + OW_O + l * 4096, wsa + OB_O + l * 64, st2);
        fin_k<<<1, 64, 0, stream>>>(st2, wsa + ON2G + l * 64, wsa + ON2B + l * 64, fi2, 64);
        comb_k<<<2048, 256, 0, stream>>>(z_buf, q_buf, fi1, fi2,
                                         wsa + OW_M1 + l * 8192, wsa + OB_M1 + l * 128,
                                         wsa + OW_M2 + l * 8192, wsa + OB_M2 + l * 64, st3);
        fin_k<<<1, 64, 0, stream>>>(st3, wsa + ON3G + l * 64, wsa + ON3B + l * 64, fi3, 64);
        bnapply_k<<<2048, 256, 0, stream>>>(z_buf, fi3, h_buf);
    }
    pool_head_k<<<128, 256, 0, stream>>>(h_buf, wsa + OW_H, wsa + OB_H, flag, d_out);
}

// Round 4
// 7914.565 us; speedup vs baseline: 1.9411x; 1.9411x over previous
//
#include <hip/hip_runtime.h>

typedef unsigned short ushort;
typedef unsigned int uint;

#define NTOT   65536
#define CH     64
#define NLAYER 4
#define NEDGE  1048576
#define EPSV   1e-5f

// staged-weight arena element offsets (order = d_in[3..32])
#define OW_EMB 0
#define OB_EMB 3072
#define OW_PE  3120
#define OB_PE  3376
#define OG_PEN 3392
#define OB_PEN 3408
#define OW_G1  3424
#define OB_G1  19808
#define OW_G2  20064
#define OB_G2  36448
#define OW_Q   36704
#define OB_Q   53088
#define OW_K   53344
#define OB_K   69728
#define OW_V   69984
#define OB_V   86368
#define OW_O   86624
#define OB_O   103008
#define ON1G   103264
#define ON1B   103520
#define ON2G   103776
#define ON2B   104032
#define ON3G   104288
#define ON3B   104544
#define OW_M1  104800
#define OB_M1  137568
#define OW_M2  138080
#define OB_M2  170848
#define OW_H   171104
#define OB_H   179296
#define TOTW   179424

__device__ __forceinline__ float bf2f(ushort u){ return __uint_as_float(((uint)u) << 16); }
__device__ __forceinline__ ushort f2bf(float f){
    uint u = __float_as_uint(f);
    uint r = (u + 0x7fffu + ((u >> 16) & 1u)) >> 16;
    return (ushort)r;
}
__device__ __forceinline__ float2 bfp2(uint w){
    return make_float2(__uint_as_float(w << 16), __uint_as_float(w & 0xffff0000u));
}

// ---------------- dtype probe: 1=bf16 inputs, 0=fp32 inputs ----------------
__global__ void detect_k(const uint* __restrict__ x, int* __restrict__ flag){
    int lane = threadIdx.x;                 // 64 lanes
    uint w = x[lane];
    uint e = (w >> 7) & 0xffu;              // exponent field of LOW bf16 half
    int ok = (e >= 100u && e <= 140u) ? 1 : 0;
    unsigned long long m = __ballot(ok);
    if (lane == 0) flag[0] = (__popcll(m) >= 48) ? 1 : 0;
}

// ---------------- convert/copy all weight tensors into bf16 arena ----------------
struct WPtrs { const void* p[30]; };

__global__ void convall_k(WPtrs ptrs, ushort* __restrict__ dst, const int* __restrict__ flag){
    const int offs[31] = {0,3072,3120,3376,3392,3408,3424,19808,20064,36448,36704,
                          53088,53344,69728,69984,86368,86624,103008,103264,103520,
                          103776,104032,104288,104544,104800,137568,138080,170848,
                          171104,179296,179424};
    int i = blockIdx.x * blockDim.x + threadIdx.x;
    if (i >= TOTW) return;
    int s = 0;
    while (s < 29 && i >= offs[s + 1]) ++s;
    int j = i - offs[s];
    if (*flag) dst[i] = ((const ushort*)ptrs.p[s])[j];
    else       dst[i] = f2bf(((const float*)ptrs.p[s])[j]);
}

// ---------------- BN stats over pe (dual dtype) ----------------
__global__ void pe_stats_k(const void* __restrict__ peraw, const int* __restrict__ flag,
                           float* __restrict__ stats){
    int bf = *flag;
    int t = threadIdx.x;
    int c = t & 15, rb = t >> 4;
    int row0 = blockIdx.x * 256;
    float s = 0.f, ss = 0.f;
    for (int i = 0; i < 16; ++i){
        int r = row0 + rb + 16 * i;
        size_t idx = (size_t)r * 16 + c;
        float v = bf ? bf2f(((const ushort*)peraw)[idx]) : ((const float*)peraw)[idx];
        s += v; ss += v * v;
    }
    __shared__ float red[256];
    red[t] = s; __syncthreads();
    if (t < 16){ float tot = 0.f; for (int j = 0; j < 16; ++j) tot += red[t + 16 * j]; atomicAdd(&stats[t], tot); }
    __syncthreads();
    red[t] = ss; __syncthreads();
    if (t < 16){ float tot = 0.f; for (int j = 0; j < 16; ++j) tot += red[t + 16 * j]; atomicAdd(&stats[64 + t], tot); }
}

__global__ void fin_k(const float* __restrict__ stats, const ushort* __restrict__ g,
                      const ushort* __restrict__ b, float* __restrict__ fin, int nch){
    int c = threadIdx.x;
    if (c >= nch) return;
    float mu  = stats[c] * (1.f / NTOT);
    float var = stats[64 + c] * (1.f / NTOT) - mu * mu;
    float a = rsqrtf(var + EPSV) * bf2f(g[c]);
    fin[c] = a;
    fin[64 + c] = bf2f(b[c]) - mu * a;
}

// ---------------- embedding (dual dtype readers for x, pe) ----------------
__global__ void embed_k(const void* __restrict__ xraw, const void* __restrict__ peraw,
                        const int* __restrict__ flag, const ushort* __restrict__ wsa,
                        const float* __restrict__ finpe, ushort* __restrict__ hout){
    __shared__ ushort xb[64 * 64];
    __shared__ float  pen[64 * 16];
    __shared__ ushort Wes[64 * 48];
    __shared__ ushort Wps[16 * 16];
    int bf = *flag;
    int t = threadIdx.x;
    int row0 = blockIdx.x * 64;
    uint* xd = (uint*)xb;
    if (bf){
        const uint* xsrc = (const uint*)((const ushort*)xraw + (size_t)row0 * 64);
        for (int i = t; i < 2048; i += 256) xd[i] = xsrc[i];
    } else {
        const float4* xsrc = (const float4*)((const float*)xraw + (size_t)row0 * 64);
        for (int i = t; i < 1024; i += 256){
            float4 f = xsrc[i];
            xd[2 * i]     = (uint)f2bf(f.x) | ((uint)f2bf(f.y) << 16);
            xd[2 * i + 1] = (uint)f2bf(f.z) | ((uint)f2bf(f.w) << 16);
        }
    }
    for (int i = t; i < 1024; i += 256){
        int r = i >> 4, k = i & 15;
        size_t idx = (size_t)(row0 + r) * 16 + k;
        float v = bf ? bf2f(((const ushort*)peraw)[idx]) : ((const float*)peraw)[idx];
        pen[i] = v * finpe[k] + finpe[64 + k];
    }
    for (int i = t; i < 3072; i += 256) Wes[i] = wsa[OW_EMB + i];
    Wps[t] = wsa[OW_PE + (t & 255)];
    __syncthreads();
    int c = t & 63, rb = t >> 6;
    if (c < 48){
        float bias = bf2f(wsa[OB_EMB + c]);
        for (int ii = 0; ii < 16; ++ii){
            int r = rb + 4 * ii; float a = bias;
            #pragma unroll
            for (int k = 0; k < 64; ++k) a += bf2f(xb[r * 64 + k]) * bf2f(Wes[k * 48 + c]);
            hout[(size_t)(row0 + r) * 64 + c] = f2bf(a);
        }
    } else {
        int cc = c - 48;
        float bias = bf2f(wsa[OB_PE + cc]);
        for (int ii = 0; ii < 16; ++ii){
            int r = rb + 4 * ii; float a = bias;
            #pragma unroll
            for (int k = 0; k < 16; ++k) a += pen[r * 16 + k] * bf2f(Wps[k * 16 + cc]);
            hout[(size_t)(row0 + r) * 64 + c] = f2bf(a);
        }
    }
}

// ---------------- CSR build ----------------
__global__ void hist_k(const int* __restrict__ dst, int* __restrict__ cnt){
    int stride = gridDim.x * blockDim.x;
    for (int e = blockIdx.x * blockDim.x + threadIdx.x; e < NEDGE; e += stride)
        atomicAdd(&cnt[dst[e]], 1);
}

__global__ void scan_k(const int* __restrict__ cnt, int* __restrict__ offs, int* __restrict__ cur){
    int t = threadIdx.x;           // 1024 threads, 64 counts each
    int base0 = t * 64;
    int s = 0;
    for (int i = 0; i < 64; ++i) s += cnt[base0 + i];
    __shared__ int pref[1024];
    pref[t] = s; __syncthreads();
    for (int off = 1; off < 1024; off <<= 1){
        int v = (t >= off) ? pref[t - off] : 0;
        __syncthreads();
        pref[t] += v;
        __syncthreads();
    }
    int run = pref[t] - s;  // exclusive prefix
    for (int i = 0; i < 64; ++i){
        offs[base0 + i] = run;
        cur[base0 + i]  = run;
        run += cnt[base0 + i];
    }
    if (t == 1023) offs[65536] = run;
}

__global__ void scatter_k(const int* __restrict__ src, const int* __restrict__ dst,
                          int* __restrict__ cur, int* __restrict__ csr){
    int stride = gridDim.x * blockDim.x;
    for (int e = blockIdx.x * blockDim.x + threadIdx.x; e < NEDGE; e += stride){
        int p = atomicAdd(&cur[dst[e]], 1);
        csr[p] = src[e];
    }
}

// ---------------- GIN aggregate: z = h + sum_in h[src] ----------------
__global__ void agg_k(const ushort* __restrict__ h, const int* __restrict__ offs,
                      const int* __restrict__ csr, ushort* __restrict__ z){
    int wave = threadIdx.x >> 6, lane = threadIdx.x & 63;
    int node = blockIdx.x * 4 + wave;
    int beg = offs[node], end = offs[node + 1];
    float s = bf2f(h[(size_t)node * CH + lane]);
    for (int i = beg; i < end; ++i){
        int sn = csr[i];
        s += bf2f(h[(size_t)sn * CH + lane]);
    }
    z[(size_t)node * CH + lane] = f2bf(s);
}

// ---------------- GIN MLP (fused 2 GEMMs) + residual + BN1 stats ----------------
__global__ void gin_k(const ushort* __restrict__ z, const ushort* __restrict__ h,
                      const ushort* __restrict__ W1, const ushort* __restrict__ b1,
                      const ushort* __restrict__ W2, const ushort* __restrict__ b2,
                      ushort* __restrict__ out, float* __restrict__ stats){
    __shared__ ushort zb[4096];
    __shared__ float  tb[4096];
    __shared__ ushort W1s[4096];
    __shared__ ushort W2s[4096];
    __shared__ float  red[256];
    int t = threadIdx.x;
    int row0 = blockIdx.x * 64;
    for (int i = t; i < 2048; i += 256){
        ((uint*)zb)[i]  = ((const uint*)(z + (size_t)row0 * 64))[i];
        ((uint*)W1s)[i] = ((const uint*)W1)[i];
        ((uint*)W2s)[i] = ((const uint*)W2)[i];
    }
    __syncthreads();
    int c = t & 63, rb = t >> 6;
    float bias1 = bf2f(b1[c]);
    for (int ii = 0; ii < 16; ++ii){
        int r = rb + 4 * ii; float a = bias1;
        #pragma unroll
        for (int k = 0; k < 64; ++k) a += bf2f(zb[r * 64 + k]) * bf2f(W1s[k * 64 + c]);
        tb[r * 64 + c] = fmaxf(a, 0.f);
    }
    __syncthreads();
    float bias2 = bf2f(b2[c]);
    float s = 0.f, ss = 0.f;
    for (int ii = 0; ii < 16; ++ii){
        int r = rb + 4 * ii; float a = bias2;
        #pragma unroll
        for (int k = 0; k < 64; ++k) a += tb[r * 64 + k] * bf2f(W2s[k * 64 + c]);
        a += bf2f(h[(size_t)(row0 + r) * 64 + c]);
        out[(size_t)(row0 + r) * 64 + c] = f2bf(a);
        s += a; ss += a * a;
    }
    red[t] = s; __syncthreads();
    if (t < 64) atomicAdd(&stats[t], red[t] + red[64 + t] + red[128 + t] + red[192 + t]);
    __syncthreads();
    red[t] = ss; __syncthreads();
    if (t < 64) atomicAdd(&stats[64 + t], red[t] + red[64 + t] + red[128 + t] + red[192 + t]);
}

// ---------------- fused QKV projections ----------------
__global__ void qkv_k(const ushort* __restrict__ h,
                      const ushort* __restrict__ Wq, const ushort* __restrict__ bq,
                      const ushort* __restrict__ Wk, const ushort* __restrict__ bk,
                      const ushort* __restrict__ Wv, const ushort* __restrict__ bv,
                      ushort* __restrict__ qo, ushort* __restrict__ ko, ushort* __restrict__ vo){
    __shared__ ushort hb[4096];
    __shared__ ushort Wqs[4096], Wks[4096], Wvs[4096];
    int t = threadIdx.x;
    int row0 = blockIdx.x * 64;
    for (int i = t; i < 2048; i += 256){
        ((uint*)hb)[i]  = ((const uint*)(h + (size_t)row0 * 64))[i];
        ((uint*)Wqs)[i] = ((const uint*)Wq)[i];
        ((uint*)Wks)[i] = ((const uint*)Wk)[i];
        ((uint*)Wvs)[i] = ((const uint*)Wv)[i];
    }
    __syncthreads();
    int c = t & 63, rb = t >> 6;
    float fbq = bf2f(bq[c]), fbk = bf2f(bk[c]), fbv = bf2f(bv[c]);
    for (int ii = 0; ii < 16; ++ii){
        int r = rb + 4 * ii;
        float aq = fbq, ak = fbk, av = fbv;
        #pragma unroll
        for (int k = 0; k < 64; ++k){
            float hv = bf2f(hb[r * 64 + k]);
            aq += hv * bf2f(Wqs[k * 64 + c]);
            ak += hv * bf2f(Wks[k * 64 + c]);
            av += hv * bf2f(Wvs[k * 64 + c]);
        }
        size_t o = (size_t)(row0 + r) * 64 + c;
        qo[o] = f2bf(aq); ko[o] = f2bf(ak); vo[o] = f2bf(av);
    }
}

// ---------------- dense per-(graph,head) attention; thread-per-query online softmax ----------------
// o written in-place over q. Block = one (graph, head); 256 threads × 2 queries each.
__global__ void attn_k(ushort* __restrict__ q, const ushort* __restrict__ k,
                       const ushort* __restrict__ v){
    __shared__ float Ks[512 * 16];   // 32 KB
    __shared__ float Vs[512 * 16];   // 32 KB
    int t = threadIdx.x;
    int g = blockIdx.x >> 2, head = blockIdx.x & 3;
    int base = g * 512;
    // stage K,V as f32 rows of 16
    for (int i = t; i < 4096; i += 256){     // 512 rows × 8 uints
        int n = i >> 3, u = i & 7;
        uint kw = ((const uint*)(k + (size_t)(base + n) * 64 + head * 16))[u];
        uint vw = ((const uint*)(v + (size_t)(base + n) * 64 + head * 16))[u];
        float2 kf = bfp2(kw), vf = bfp2(vw);
        Ks[n * 16 + 2 * u]     = kf.x;
        Ks[n * 16 + 2 * u + 1] = kf.y;
        Vs[n * 16 + 2 * u]     = vf.x;
        Vs[n * 16 + 2 * u + 1] = vf.y;
    }
    __syncthreads();
    // two queries per thread: rows t and t+256
    float qa[16], qb[16], oa[16], ob[16];
    {
        const uint* qpa = (const uint*)(q + (size_t)(base + t) * 64 + head * 16);
        const uint* qpb = (const uint*)(q + (size_t)(base + t + 256) * 64 + head * 16);
        #pragma unroll
        for (int u = 0; u < 8; ++u){
            float2 fa = bfp2(qpa[u]); qa[2 * u] = fa.x; qa[2 * u + 1] = fa.y;
            float2 fb = bfp2(qpb[u]); qb[2 * u] = fb.x; qb[2 * u + 1] = fb.y;
        }
    }
    #pragma unroll
    for (int d = 0; d < 16; ++d){ oa[d] = 0.f; ob[d] = 0.f; }
    float ma = -1e30f, mb = -1e30f, la = 0.f, lb = 0.f;

    for (int j = 0; j < 512; ++j){
        const float4* kr = (const float4*)(Ks + j * 16);
        float4 k0 = kr[0], k1 = kr[1], k2 = kr[2], k3 = kr[3];
        // 4-way partial dots to shorten the dependency chain
        float a0 = qa[0]*k0.x + qa[1]*k0.y + qa[2]*k0.z + qa[3]*k0.w;
        float a1 = qa[4]*k1.x + qa[5]*k1.y + qa[6]*k1.z + qa[7]*k1.w;
        float a2 = qa[8]*k2.x + qa[9]*k2.y + qa[10]*k2.z + qa[11]*k2.w;
        float a3 = qa[12]*k3.x + qa[13]*k3.y + qa[14]*k3.z + qa[15]*k3.w;
        float b0 = qb[0]*k0.x + qb[1]*k0.y + qb[2]*k0.z + qb[3]*k0.w;
        float b1 = qb[4]*k1.x + qb[5]*k1.y + qb[6]*k1.z + qb[7]*k1.w;
        float b2 = qb[8]*k2.x + qb[9]*k2.y + qb[10]*k2.z + qb[11]*k2.w;
        float b3 = qb[12]*k3.x + qb[13]*k3.y + qb[14]*k3.z + qb[15]*k3.w;
        float sa = ((a0 + a1) + (a2 + a3)) * 0.25f;
        float sb = ((b0 + b1) + (b2 + b3)) * 0.25f;
        float mna = fmaxf(ma, sa), mnb = fmaxf(mb, sb);
        float pa = __expf(sa - mna), pb = __expf(sb - mnb);
        float ca = __expf(ma - mna), cb = __expf(mb - mnb);
        ma = mna; mb = mnb;
        la = fmaf(la, ca, pa); lb = fmaf(lb, cb, pb);
        const float4* vr = (const float4*)(Vs + j * 16);
        float4 v0 = vr[0], v1 = vr[1], v2 = vr[2], v3 = vr[3];
        oa[0]  = fmaf(oa[0],  ca, pa * v0.x); oa[1]  = fmaf(oa[1],  ca, pa * v0.y);
        oa[2]  = fmaf(oa[2],  ca, pa * v0.z); oa[3]  = fmaf(oa[3],  ca, pa * v0.w);
        oa[4]  = fmaf(oa[4],  ca, pa * v1.x); oa[5]  = fmaf(oa[5],  ca, pa * v1.y);
        oa[6]  = fmaf(oa[6],  ca, pa * v1.z); oa[7]  = fmaf(oa[7],  ca, pa * v1.w);
        oa[8]  = fmaf(oa[8],  ca, pa * v2.x); oa[9]  = fmaf(oa[9],  ca, pa * v2.y);
        oa[10] = fmaf(oa[10], ca, pa * v2.z); oa[11] = fmaf(oa[11], ca, pa * v2.w);
        oa[12] = fmaf(oa[12], ca, pa * v3.x); oa[13] = fmaf(oa[13], ca, pa * v3.y);
        oa[14] = fmaf(oa[14], ca, pa * v3.z); oa[15] = fmaf(oa[15], ca, pa * v3.w);
        ob[0]  = fmaf(ob[0],  cb, pb * v0.x); ob[1]  = fmaf(ob[1],  cb, pb * v0.y);
        ob[2]  = fmaf(ob[2],  cb, pb * v0.z); ob[3]  = fmaf(ob[3],  cb, pb * v0.w);
        ob[4]  = fmaf(ob[4],  cb, pb * v1.x); ob[5]  = fmaf(ob[5],  cb, pb * v1.y);
        ob[6]  = fmaf(ob[6],  cb, pb * v1.z); ob[7]  = fmaf(ob[7],  cb, pb * v1.w);
        ob[8]  = fmaf(ob[8],  cb, pb * v2.x); ob[9]  = fmaf(ob[9],  cb, pb * v2.y);
        ob[10] = fmaf(ob[10], cb, pb * v2.z); ob[11] = fmaf(ob[11], cb, pb * v2.w);
        ob[12] = fmaf(ob[12], cb, pb * v3.x); ob[13] = fmaf(ob[13], cb, pb * v3.y);
        ob[14] = fmaf(ob[14], cb, pb * v3.z); ob[15] = fmaf(ob[15], cb, pb * v3.w);
    }
    float inva = 1.f / la, invb = 1.f / lb;
    uint* opa = (uint*)(q + (size_t)(base + t) * 64 + head * 16);
    uint* opb = (uint*)(q + (size_t)(base + t + 256) * 64 + head * 16);
    #pragma unroll
    for (int u = 0; u < 8; ++u){
        opa[u] = (uint)f2bf(oa[2 * u] * inva) | ((uint)f2bf(oa[2 * u + 1] * inva) << 16);
        opb[u] = (uint)f2bf(ob[2 * u] * invb) | ((uint)f2bf(ob[2 * u + 1] * invb) << 16);
    }
}

// ---------------- attention output projection + residual + BN2 stats (in-place on o) ----------------
__global__ void oproj_k(ushort* __restrict__ o, const ushort* __restrict__ h,
                        const ushort* __restrict__ Wo, const ushort* __restrict__ bo,
                        float* __restrict__ stats){
    __shared__ ushort ob[4096];
    __shared__ ushort Wos[4096];
    __shared__ float  red[256];
    int t = threadIdx.x;
    int row0 = blockIdx.x * 64;
    for (int i = t; i < 2048; i += 256){
        ((uint*)ob)[i]  = ((const uint*)(o + (size_t)row0 * 64))[i];
        ((uint*)Wos)[i] = ((const uint*)Wo)[i];
    }
    __syncthreads();
    int c = t & 63, rb = t >> 6;
    float bias = bf2f(bo[c]);
    float s = 0.f, ss = 0.f;
    for (int ii = 0; ii < 16; ++ii){
        int r = rb + 4 * ii; float a = bias;
        #pragma unroll
        for (int k = 0; k < 64; ++k) a += bf2f(ob[r * 64 + k]) * bf2f(Wos[k * 64 + c]);
        a += bf2f(h[(size_t)(row0 + r) * 64 + c]);
        o[(size_t)(row0 + r) * 64 + c] = f2bf(a);
        s += a; ss += a * a;
    }
    red[t] = s; __syncthreads();
    if (t < 64) atomicAdd(&stats[t], red[t] + red[64 + t] + red[128 + t] + red[192 + t]);
    __syncthreads();
    red[t] = ss; __syncthreads();
    if (t < 64) atomicAdd(&stats[64 + t], red[t] + red[64 + t] + red[128 + t] + red[192 + t]);
}

// ---------------- out = bn1(hl)+bn2(ha); fused MLP; BN3 stats (in-place on hl) ----------------
__global__ void comb_k(ushort* __restrict__ hlpre, const ushort* __restrict__ hapre,
                       const float* __restrict__ fin1, const float* __restrict__ fin2,
                       const ushort* __restrict__ W1, const ushort* __restrict__ b1,
                       const ushort* __restrict__ W2, const ushort* __restrict__ b2,
                       float* __restrict__ stats){
    __shared__ float  outb[32 * 64];
    __shared__ float  hid[32 * 128];
    __shared__ ushort W1s[64 * 128];
    __shared__ ushort W2s[128 * 64];
    __shared__ float  red[256];
    int t = threadIdx.x;
    int row0 = blockIdx.x * 32;
    for (int i = t; i < 2048; i += 256){
        int r = i >> 6, cn = i & 63;
        size_t gi = (size_t)(row0 + r) * 64 + cn;
        outb[i] = bf2f(hlpre[gi]) * fin1[cn] + fin1[64 + cn]
                + bf2f(hapre[gi]) * fin2[cn] + fin2[64 + cn];
    }
    for (int i = t; i < 4096; i += 256){
        ((uint*)W1s)[i] = ((const uint*)W1)[i];
        ((uint*)W2s)[i] = ((const uint*)W2)[i];
    }
    __syncthreads();
    int cc = t & 127, rh = t >> 7;
    float bias1 = bf2f(b1[cc]);
    for (int ii = 0; ii < 16; ++ii){
        int r = rh + 2 * ii; float a = bias1;
        #pragma unroll
        for (int k = 0; k < 64; ++k) a += outb[r * 64 + k] * bf2f(W1s[k * 128 + cc]);
        hid[r * 128 + cc] = fmaxf(a, 0.f);
    }
    __syncthreads();
    int c = t & 63, rb = t >> 6;
    float bias2 = bf2f(b2[c]);
    float s = 0.f, ss = 0.f;
    for (int ii = 0; ii < 8; ++ii){
        int r = rb + 4 * ii; float a = bias2;
        #pragma unroll
        for (int k = 0; k < 128; ++k) a += hid[r * 128 + k] * bf2f(W2s[k * 64 + c]);
        a += outb[r * 64 + c];
        hlpre[(size_t)(row0 + r) * 64 + c] = f2bf(a);
        s += a; ss += a * a;
    }
    red[t] = s; __syncthreads();
    if (t < 64) atomicAdd(&stats[t], red[t] + red[64 + t] + red[128 + t] + red[192 + t]);
    __syncthreads();
    red[t] = ss; __syncthreads();
    if (t < 64) atomicAdd(&stats[64 + t], red[t] + red[64 + t] + red[128 + t] + red[192 + t]);
}

__global__ void bnapply_k(const ushort* __restrict__ in, const float* __restrict__ fin,
                          ushort* __restrict__ out){
    int stride = gridDim.x * blockDim.x;
    const uint* in2 = (const uint*)in;
    uint* out2 = (uint*)out;
    for (int i = blockIdx.x * blockDim.x + threadIdx.x; i < NTOT * CH / 2; i += stride){
        uint w = in2[i];
        float2 p = bfp2(w);
        int cu = (i & 31) * 2;
        float a = p.x * fin[cu] + fin[64 + cu];
        float b = p.y * fin[cu + 1] + fin[64 + cu + 1];
        out2[i] = (uint)f2bf(a) | ((uint)f2bf(b) << 16);
    }
}

// ---------------- mean pool + head GEMM (dual dtype output) ----------------
__global__ void pool_head_k(const ushort* __restrict__ h, const ushort* __restrict__ Wh,
                            const ushort* __restrict__ bh, const int* __restrict__ flag,
                            void* __restrict__ out){
    __shared__ float red[256];
    __shared__ float pooled[64];
    int t = threadIdx.x, g = blockIdx.x;
    int c = t & 63, rb = t >> 6;
    float s = 0.f;
    for (int ii = 0; ii < 128; ++ii){
        int r = rb + 4 * ii;
        s += bf2f(h[(size_t)(g * 512 + r) * 64 + c]);
    }
    red[t] = s; __syncthreads();
    if (t < 64) pooled[t] = (red[t] + red[64 + t] + red[128 + t] + red[192 + t]) * (1.f / 512.f);
    __syncthreads();
    if (t < 128){
        float a = bf2f(bh[t]);
        #pragma unroll
        for (int k = 0; k < 64; ++k) a += pooled[k] * bf2f(Wh[k * 128 + t]);
        if (*flag) ((ushort*)out)[(size_t)g * 128 + t] = f2bf(a);
        else       ((float*)out)[(size_t)g * 128 + t] = a;
    }
}

extern "C" void kernel_launch(void* const* d_in, const int* in_sizes, int n_in,
                              void* d_out, int out_size, void* d_ws, size_t ws_size,
                              hipStream_t stream){
    const void* x  = d_in[0];
    const void* pe = d_in[1];
    const int* eidx = (const int*)d_in[2];

    char* ws = (char*)d_ws;
    const size_t MB = 1024 * 1024;
    const size_t KB = 1024;
    ushort* h_buf = (ushort*)(ws);                 // 8 MB
    ushort* z_buf = (ushort*)(ws + 8 * MB);        // 8 MB (gin out -> comb out, in place)
    ushort* q_buf = (ushort*)(ws + 16 * MB);       // 8 MB (q -> attn o -> oproj out, in place)
    ushort* k_buf = (ushort*)(ws + 24 * MB);       // 8 MB
    ushort* v_buf = (ushort*)(ws + 32 * MB);       // 8 MB
    int* csr   = (int*)(ws + 40 * MB);             // 4 MB
    int* offs  = (int*)(ws + 44 * MB);             // 256 KB + 4
    int* cnt   = (int*)(ws + 44 * MB + 384 * KB);  // 256 KB
    int* cur   = (int*)(ws + 44 * MB + 640 * KB);  // 256 KB
    float* stats = (float*)(ws + 44 * MB + 896 * KB);  // 8 KB
    float* fin   = (float*)(ws + 44 * MB + 904 * KB);  // 8 KB
    int*   flag  = (int*)(ws + 44 * MB + 912 * KB);    // 4 B
    ushort* wsa  = (ushort*)(ws + 45 * MB);            // 360 KB weight arena

    hipMemsetAsync(stats, 0, 13 * 128 * sizeof(float), stream);
    hipMemsetAsync(cnt, 0, 65536 * sizeof(int), stream);

    detect_k<<<1, 64, 0, stream>>>((const uint*)x, flag);

    WPtrs wp;
    for (int i = 0; i < 30; ++i) wp.p[i] = d_in[3 + i];
    convall_k<<<(TOTW + 255) / 256, 256, 0, stream>>>(wp, wsa, flag);

    pe_stats_k<<<256, 256, 0, stream>>>(pe, flag, stats);
    fin_k<<<1, 64, 0, stream>>>(stats, wsa + OG_PEN, wsa + OB_PEN, fin, 16);
    embed_k<<<1024, 256, 0, stream>>>(x, pe, flag, wsa, fin, h_buf);
    hist_k<<<1024, 256, 0, stream>>>(eidx + NEDGE, cnt);
    scan_k<<<1, 1024, 0, stream>>>(cnt, offs, cur);
    scatter_k<<<1024, 256, 0, stream>>>(eidx, eidx + NEDGE, cur, csr);

    for (int l = 0; l < NLAYER; ++l){
        float* st1 = stats + (1 + 3 * l) * 128; float* fi1 = fin + (1 + 3 * l) * 128;
        float* st2 = stats + (2 + 3 * l) * 128; float* fi2 = fin + (2 + 3 * l) * 128;
        float* st3 = stats + (3 + 3 * l) * 128; float* fi3 = fin + (3 + 3 * l) * 128;

        agg_k<<<16384, 256, 0, stream>>>(h_buf, offs, csr, z_buf);
        gin_k<<<1024, 256, 0, stream>>>(z_buf, h_buf, wsa + OW_G1 + l * 4096, wsa + OB_G1 + l * 64,
                                        wsa + OW_G2 + l * 4096, wsa + OB_G2 + l * 64, z_buf, st1);
        fin_k<<<1, 64, 0, stream>>>(st1, wsa + ON1G + l * 64, wsa + ON1B + l * 64, fi1, 64);
        qkv_k<<<1024, 256, 0, stream>>>(h_buf,
                                        wsa + OW_Q + l * 4096, wsa + OB_Q + l * 64,
                                        wsa + OW_K + l * 4096, wsa + OB_K + l * 64,
                                        wsa + OW_V + l * 4096, wsa + OB_V + l * 64,
                                        q_buf, k_buf, v_buf);
        attn_k<<<512, 256, 0, stream>>>(q_buf, k_buf, v_buf);
        oproj_k<<<1024, 256, 0, stream>>>(q_buf, h_buf, wsa + OW_O + l * 4096, wsa + OB_O + l * 64, st2);
        fin_k<<<1, 64, 0, stream>>>(st2, wsa + ON2G + l * 64, wsa + ON2B + l * 64, fi2, 64);
        comb_k<<<2048, 256, 0, stream>>>(z_buf, q_buf, fi1, fi2,
                                         wsa + OW_M1 + l * 8192, wsa + OB_M1 + l * 128,
                                         wsa + OW_M2 + l * 8192, wsa + OB_M2 + l * 64, st3);
        fin_k<<<1, 64, 0, stream>>>(st3, wsa + ON3G + l * 64, wsa + ON3B + l * 64, fi3, 64);
        bnapply_k<<<2048, 256, 0, stream>>>(z_buf, fi3, h_buf);
    }
    pool_head_k<<<128, 256, 0, stream>>>(h_buf, wsa + OW_H, wsa + OB_H, flag, d_out);
}

// Round 5
// 2169.462 us; speedup vs baseline: 7.0813x; 3.6482x over previous
//
#include <hip/hip_runtime.h>

typedef unsigned short ushort;
typedef unsigned int uint;
typedef __attribute__((ext_vector_type(8))) short short8;
typedef __attribute__((ext_vector_type(4))) float floatx4;

#define NTOT   65536
#define CH     64
#define NLAYER 4
#define NEDGE  1048576
#define EPSV   1e-5f

// staged-weight arena element offsets (order = d_in[3..32]); 2-D weights stored TRANSPOSED [n][k]
#define OW_EMB 0
#define OB_EMB 3072
#define OW_PE  3120
#define OB_PE  3376
#define OG_PEN 3392
#define OB_PEN 3408
#define OW_G1  3424
#define OB_G1  19808
#define OW_G2  20064
#define OB_G2  36448
#define OW_Q   36704
#define OB_Q   53088
#define OW_K   53344
#define OB_K   69728
#define OW_V   69984
#define OB_V   86368
#define OW_O   86624
#define OB_O   103008
#define ON1G   103264
#define ON1B   103520
#define ON2G   103776
#define ON2B   104032
#define ON3G   104288
#define ON3B   104544
#define OW_M1  104800
#define OB_M1  137568
#define OW_M2  138080
#define OB_M2  170848
#define OW_H   171104
#define OB_H   179296
#define TOTW   179424

__device__ __forceinline__ float bf2f(ushort u){ return __uint_as_float(((uint)u) << 16); }
__device__ __forceinline__ ushort f2bf(float f){
    uint u = __float_as_uint(f);
    uint r = (u + 0x7fffu + ((u >> 16) & 1u)) >> 16;
    return (ushort)r;
}
__device__ __forceinline__ float2 bfp2(uint w){
    return make_float2(__uint_as_float(w << 16), __uint_as_float(w & 0xffff0000u));
}
__device__ __forceinline__ short8 ldf(const ushort* p){ return *(const short8*)p; }
__device__ __forceinline__ floatx4 mfma16(short8 a, short8 b, floatx4 c){
    return __builtin_amdgcn_mfma_f32_16x16x32_bf16(a, b, c, 0, 0, 0);
}

// ---------------- dtype probe: 1=bf16 inputs, 0=fp32 inputs ----------------
__global__ void detect_k(const uint* __restrict__ x, int* __restrict__ flag){
    int lane = threadIdx.x;
    uint w = x[lane];
    uint e = (w >> 7) & 0xffu;
    int ok = (e >= 100u && e <= 140u) ? 1 : 0;
    unsigned long long m = __ballot(ok);
    if (lane == 0) flag[0] = (__popcll(m) >= 48) ? 1 : 0;
}

// ---------------- convert/copy weights into bf16 arena (2-D weights transposed) ----------------
struct WPtrs { const void* p[30]; };

__global__ void convall_k(WPtrs ptrs, ushort* __restrict__ dst, const int* __restrict__ flag){
    const int offs[31] = {0,3072,3120,3376,3392,3408,3424,19808,20064,36448,36704,
                          53088,53344,69728,69984,86368,86624,103008,103264,103520,
                          103776,104032,104288,104544,104800,137568,138080,170848,
                          171104,179296,179424};
    // K (input dim) and N (output dim) for transposed tensors; K=0 -> straight copy
    const int kdt[30] = {64,0,16,0,0,0, 64,0,64,0, 64,0,64,0,64,0,64,0,
                         0,0,0,0,0,0, 64,0,128,0, 64,0};
    const int ndt[30] = {48,0,16,0,0,0, 64,0,64,0, 64,0,64,0,64,0,64,0,
                         0,0,0,0,0,0, 128,0,64,0, 128,0};
    int i = blockIdx.x * blockDim.x + threadIdx.x;
    if (i >= TOTW) return;
    int s = 0;
    while (s < 29 && i >= offs[s + 1]) ++s;
    int j = i - offs[s];
    int srcj = j;
    int K = kdt[s];
    if (K > 0){
        int N = ndt[s], KN = K * N;
        int l = j / KN, r = j - l * KN;
        int n = r / K, k2 = r - n * K;
        srcj = l * KN + k2 * N + n;
    }
    if (*flag) dst[i] = ((const ushort*)ptrs.p[s])[srcj];
    else       dst[i] = f2bf(((const float*)ptrs.p[s])[srcj]);
}

// ---------------- BN stats over pe ----------------
__global__ void pe_stats_k(const void* __restrict__ peraw, const int* __restrict__ flag,
                           float* __restrict__ stats){
    int bf = *flag;
    int t = threadIdx.x;
    int c = t & 15, rb = t >> 4;
    int row0 = blockIdx.x * 256;
    float s = 0.f, ss = 0.f;
    for (int i = 0; i < 16; ++i){
        int r = row0 + rb + 16 * i;
        size_t idx = (size_t)r * 16 + c;
        float v = bf ? bf2f(((const ushort*)peraw)[idx]) : ((const float*)peraw)[idx];
        s += v; ss += v * v;
    }
    __shared__ float red[256];
    red[t] = s; __syncthreads();
    if (t < 16){ float tot = 0.f; for (int j = 0; j < 16; ++j) tot += red[t + 16 * j]; atomicAdd(&stats[t], tot); }
    __syncthreads();
    red[t] = ss; __syncthreads();
    if (t < 16){ float tot = 0.f; for (int j = 0; j < 16; ++j) tot += red[t + 16 * j]; atomicAdd(&stats[64 + t], tot); }
}

__global__ void fin_k(const float* __restrict__ stats, const ushort* __restrict__ g,
                      const ushort* __restrict__ b, float* __restrict__ fin, int nch){
    int c = threadIdx.x;
    if (c >= nch) return;
    float mu  = stats[c] * (1.f / NTOT);
    float var = stats[64 + c] * (1.f / NTOT) - mu * mu;
    float a = rsqrtf(var + EPSV) * bf2f(g[c]);
    fin[c] = a;
    fin[64 + c] = bf2f(b[c]) - mu * a;
}

// ---------------- embedding (weights transposed: W[c][k]) ----------------
__global__ void embed_k(const void* __restrict__ xraw, const void* __restrict__ peraw,
                        const int* __restrict__ flag, const ushort* __restrict__ wsa,
                        const float* __restrict__ finpe, ushort* __restrict__ hout){
    __shared__ ushort xb[64 * 64];
    __shared__ float  pen[64 * 16];
    __shared__ ushort Wes[48 * 64];
    __shared__ ushort Wps[16 * 16];
    int bf = *flag;
    int t = threadIdx.x;
    int row0 = blockIdx.x * 64;
    uint* xd = (uint*)xb;
    if (bf){
        const uint* xsrc = (const uint*)((const ushort*)xraw + (size_t)row0 * 64);
        for (int i = t; i < 2048; i += 256) xd[i] = xsrc[i];
    } else {
        const float4* xsrc = (const float4*)((const float*)xraw + (size_t)row0 * 64);
        for (int i = t; i < 1024; i += 256){
            float4 f = xsrc[i];
            xd[2 * i]     = (uint)f2bf(f.x) | ((uint)f2bf(f.y) << 16);
            xd[2 * i + 1] = (uint)f2bf(f.z) | ((uint)f2bf(f.w) << 16);
        }
    }
    for (int i = t; i < 1024; i += 256){
        int r = i >> 4, k = i & 15;
        size_t idx = (size_t)(row0 + r) * 16 + k;
        float v = bf ? bf2f(((const ushort*)peraw)[idx]) : ((const float*)peraw)[idx];
        pen[i] = v * finpe[k] + finpe[64 + k];
    }
    for (int i = t; i < 3072; i += 256) Wes[i] = wsa[OW_EMB + i];
    Wps[t] = wsa[OW_PE + (t & 255)];
    __syncthreads();
    int c = t & 63, rb = t >> 6;
    if (c < 48){
        float bias = bf2f(wsa[OB_EMB + c]);
        for (int ii = 0; ii < 16; ++ii){
            int r = rb + 4 * ii; float a = bias;
            #pragma unroll
            for (int k = 0; k < 64; ++k) a += bf2f(xb[r * 64 + k]) * bf2f(Wes[c * 64 + k]);
            hout[(size_t)(row0 + r) * 64 + c] = f2bf(a);
        }
    } else {
        int cc = c - 48;
        float bias = bf2f(wsa[OB_PE + cc]);
        for (int ii = 0; ii < 16; ++ii){
            int r = rb + 4 * ii; float a = bias;
            #pragma unroll
            for (int k = 0; k < 16; ++k) a += pen[r * 16 + k] * bf2f(Wps[cc * 16 + k]);
            hout[(size_t)(row0 + r) * 64 + c] = f2bf(a);
        }
    }
}

// ---------------- CSR build ----------------
__global__ void hist_k(const int* __restrict__ dst, int* __restrict__ cnt){
    int stride = gridDim.x * blockDim.x;
    for (int e = blockIdx.x * blockDim.x + threadIdx.x; e < NEDGE; e += stride)
        atomicAdd(&cnt[dst[e]], 1);
}

__global__ void scan_k(const int* __restrict__ cnt, int* __restrict__ offs, int* __restrict__ cur){
    int t = threadIdx.x;
    int base0 = t * 64;
    int s = 0;
    for (int i = 0; i < 64; ++i) s += cnt[base0 + i];
    __shared__ int pref[1024];
    pref[t] = s; __syncthreads();
    for (int off = 1; off < 1024; off <<= 1){
        int v = (t >= off) ? pref[t - off] : 0;
        __syncthreads();
        pref[t] += v;
        __syncthreads();
    }
    int run = pref[t] - s;
    for (int i = 0; i < 64; ++i){
        offs[base0 + i] = run;
        cur[base0 + i]  = run;
        run += cnt[base0 + i];
    }
    if (t == 1023) offs[65536] = run;
}

__global__ void scatter_k(const int* __restrict__ src, const int* __restrict__ dst,
                          int* __restrict__ cur, int* __restrict__ csr){
    int stride = gridDim.x * blockDim.x;
    for (int e = blockIdx.x * blockDim.x + threadIdx.x; e < NEDGE; e += stride){
        int p = atomicAdd(&cur[dst[e]], 1);
        csr[p] = src[e];
    }
}

// ---------------- GIN aggregate ----------------
__global__ void agg_k(const ushort* __restrict__ h, const int* __restrict__ offs,
                      const int* __restrict__ csr, ushort* __restrict__ z){
    int wave = threadIdx.x >> 6, lane = threadIdx.x & 63;
    int node = blockIdx.x * 4 + wave;
    int beg = offs[node], end = offs[node + 1];
    float s = bf2f(h[(size_t)node * CH + lane]);
    for (int i = beg; i < end; ++i){
        int sn = csr[i];
        s += bf2f(h[(size_t)sn * CH + lane]);
    }
    z[(size_t)node * CH + lane] = f2bf(s);
}

// ======== MFMA GEMM kernels: 64-row tiles, 4 waves, A/B frags = ds_read_b128 ========
// A LDS tile [64][72] bf16 (row stride 144 B, 16B-aligned); Wt LDS [n][72].
// frag: row = 16w+(l&15) (A) or nt*16+(l&15) (B); k = kstep*32 + (l>>4)*8.

// ---------------- GIN MLP: relu(z@W1+b1)@W2+b2 + h, BN1 stats ----------------
__global__ void gin_k(const ushort* __restrict__ z, const ushort* __restrict__ h,
                      const ushort* __restrict__ W1, const ushort* __restrict__ b1,
                      const ushort* __restrict__ W2, const ushort* __restrict__ b2,
                      ushort* __restrict__ out, float* __restrict__ stats){
    __shared__ __align__(16) ushort As[64 * 72];
    __shared__ __align__(16) ushort W1s[64 * 72];
    __shared__ __align__(16) ushort W2s[64 * 72];
    __shared__ __align__(16) ushort Ts[64 * 72];
    __shared__ float sb[128];
    int t = threadIdx.x;
    int row0 = blockIdx.x * 64;
    for (int i = t; i < 2048; i += 256){
        int r = i >> 5, u = i & 31;
        ((uint*)(As  + r * 72))[u] = ((const uint*)(z + (size_t)row0 * 64))[i];
        ((uint*)(W1s + r * 72))[u] = ((const uint*)W1)[i];
        ((uint*)(W2s + r * 72))[u] = ((const uint*)W2)[i];
    }
    if (t < 128) sb[t] = 0.f;
    __syncthreads();
    int w = t >> 6, l = t & 63, m = l & 15, q4 = l >> 4;
    const ushort* ap = As + (16 * w + m) * 72 + q4 * 8;
    short8 a0 = ldf(ap), a1 = ldf(ap + 32);
    floatx4 acc[4];
    #pragma unroll
    for (int nt = 0; nt < 4; ++nt){
        const ushort* bp = W1s + (nt * 16 + m) * 72 + q4 * 8;
        floatx4 c = {0.f, 0.f, 0.f, 0.f};
        c = mfma16(a0, ldf(bp), c);
        c = mfma16(a1, ldf(bp + 32), c);
        acc[nt] = c;
    }
    #pragma unroll
    for (int nt = 0; nt < 4; ++nt){
        float bv = bf2f(b1[nt * 16 + m]);
        #pragma unroll
        for (int r = 0; r < 4; ++r)
            Ts[(16 * w + q4 * 4 + r) * 72 + nt * 16 + m] = f2bf(fmaxf(acc[nt][r] + bv, 0.f));
    }
    // wave-local: reads below are the wave's own rows
    const ushort* ap2 = Ts + (16 * w + m) * 72 + q4 * 8;
    short8 t0 = ldf(ap2), t1 = ldf(ap2 + 32);
    #pragma unroll
    for (int nt = 0; nt < 4; ++nt){
        const ushort* bp = W2s + (nt * 16 + m) * 72 + q4 * 8;
        floatx4 c = {0.f, 0.f, 0.f, 0.f};
        c = mfma16(t0, ldf(bp), c);
        c = mfma16(t1, ldf(bp + 32), c);
        acc[nt] = c;
    }
    #pragma unroll
    for (int nt = 0; nt < 4; ++nt){
        float bv = bf2f(b2[nt * 16 + m]);
        float vs = 0.f, vss = 0.f;
        #pragma unroll
        for (int r = 0; r < 4; ++r){
            size_t gi = (size_t)(row0 + 16 * w + q4 * 4 + r) * 64 + nt * 16 + m;
            float val = acc[nt][r] + bv + bf2f(h[gi]);
            out[gi] = f2bf(val);
            vs += val; vss += val * val;
        }
        vs  += __shfl_xor(vs, 16, 64);  vs  += __shfl_xor(vs, 32, 64);
        vss += __shfl_xor(vss, 16, 64); vss += __shfl_xor(vss, 32, 64);
        if (q4 == 0){
            atomicAdd(&sb[nt * 16 + m], vs);
            atomicAdd(&sb[64 + nt * 16 + m], vss);
        }
    }
    __syncthreads();
    if (t < 64){
        atomicAdd(&stats[t], sb[t]);
        atomicAdd(&stats[64 + t], sb[64 + t]);
    }
}

// ---------------- fused QKV projections (MFMA) ----------------
__global__ void qkv_k(const ushort* __restrict__ h,
                      const ushort* __restrict__ Wq, const ushort* __restrict__ bq,
                      const ushort* __restrict__ Wk, const ushort* __restrict__ bk,
                      const ushort* __restrict__ Wv, const ushort* __restrict__ bv,
                      ushort* __restrict__ qo, ushort* __restrict__ ko, ushort* __restrict__ vo){
    __shared__ __align__(16) ushort As[64 * 72];
    __shared__ __align__(16) ushort Ws[3][64 * 72];
    int t = threadIdx.x;
    int row0 = blockIdx.x * 64;
    for (int i = t; i < 2048; i += 256){
        int r = i >> 5, u = i & 31;
        ((uint*)(As + r * 72))[u]    = ((const uint*)(h + (size_t)row0 * 64))[i];
        ((uint*)(Ws[0] + r * 72))[u] = ((const uint*)Wq)[i];
        ((uint*)(Ws[1] + r * 72))[u] = ((const uint*)Wk)[i];
        ((uint*)(Ws[2] + r * 72))[u] = ((const uint*)Wv)[i];
    }
    __syncthreads();
    int w = t >> 6, l = t & 63, m = l & 15, q4 = l >> 4;
    const ushort* ap = As + (16 * w + m) * 72 + q4 * 8;
    short8 a0 = ldf(ap), a1 = ldf(ap + 32);
    ushort* outs[3] = {qo, ko, vo};
    const ushort* bias[3] = {bq, bk, bv};
    #pragma unroll
    for (int o = 0; o < 3; ++o){
        #pragma unroll
        for (int nt = 0; nt < 4; ++nt){
            const ushort* bp = Ws[o] + (nt * 16 + m) * 72 + q4 * 8;
            floatx4 c = {0.f, 0.f, 0.f, 0.f};
            c = mfma16(a0, ldf(bp), c);
            c = mfma16(a1, ldf(bp + 32), c);
            float bv2 = bf2f(bias[o][nt * 16 + m]);
            #pragma unroll
            for (int r = 0; r < 4; ++r)
                outs[o][(size_t)(row0 + 16 * w + q4 * 4 + r) * 64 + nt * 16 + m] = f2bf(c[r] + bv2);
        }
    }
}

// ---------------- dense per-(graph,head) attention; thread-per-query online softmax ----------------
__global__ void attn_k(ushort* __restrict__ q, const ushort* __restrict__ k,
                       const ushort* __restrict__ v){
    __shared__ float Ks[512 * 16];
    __shared__ float Vs[512 * 16];
    int t = threadIdx.x;
    int g = blockIdx.x >> 2, head = blockIdx.x & 3;
    int base = g * 512;
    for (int i = t; i < 4096; i += 256){
        int n = i >> 3, u = i & 7;
        uint kw = ((const uint*)(k + (size_t)(base + n) * 64 + head * 16))[u];
        uint vw = ((const uint*)(v + (size_t)(base + n) * 64 + head * 16))[u];
        float2 kf = bfp2(kw), vf = bfp2(vw);
        Ks[n * 16 + 2 * u]     = kf.x;
        Ks[n * 16 + 2 * u + 1] = kf.y;
        Vs[n * 16 + 2 * u]     = vf.x;
        Vs[n * 16 + 2 * u + 1] = vf.y;
    }
    __syncthreads();
    float qa[16], qb[16], oa[16], ob[16];
    {
        const uint* qpa = (const uint*)(q + (size_t)(base + t) * 64 + head * 16);
        const uint* qpb = (const uint*)(q + (size_t)(base + t + 256) * 64 + head * 16);
        #pragma unroll
        for (int u = 0; u < 8; ++u){
            float2 fa = bfp2(qpa[u]); qa[2 * u] = fa.x; qa[2 * u + 1] = fa.y;
            float2 fb = bfp2(qpb[u]); qb[2 * u] = fb.x; qb[2 * u + 1] = fb.y;
        }
    }
    #pragma unroll
    for (int d = 0; d < 16; ++d){ oa[d] = 0.f; ob[d] = 0.f; }
    float ma = -1e30f, mb = -1e30f, la = 0.f, lb = 0.f;

    for (int j = 0; j < 512; ++j){
        const float4* kr = (const float4*)(Ks + j * 16);
        float4 k0 = kr[0], k1 = kr[1], k2 = kr[2], k3 = kr[3];
        float a0 = qa[0]*k0.x + qa[1]*k0.y + qa[2]*k0.z + qa[3]*k0.w;
        float a1 = qa[4]*k1.x + qa[5]*k1.y + qa[6]*k1.z + qa[7]*k1.w;
        float a2 = qa[8]*k2.x + qa[9]*k2.y + qa[10]*k2.z + qa[11]*k2.w;
        float a3 = qa[12]*k3.x + qa[13]*k3.y + qa[14]*k3.z + qa[15]*k3.w;
        float b0 = qb[0]*k0.x + qb[1]*k0.y + qb[2]*k0.z + qb[3]*k0.w;
        float b1 = qb[4]*k1.x + qb[5]*k1.y + qb[6]*k1.z + qb[7]*k1.w;
        float b2 = qb[8]*k2.x + qb[9]*k2.y + qb[10]*k2.z + qb[11]*k2.w;
        float b3 = qb[12]*k3.x + qb[13]*k3.y + qb[14]*k3.z + qb[15]*k3.w;
        float sa = ((a0 + a1) + (a2 + a3)) * 0.25f;
        float sb = ((b0 + b1) + (b2 + b3)) * 0.25f;
        float mna = fmaxf(ma, sa), mnb = fmaxf(mb, sb);
        float pa = __expf(sa - mna), pb = __expf(sb - mnb);
        float ca = __expf(ma - mna), cb = __expf(mb - mnb);
        ma = mna; mb = mnb;
        la = fmaf(la, ca, pa); lb = fmaf(lb, cb, pb);
        const float4* vr = (const float4*)(Vs + j * 16);
        float4 v0 = vr[0], v1 = vr[1], v2 = vr[2], v3 = vr[3];
        oa[0]  = fmaf(oa[0],  ca, pa * v0.x); oa[1]  = fmaf(oa[1],  ca, pa * v0.y);
        oa[2]  = fmaf(oa[2],  ca, pa * v0.z); oa[3]  = fmaf(oa[3],  ca, pa * v0.w);
        oa[4]  = fmaf(oa[4],  ca, pa * v1.x); oa[5]  = fmaf(oa[5],  ca, pa * v1.y);
        oa[6]  = fmaf(oa[6],  ca, pa * v1.z); oa[7]  = fmaf(oa[7],  ca, pa * v1.w);
        oa[8]  = fmaf(oa[8],  ca, pa * v2.x); oa[9]  = fmaf(oa[9],  ca, pa * v2.y);
        oa[10] = fmaf(oa[10], ca, pa * v2.z); oa[11] = fmaf(oa[11], ca, pa * v2.w);
        oa[12] = fmaf(oa[12], ca, pa * v3.x); oa[13] = fmaf(oa[13], ca, pa * v3.y);
        oa[14] = fmaf(oa[14], ca, pa * v3.z); oa[15] = fmaf(oa[15], ca, pa * v3.w);
        ob[0]  = fmaf(ob[0],  cb, pb * v0.x); ob[1]  = fmaf(ob[1],  cb, pb * v0.y);
        ob[2]  = fmaf(ob[2],  cb, pb * v0.z); ob[3]  = fmaf(ob[3],  cb, pb * v0.w);
        ob[4]  = fmaf(ob[4],  cb, pb * v1.x); ob[5]  = fmaf(ob[5],  cb, pb * v1.y);
        ob[6]  = fmaf(ob[6],  cb, pb * v1.z); ob[7]  = fmaf(ob[7],  cb, pb * v1.w);
        ob[8]  = fmaf(ob[8],  cb, pb * v2.x); ob[9]  = fmaf(ob[9],  cb, pb * v2.y);
        ob[10] = fmaf(ob[10], cb, pb * v2.z); ob[11] = fmaf(ob[11], cb, pb * v2.w);
        ob[12] = fmaf(ob[12], cb, pb * v3.x); ob[13] = fmaf(ob[13], cb, pb * v3.y);
        ob[14] = fmaf(ob[14], cb, pb * v3.z); ob[15] = fmaf(ob[15], cb, pb * v3.w);
    }
    float inva = 1.f / la, invb = 1.f / lb;
    uint* opa = (uint*)(q + (size_t)(base + t) * 64 + head * 16);
    uint* opb = (uint*)(q + (size_t)(base + t + 256) * 64 + head * 16);
    #pragma unroll
    for (int u = 0; u < 8; ++u){
        opa[u] = (uint)f2bf(oa[2 * u] * inva) | ((uint)f2bf(oa[2 * u + 1] * inva) << 16);
        opb[u] = (uint)f2bf(ob[2 * u] * invb) | ((uint)f2bf(ob[2 * u + 1] * invb) << 16);
    }
}

// ---------------- O-projection + residual + BN2 stats (MFMA, in-place on o) ----------------
__global__ void oproj_k(ushort* __restrict__ o, const ushort* __restrict__ h,
                        const ushort* __restrict__ Wo, const ushort* __restrict__ bo,
                        float* __restrict__ stats){
    __shared__ __align__(16) ushort As[64 * 72];
    __shared__ __align__(16) ushort Ws[64 * 72];
    __shared__ float sb[128];
    int t = threadIdx.x;
    int row0 = blockIdx.x * 64;
    for (int i = t; i < 2048; i += 256){
        int r = i >> 5, u = i & 31;
        ((uint*)(As + r * 72))[u] = ((const uint*)(o + (size_t)row0 * 64))[i];
        ((uint*)(Ws + r * 72))[u] = ((const uint*)Wo)[i];
    }
    if (t < 128) sb[t] = 0.f;
    __syncthreads();
    int w = t >> 6, l = t & 63, m = l & 15, q4 = l >> 4;
    const ushort* ap = As + (16 * w + m) * 72 + q4 * 8;
    short8 a0 = ldf(ap), a1 = ldf(ap + 32);
    #pragma unroll
    for (int nt = 0; nt < 4; ++nt){
        const ushort* bp = Ws + (nt * 16 + m) * 72 + q4 * 8;
        floatx4 c = {0.f, 0.f, 0.f, 0.f};
        c = mfma16(a0, ldf(bp), c);
        c = mfma16(a1, ldf(bp + 32), c);
        float bv = bf2f(bo[nt * 16 + m]);
        float vs = 0.f, vss = 0.f;
        #pragma unroll
        for (int r = 0; r < 4; ++r){
            size_t gi = (size_t)(row0 + 16 * w + q4 * 4 + r) * 64 + nt * 16 + m;
            float val = c[r] + bv + bf2f(h[gi]);
            o[gi] = f2bf(val);
            vs += val; vss += val * val;
        }
        vs  += __shfl_xor(vs, 16, 64);  vs  += __shfl_xor(vs, 32, 64);
        vss += __shfl_xor(vss, 16, 64); vss += __shfl_xor(vss, 32, 64);
        if (q4 == 0){
            atomicAdd(&sb[nt * 16 + m], vs);
            atomicAdd(&sb[64 + nt * 16 + m], vss);
        }
    }
    __syncthreads();
    if (t < 64){
        atomicAdd(&stats[t], sb[t]);
        atomicAdd(&stats[64 + t], sb[64 + t]);
    }
}

// ---------------- comb: outb = bn1(hl)+bn2(ha); out = outb + MLP(outb); BN3 stats ----------------
__global__ void comb_k(ushort* __restrict__ hlpre, const ushort* __restrict__ hapre,
                       const float* __restrict__ fin1, const float* __restrict__ fin2,
                       const ushort* __restrict__ W1, const ushort* __restrict__ b1,
                       const ushort* __restrict__ W2, const ushort* __restrict__ b2,
                       float* __restrict__ stats){
    __shared__ __align__(16) ushort Ob[64 * 72];     // bf16 outb (MFMA A)
    __shared__ float Of[64 * 64];                    // f32 outb (residual)
    __shared__ __align__(16) ushort W1s[128 * 72];
    __shared__ __align__(16) ushort Hs[64 * 136];
    __shared__ __align__(16) ushort W2s[64 * 136];
    __shared__ float sb[128];
    int t = threadIdx.x;
    int row0 = blockIdx.x * 64;
    for (int i = t; i < 2048; i += 256){
        int r = i >> 5, u = i & 31;
        size_t gi = (size_t)(row0 + r) * 32 + u;
        uint wl = ((const uint*)hlpre)[gi], wa = ((const uint*)hapre)[gi];
        int c0 = u * 2;
        float2 pl = bfp2(wl), pa = bfp2(wa);
        float v0 = pl.x * fin1[c0] + fin1[64 + c0] + pa.x * fin2[c0] + fin2[64 + c0];
        float v1 = pl.y * fin1[c0 + 1] + fin1[64 + c0 + 1] + pa.y * fin2[c0 + 1] + fin2[64 + c0 + 1];
        ((uint*)(Ob + r * 72))[u] = (uint)f2bf(v0) | ((uint)f2bf(v1) << 16);
        Of[r * 64 + c0] = v0; Of[r * 64 + c0 + 1] = v1;
    }
    for (int i = t; i < 4096; i += 256){
        int r = i >> 5, u = i & 31;
        ((uint*)(W1s + r * 72))[u] = ((const uint*)W1)[i];
        int r2 = i >> 6, u2 = i & 63;
        ((uint*)(W2s + r2 * 136))[u2] = ((const uint*)W2)[i];
    }
    if (t < 128) sb[t] = 0.f;
    __syncthreads();
    int w = t >> 6, l = t & 63, m = l & 15, q4 = l >> 4;
    const ushort* ap = Ob + (16 * w + m) * 72 + q4 * 8;
    short8 a0 = ldf(ap), a1 = ldf(ap + 32);
    // stage 1: 64 -> 128, relu
    #pragma unroll
    for (int nt = 0; nt < 8; ++nt){
        const ushort* bp = W1s + (nt * 16 + m) * 72 + q4 * 8;
        floatx4 c = {0.f, 0.f, 0.f, 0.f};
        c = mfma16(a0, ldf(bp), c);
        c = mfma16(a1, ldf(bp + 32), c);
        float bv = bf2f(b1[nt * 16 + m]);
        #pragma unroll
        for (int r = 0; r < 4; ++r)
            Hs[(16 * w + q4 * 4 + r) * 136 + nt * 16 + m] = f2bf(fmaxf(c[r] + bv, 0.f));
    }
    // stage 2: 128 -> 64 (wave-local rows of Hs)
    const ushort* ap2 = Hs + (16 * w + m) * 136 + q4 * 8;
    short8 h0 = ldf(ap2), h1 = ldf(ap2 + 32), h2 = ldf(ap2 + 64), h3 = ldf(ap2 + 96);
    #pragma unroll
    for (int nt = 0; nt < 4; ++nt){
        const ushort* bp = W2s + (nt * 16 + m) * 136 + q4 * 8;
        floatx4 c = {0.f, 0.f, 0.f, 0.f};
        c = mfma16(h0, ldf(bp), c);
        c = mfma16(h1, ldf(bp + 32), c);
        c = mfma16(h2, ldf(bp + 64), c);
        c = mfma16(h3, ldf(bp + 96), c);
        float bv = bf2f(b2[nt * 16 + m]);
        float vs = 0.f, vss = 0.f;
        #pragma unroll
        for (int r = 0; r < 4; ++r){
            int lr = 16 * w + q4 * 4 + r;
            float val = c[r] + bv + Of[lr * 64 + nt * 16 + m];
            hlpre[(size_t)(row0 + lr) * 64 + nt * 16 + m] = f2bf(val);
            vs += val; vss += val * val;
        }
        vs  += __shfl_xor(vs, 16, 64);  vs  += __shfl_xor(vs, 32, 64);
        vss += __shfl_xor(vss, 16, 64); vss += __shfl_xor(vss, 32, 64);
        if (q4 == 0){
            atomicAdd(&sb[nt * 16 + m], vs);
            atomicAdd(&sb[64 + nt * 16 + m], vss);
        }
    }
    __syncthreads();
    if (t < 64){
        atomicAdd(&stats[t], sb[t]);
        atomicAdd(&stats[64 + t], sb[64 + t]);
    }
}

__global__ void bnapply_k(const ushort* __restrict__ in, const float* __restrict__ fin,
                          ushort* __restrict__ out){
    int stride = gridDim.x * blockDim.x;
    const uint* in2 = (const uint*)in;
    uint* out2 = (uint*)out;
    for (int i = blockIdx.x * blockDim.x + threadIdx.x; i < NTOT * CH / 2; i += stride){
        uint w = in2[i];
        float2 p = bfp2(w);
        int cu = (i & 31) * 2;
        float a = p.x * fin[cu] + fin[64 + cu];
        float b = p.y * fin[cu + 1] + fin[64 + cu + 1];
        out2[i] = (uint)f2bf(a) | ((uint)f2bf(b) << 16);
    }
}

// ---------------- mean pool + head GEMM (head_w transposed [128][64]) ----------------
__global__ void pool_head_k(const ushort* __restrict__ h, const ushort* __restrict__ Wh,
                            const ushort* __restrict__ bh, const int* __restrict__ flag,
                            void* __restrict__ out){
    __shared__ float red[256];
    __shared__ float pooled[64];
    int t = threadIdx.x, g = blockIdx.x;
    int c = t & 63, rb = t >> 6;
    float s = 0.f;
    for (int ii = 0; ii < 128; ++ii){
        int r = rb + 4 * ii;
        s += bf2f(h[(size_t)(g * 512 + r) * 64 + c]);
    }
    red[t] = s; __syncthreads();
    if (t < 64) pooled[t] = (red[t] + red[64 + t] + red[128 + t] + red[192 + t]) * (1.f / 512.f);
    __syncthreads();
    if (t < 128){
        float a = bf2f(bh[t]);
        #pragma unroll
        for (int k = 0; k < 64; ++k) a += pooled[k] * bf2f(Wh[t * 64 + k]);
        if (*flag) ((ushort*)out)[(size_t)g * 128 + t] = f2bf(a);
        else       ((float*)out)[(size_t)g * 128 + t] = a;
    }
}

extern "C" void kernel_launch(void* const* d_in, const int* in_sizes, int n_in,
                              void* d_out, int out_size, void* d_ws, size_t ws_size,
                              hipStream_t stream){
    const void* x  = d_in[0];
    const void* pe = d_in[1];
    const int* eidx = (const int*)d_in[2];

    char* ws = (char*)d_ws;
    const size_t MB = 1024 * 1024;
    const size_t KB = 1024;
    ushort* h_buf = (ushort*)(ws);
    ushort* z_buf = (ushort*)(ws + 8 * MB);
    ushort* q_buf = (ushort*)(ws + 16 * MB);
    ushort* k_buf = (ushort*)(ws + 24 * MB);
    ushort* v_buf = (ushort*)(ws + 32 * MB);
    int* csr   = (int*)(ws + 40 * MB);
    int* offs  = (int*)(ws + 44 * MB);
    int* cnt   = (int*)(ws + 44 * MB + 384 * KB);
    int* cur   = (int*)(ws + 44 * MB + 640 * KB);
    float* stats = (float*)(ws + 44 * MB + 896 * KB);
    float* fin   = (float*)(ws + 44 * MB + 904 * KB);
    int*   flag  = (int*)(ws + 44 * MB + 912 * KB);
    ushort* wsa  = (ushort*)(ws + 45 * MB);

    hipMemsetAsync(stats, 0, 13 * 128 * sizeof(float), stream);
    hipMemsetAsync(cnt, 0, 65536 * sizeof(int), stream);

    detect_k<<<1, 64, 0, stream>>>((const uint*)x, flag);

    WPtrs wp;
    for (int i = 0; i < 30; ++i) wp.p[i] = d_in[3 + i];
    convall_k<<<(TOTW + 255) / 256, 256, 0, stream>>>(wp, wsa, flag);

    pe_stats_k<<<256, 256, 0, stream>>>(pe, flag, stats);
    fin_k<<<1, 64, 0, stream>>>(stats, wsa + OG_PEN, wsa + OB_PEN, fin, 16);
    embed_k<<<1024, 256, 0, stream>>>(x, pe, flag, wsa, fin, h_buf);
    hist_k<<<1024, 256, 0, stream>>>(eidx + NEDGE, cnt);
    scan_k<<<1, 1024, 0, stream>>>(cnt, offs, cur);
    scatter_k<<<1024, 256, 0, stream>>>(eidx, eidx + NEDGE, cur, csr);

    for (int l = 0; l < NLAYER; ++l){
        float* st1 = stats + (1 + 3 * l) * 128; float* fi1 = fin + (1 + 3 * l) * 128;
        float* st2 = stats + (2 + 3 * l) * 128; float* fi2 = fin + (2 + 3 * l) * 128;
        float* st3 = stats + (3 + 3 * l) * 128; float* fi3 = fin + (3 + 3 * l) * 128;

        agg_k<<<16384, 256, 0, stream>>>(h_buf, offs, csr, z_buf);
        gin_k<<<1024, 256, 0, stream>>>(z_buf, h_buf, wsa + OW_G1 + l * 4096, wsa + OB_G1 + l * 64,
                                        wsa + OW_G2 + l * 4096, wsa + OB_G2 + l * 64, z_buf, st1);
        fin_k<<<1, 64, 0, stream>>>(st1, wsa + ON1G + l * 64, wsa + ON1B + l * 64, fi1, 64);
        qkv_k<<<1024, 256, 0, stream>>>(h_buf,
                                        wsa + OW_Q + l * 4096, wsa + OB_Q + l * 64,
                                        wsa + OW_K + l * 4096, wsa + OB_K + l * 64,
                                        wsa + OW_V + l * 4096, wsa + OB_V + l * 64,
                                        q_buf, k_buf, v_buf);
        attn_k<<<512, 256, 0, stream>>>(q_buf, k_buf, v_buf);
        oproj_k<<<1024, 256, 0, stream>>>(q_buf, h_buf, wsa + OW_O + l * 4096, wsa + OB_O + l * 64, st2);
        fin_k<<<1, 64, 0, stream>>>(st2, wsa + ON2G + l * 64, wsa + ON2B + l * 64, fi2, 64);
        comb_k<<<1024, 256, 0, stream>>>(z_buf, q_buf, fi1, fi2,
                                         wsa + OW_M1 + l * 8192, wsa + OB_M1 + l * 128,
                                         wsa + OW_M2 + l * 8192, wsa + OB_M2 + l * 64, st3);
        fin_k<<<1, 64, 0, stream>>>(st3, wsa + ON3G + l * 64, wsa + ON3B + l * 64, fi3, 64);
        bnapply_k<<<2048, 256, 0, stream>>>(z_buf, fi3, h_buf);
    }
    pool_head_k<<<128, 256, 0, stream>>>(h_buf, wsa + OW_H, wsa + OB_H, flag, d_out);
}

// Round 6
// 1556.063 us; speedup vs baseline: 9.8728x; 1.3942x over previous
//
#include <hip/hip_runtime.h>

typedef unsigned short ushort;
typedef unsigned int uint;
typedef __attribute__((ext_vector_type(8))) short short8;
typedef __attribute__((ext_vector_type(4))) float floatx4;

#define NTOT   65536
#define CH     64
#define NLAYER 4
#define NEDGE  1048576
#define EPSV   1e-5f

// staged-weight arena element offsets (order = d_in[3..32]); 2-D weights stored TRANSPOSED [n][k]
#define OW_EMB 0
#define OB_EMB 3072
#define OW_PE  3120
#define OB_PE  3376
#define OG_PEN 3392
#define OB_PEN 3408
#define OW_G1  3424
#define OB_G1  19808
#define OW_G2  20064
#define OB_G2  36448
#define OW_Q   36704
#define OB_Q   53088
#define OW_K   53344
#define OB_K   69728
#define OW_V   69984
#define OB_V   86368
#define OW_O   86624
#define OB_O   103008
#define ON1G   103264
#define ON1B   103520
#define ON2G   103776
#define ON2B   104032
#define ON3G   104288
#define ON3B   104544
#define OW_M1  104800
#define OB_M1  137568
#define OW_M2  138080
#define OB_M2  170848
#define OW_H   171104
#define OB_H   179296
#define TOTW   179424

__device__ __forceinline__ float bf2f(ushort u){ return __uint_as_float(((uint)u) << 16); }
__device__ __forceinline__ ushort f2bf(float f){
    uint u = __float_as_uint(f);
    uint r = (u + 0x7fffu + ((u >> 16) & 1u)) >> 16;
    return (ushort)r;
}
__device__ __forceinline__ float2 bfp2(uint w){
    return make_float2(__uint_as_float(w << 16), __uint_as_float(w & 0xffff0000u));
}
__device__ __forceinline__ short8 ldf(const ushort* p){ return *(const short8*)p; }
__device__ __forceinline__ floatx4 mfma16(short8 a, short8 b, floatx4 c){
    return __builtin_amdgcn_mfma_f32_16x16x32_bf16(a, b, c, 0, 0, 0);
}

// ---------------- dtype probe: 1=bf16 inputs, 0=fp32 inputs ----------------
__global__ void detect_k(const uint* __restrict__ x, int* __restrict__ flag){
    int lane = threadIdx.x;
    uint w = x[lane];
    uint e = (w >> 7) & 0xffu;
    int ok = (e >= 100u && e <= 140u) ? 1 : 0;
    unsigned long long m = __ballot(ok);
    if (lane == 0) flag[0] = (__popcll(m) >= 48) ? 1 : 0;
}

// ---------------- convert/copy weights into bf16 arena (2-D weights transposed) ----------------
struct WPtrs { const void* p[30]; };

__global__ void convall_k(WPtrs ptrs, ushort* __restrict__ dst, const int* __restrict__ flag){
    const int offs[31] = {0,3072,3120,3376,3392,3408,3424,19808,20064,36448,36704,
                          53088,53344,69728,69984,86368,86624,103008,103264,103520,
                          103776,104032,104288,104544,104800,137568,138080,170848,
                          171104,179296,179424};
    const int kdt[30] = {64,0,16,0,0,0, 64,0,64,0, 64,0,64,0,64,0,64,0,
                         0,0,0,0,0,0, 64,0,128,0, 64,0};
    const int ndt[30] = {48,0,16,0,0,0, 64,0,64,0, 64,0,64,0,64,0,64,0,
                         0,0,0,0,0,0, 128,0,64,0, 128,0};
    int i = blockIdx.x * blockDim.x + threadIdx.x;
    if (i >= TOTW) return;
    int s = 0;
    while (s < 29 && i >= offs[s + 1]) ++s;
    int j = i - offs[s];
    int srcj = j;
    int K = kdt[s];
    if (K > 0){
        int N = ndt[s], KN = K * N;
        int l = j / KN, r = j - l * KN;
        int n = r / K, k2 = r - n * K;
        srcj = l * KN + k2 * N + n;
    }
    if (*flag) dst[i] = ((const ushort*)ptrs.p[s])[srcj];
    else       dst[i] = f2bf(((const float*)ptrs.p[s])[srcj]);
}

// ---------------- BN stats over pe ----------------
__global__ void pe_stats_k(const void* __restrict__ peraw, const int* __restrict__ flag,
                           float* __restrict__ stats){
    int bf = *flag;
    int t = threadIdx.x;
    int c = t & 15, rb = t >> 4;
    int row0 = blockIdx.x * 256;
    float s = 0.f, ss = 0.f;
    for (int i = 0; i < 16; ++i){
        int r = row0 + rb + 16 * i;
        size_t idx = (size_t)r * 16 + c;
        float v = bf ? bf2f(((const ushort*)peraw)[idx]) : ((const float*)peraw)[idx];
        s += v; ss += v * v;
    }
    __shared__ float red[256];
    red[t] = s; __syncthreads();
    if (t < 16){ float tot = 0.f; for (int j = 0; j < 16; ++j) tot += red[t + 16 * j]; atomicAdd(&stats[t], tot); }
    __syncthreads();
    red[t] = ss; __syncthreads();
    if (t < 16){ float tot = 0.f; for (int j = 0; j < 16; ++j) tot += red[t + 16 * j]; atomicAdd(&stats[64 + t], tot); }
}

__global__ void fin_k(const float* __restrict__ stats, const ushort* __restrict__ g,
                      const ushort* __restrict__ b, float* __restrict__ fin, int nch){
    int c = threadIdx.x;
    if (c >= nch) return;
    float mu  = stats[c] * (1.f / NTOT);
    float var = stats[64 + c] * (1.f / NTOT) - mu * mu;
    float a = rsqrtf(var + EPSV) * bf2f(g[c]);
    fin[c] = a;
    fin[64 + c] = bf2f(b[c]) - mu * a;
}

// merged finalize for two BN stat sets (BN1 + BN2) in one launch
__global__ void fin2_k(const float* __restrict__ st1, const ushort* __restrict__ g1,
                       const ushort* __restrict__ b1, float* __restrict__ f1,
                       const float* __restrict__ st2, const ushort* __restrict__ g2,
                       const ushort* __restrict__ b2, float* __restrict__ f2){
    int t = threadIdx.x;            // 128
    int c = t & 63;
    const float* st = (t < 64) ? st1 : st2;
    const ushort* g = (t < 64) ? g1 : g2;
    const ushort* b = (t < 64) ? b1 : b2;
    float* f = (t < 64) ? f1 : f2;
    float mu  = st[c] * (1.f / NTOT);
    float var = st[64 + c] * (1.f / NTOT) - mu * mu;
    float a = rsqrtf(var + EPSV) * bf2f(g[c]);
    f[c] = a;
    f[64 + c] = bf2f(b[c]) - mu * a;
}

// ---------------- embedding (weights transposed: W[c][k]) ----------------
__global__ void embed_k(const void* __restrict__ xraw, const void* __restrict__ peraw,
                        const int* __restrict__ flag, const ushort* __restrict__ wsa,
                        const float* __restrict__ finpe, ushort* __restrict__ hout){
    __shared__ ushort xb[64 * 64];
    __shared__ float  pen[64 * 16];
    __shared__ ushort Wes[48 * 64];
    __shared__ ushort Wps[16 * 16];
    int bf = *flag;
    int t = threadIdx.x;
    int row0 = blockIdx.x * 64;
    uint* xd = (uint*)xb;
    if (bf){
        const uint* xsrc = (const uint*)((const ushort*)xraw + (size_t)row0 * 64);
        for (int i = t; i < 2048; i += 256) xd[i] = xsrc[i];
    } else {
        const float4* xsrc = (const float4*)((const float*)xraw + (size_t)row0 * 64);
        for (int i = t; i < 1024; i += 256){
            float4 f = xsrc[i];
            xd[2 * i]     = (uint)f2bf(f.x) | ((uint)f2bf(f.y) << 16);
            xd[2 * i + 1] = (uint)f2bf(f.z) | ((uint)f2bf(f.w) << 16);
        }
    }
    for (int i = t; i < 1024; i += 256){
        int r = i >> 4, k = i & 15;
        size_t idx = (size_t)(row0 + r) * 16 + k;
        float v = bf ? bf2f(((const ushort*)peraw)[idx]) : ((const float*)peraw)[idx];
        pen[i] = v * finpe[k] + finpe[64 + k];
    }
    for (int i = t; i < 3072; i += 256) Wes[i] = wsa[OW_EMB + i];
    Wps[t] = wsa[OW_PE + (t & 255)];
    __syncthreads();
    int c = t & 63, rb = t >> 6;
    if (c < 48){
        float bias = bf2f(wsa[OB_EMB + c]);
        for (int ii = 0; ii < 16; ++ii){
            int r = rb + 4 * ii; float a = bias;
            #pragma unroll
            for (int k = 0; k < 64; ++k) a += bf2f(xb[r * 64 + k]) * bf2f(Wes[c * 64 + k]);
            hout[(size_t)(row0 + r) * 64 + c] = f2bf(a);
        }
    } else {
        int cc = c - 48;
        float bias = bf2f(wsa[OB_PE + cc]);
        for (int ii = 0; ii < 16; ++ii){
            int r = rb + 4 * ii; float a = bias;
            #pragma unroll
            for (int k = 0; k < 16; ++k) a += pen[r * 16 + k] * bf2f(Wps[cc * 16 + k]);
            hout[(size_t)(row0 + r) * 64 + c] = f2bf(a);
        }
    }
}

// ---------------- CSR build ----------------
__global__ void hist_k(const int* __restrict__ dst, int* __restrict__ cnt){
    int stride = gridDim.x * blockDim.x;
    for (int e = blockIdx.x * blockDim.x + threadIdx.x; e < NEDGE; e += stride)
        atomicAdd(&cnt[dst[e]], 1);
}

__global__ void scan_k(const int* __restrict__ cnt, int* __restrict__ offs, int* __restrict__ cur){
    int t = threadIdx.x;
    int base0 = t * 64;
    int s = 0;
    for (int i = 0; i < 64; ++i) s += cnt[base0 + i];
    __shared__ int pref[1024];
    pref[t] = s; __syncthreads();
    for (int off = 1; off < 1024; off <<= 1){
        int v = (t >= off) ? pref[t - off] : 0;
        __syncthreads();
        pref[t] += v;
        __syncthreads();
    }
    int run = pref[t] - s;
    for (int i = 0; i < 64; ++i){
        offs[base0 + i] = run;
        cur[base0 + i]  = run;
        run += cnt[base0 + i];
    }
    if (t == 1023) offs[65536] = run;
}

__global__ void scatter_k(const int* __restrict__ src, const int* __restrict__ dst,
                          int* __restrict__ cur, int* __restrict__ csr){
    int stride = gridDim.x * blockDim.x;
    for (int e = blockIdx.x * blockDim.x + threadIdx.x; e < NEDGE; e += stride){
        int p = atomicAdd(&cur[dst[e]], 1);
        csr[p] = src[e];
    }
}

// ---------------- GIN aggregate ----------------
__global__ void agg_k(const ushort* __restrict__ h, const int* __restrict__ offs,
                      const int* __restrict__ csr, ushort* __restrict__ z){
    int wave = threadIdx.x >> 6, lane = threadIdx.x & 63;
    int node = blockIdx.x * 4 + wave;
    int beg = offs[node], end = offs[node + 1];
    float s = bf2f(h[(size_t)node * CH + lane]);
    for (int i = beg; i < end; ++i){
        int sn = csr[i];
        s += bf2f(h[(size_t)sn * CH + lane]);
    }
    z[(size_t)node * CH + lane] = f2bf(s);
}

// ======== MFMA GEMM kernels (64-row tiles, 4 waves) ========

__global__ void gin_k(const ushort* __restrict__ z, const ushort* __restrict__ h,
                      const ushort* __restrict__ W1, const ushort* __restrict__ b1,
                      const ushort* __restrict__ W2, const ushort* __restrict__ b2,
                      ushort* __restrict__ out, float* __restrict__ stats){
    __shared__ __align__(16) ushort As[64 * 72];
    __shared__ __align__(16) ushort W1s[64 * 72];
    __shared__ __align__(16) ushort W2s[64 * 72];
    __shared__ __align__(16) ushort Ts[64 * 72];
    __shared__ float sb[128];
    int t = threadIdx.x;
    int row0 = blockIdx.x * 64;
    for (int i = t; i < 2048; i += 256){
        int r = i >> 5, u = i & 31;
        ((uint*)(As  + r * 72))[u] = ((const uint*)(z + (size_t)row0 * 64))[i];
        ((uint*)(W1s + r * 72))[u] = ((const uint*)W1)[i];
        ((uint*)(W2s + r * 72))[u] = ((const uint*)W2)[i];
    }
    if (t < 128) sb[t] = 0.f;
    __syncthreads();
    int w = t >> 6, l = t & 63, m = l & 15, q4 = l >> 4;
    const ushort* ap = As + (16 * w + m) * 72 + q4 * 8;
    short8 a0 = ldf(ap), a1 = ldf(ap + 32);
    floatx4 acc[4];
    #pragma unroll
    for (int nt = 0; nt < 4; ++nt){
        const ushort* bp = W1s + (nt * 16 + m) * 72 + q4 * 8;
        floatx4 c = {0.f, 0.f, 0.f, 0.f};
        c = mfma16(a0, ldf(bp), c);
        c = mfma16(a1, ldf(bp + 32), c);
        acc[nt] = c;
    }
    #pragma unroll
    for (int nt = 0; nt < 4; ++nt){
        float bv = bf2f(b1[nt * 16 + m]);
        #pragma unroll
        for (int r = 0; r < 4; ++r)
            Ts[(16 * w + q4 * 4 + r) * 72 + nt * 16 + m] = f2bf(fmaxf(acc[nt][r] + bv, 0.f));
    }
    const ushort* ap2 = Ts + (16 * w + m) * 72 + q4 * 8;
    short8 t0 = ldf(ap2), t1 = ldf(ap2 + 32);
    #pragma unroll
    for (int nt = 0; nt < 4; ++nt){
        const ushort* bp = W2s + (nt * 16 + m) * 72 + q4 * 8;
        floatx4 c = {0.f, 0.f, 0.f, 0.f};
        c = mfma16(t0, ldf(bp), c);
        c = mfma16(t1, ldf(bp + 32), c);
        acc[nt] = c;
    }
    #pragma unroll
    for (int nt = 0; nt < 4; ++nt){
        float bv = bf2f(b2[nt * 16 + m]);
        float vs = 0.f, vss = 0.f;
        #pragma unroll
        for (int r = 0; r < 4; ++r){
            size_t gi = (size_t)(row0 + 16 * w + q4 * 4 + r) * 64 + nt * 16 + m;
            float val = acc[nt][r] + bv + bf2f(h[gi]);
            out[gi] = f2bf(val);
            vs += val; vss += val * val;
        }
        vs  += __shfl_xor(vs, 16, 64);  vs  += __shfl_xor(vs, 32, 64);
        vss += __shfl_xor(vss, 16, 64); vss += __shfl_xor(vss, 32, 64);
        if (q4 == 0){
            atomicAdd(&sb[nt * 16 + m], vs);
            atomicAdd(&sb[64 + nt * 16 + m], vss);
        }
    }
    __syncthreads();
    if (t < 64){
        atomicAdd(&stats[t], sb[t]);
        atomicAdd(&stats[64 + t], sb[64 + t]);
    }
}

__global__ void qkv_k(const ushort* __restrict__ h,
                      const ushort* __restrict__ Wq, const ushort* __restrict__ bq,
                      const ushort* __restrict__ Wk, const ushort* __restrict__ bk,
                      const ushort* __restrict__ Wv, const ushort* __restrict__ bv,
                      ushort* __restrict__ qo, ushort* __restrict__ ko, ushort* __restrict__ vo){
    __shared__ __align__(16) ushort As[64 * 72];
    __shared__ __align__(16) ushort Ws[3][64 * 72];
    int t = threadIdx.x;
    int row0 = blockIdx.x * 64;
    for (int i = t; i < 2048; i += 256){
        int r = i >> 5, u = i & 31;
        ((uint*)(As + r * 72))[u]    = ((const uint*)(h + (size_t)row0 * 64))[i];
        ((uint*)(Ws[0] + r * 72))[u] = ((const uint*)Wq)[i];
        ((uint*)(Ws[1] + r * 72))[u] = ((const uint*)Wk)[i];
        ((uint*)(Ws[2] + r * 72))[u] = ((const uint*)Wv)[i];
    }
    __syncthreads();
    int w = t >> 6, l = t & 63, m = l & 15, q4 = l >> 4;
    const ushort* ap = As + (16 * w + m) * 72 + q4 * 8;
    short8 a0 = ldf(ap), a1 = ldf(ap + 32);
    ushort* outs[3] = {qo, ko, vo};
    const ushort* bias[3] = {bq, bk, bv};
    #pragma unroll
    for (int o = 0; o < 3; ++o){
        #pragma unroll
        for (int nt = 0; nt < 4; ++nt){
            const ushort* bp = Ws[o] + (nt * 16 + m) * 72 + q4 * 8;
            floatx4 c = {0.f, 0.f, 0.f, 0.f};
            c = mfma16(a0, ldf(bp), c);
            c = mfma16(a1, ldf(bp + 32), c);
            float bv2 = bf2f(bias[o][nt * 16 + m]);
            #pragma unroll
            for (int r = 0; r < 4; ++r)
                outs[o][(size_t)(row0 + 16 * w + q4 * 4 + r) * 64 + nt * 16 + m] = f2bf(c[r] + bv2);
        }
    }
}

// ---------------- MFMA flash attention: block=(graph,head), 4 waves × 8 q-tiles ----------------
// S-MFMA: A=K-tile (m=key, permuted rows), B=Q (n=query) -> P frag lands directly in
// B-operand layout for PV-MFMA (A=V^T). dh=16 padded to K=32 with zero frags (quads 2,3).
__global__ void attn_k(ushort* __restrict__ q, const ushort* __restrict__ k,
                       const ushort* __restrict__ v){
    __shared__ __align__(16) ushort Ks[512 * 24];   // K prescaled by 0.25; cols 0-15 valid
    __shared__ __align__(16) ushort Vt[16 * 536];   // V transposed [d][key]
    int t = threadIdx.x;
    int g = blockIdx.x >> 2, head = blockIdx.x & 3;
    int base = g * 512;
    for (int i = t; i < 4096; i += 256){
        int n = i >> 3, u = i & 7;
        uint kw = ((const uint*)(k + (size_t)(base + n) * 64 + head * 16))[u];
        uint vw = ((const uint*)(v + (size_t)(base + n) * 64 + head * 16))[u];
        float2 kf = bfp2(kw);
        Ks[n * 24 + 2 * u]     = f2bf(kf.x * 0.25f);
        Ks[n * 24 + 2 * u + 1] = f2bf(kf.y * 0.25f);
        Vt[(2 * u) * 536 + n]     = (ushort)(vw & 0xffffu);
        Vt[(2 * u + 1) * 536 + n] = (ushort)(vw >> 16);
    }
    __syncthreads();
    int w = t >> 6, l = t & 63, m16 = l & 15, quad = l >> 4;
    const short8 zero8 = {0, 0, 0, 0, 0, 0, 0, 0};
    const floatx4 zf4 = {0.f, 0.f, 0.f, 0.f};
    // permuted A-row -> key mapping: key1(m) = (m/4)*8 + m%4 ; key2 = key1 + 4
    int key1 = ((m16 >> 2) << 3) + (m16 & 3);

    for (int qi = 0; qi < 8; ++qi){
        int qt = w * 8 + qi;
        int qrow = base + qt * 16 + m16;
        short8 qf = zero8;
        if (quad < 2) qf = ldf(q + (size_t)qrow * 64 + head * 16 + quad * 8);
        floatx4 O = zf4;
        float mm = -1e30f, ll = 0.f;
        for (int kg = 0; kg < 16; ++kg){
            int kb = kg * 32;
            short8 af1 = zero8, af2 = zero8;
            if (quad < 2){
                const ushort* kp = Ks + (kb + key1) * 24 + quad * 8;
                af1 = ldf(kp);
                af2 = ldf(kp + 96);          // +4 key rows
            }
            floatx4 s1 = mfma16(af1, qf, zf4);
            floatx4 s2 = mfma16(af2, qf, zf4);
            float tm = fmaxf(fmaxf(fmaxf(s1[0], s1[1]), fmaxf(s1[2], s1[3])),
                             fmaxf(fmaxf(s2[0], s2[1]), fmaxf(s2[2], s2[3])));
            tm = fmaxf(tm, __shfl_xor(tm, 16, 64));
            tm = fmaxf(tm, __shfl_xor(tm, 32, 64));
            float mn = fmaxf(mm, tm);
            float c = __expf(mm - mn);
            float p0 = __expf(s1[0] - mn), p1 = __expf(s1[1] - mn);
            float p2 = __expf(s1[2] - mn), p3 = __expf(s1[3] - mn);
            float p4 = __expf(s2[0] - mn), p5 = __expf(s2[1] - mn);
            float p6 = __expf(s2[2] - mn), p7 = __expf(s2[3] - mn);
            float ts = ((p0 + p1) + (p2 + p3)) + ((p4 + p5) + (p6 + p7));
            ts += __shfl_xor(ts, 16, 64);
            ts += __shfl_xor(ts, 32, 64);
            ll = ll * c + ts;
            mm = mn;
            short8 pf;
            pf[0] = (short)f2bf(p0); pf[1] = (short)f2bf(p1);
            pf[2] = (short)f2bf(p2); pf[3] = (short)f2bf(p3);
            pf[4] = (short)f2bf(p4); pf[5] = (short)f2bf(p5);
            pf[6] = (short)f2bf(p6); pf[7] = (short)f2bf(p7);
            short8 vf = ldf(Vt + m16 * 536 + kb + quad * 8);
            O[0] *= c; O[1] *= c; O[2] *= c; O[3] *= c;
            O = mfma16(vf, pf, O);
        }
        float inv = 1.f / ll;
        uint lo = (uint)f2bf(O[0] * inv) | ((uint)f2bf(O[1] * inv) << 16);
        uint hi = (uint)f2bf(O[2] * inv) | ((uint)f2bf(O[3] * inv) << 16);
        uint2 st = {lo, hi};
        *(uint2*)(q + (size_t)qrow * 64 + head * 16 + quad * 4) = st;
    }
}

__global__ void oproj_k(ushort* __restrict__ o, const ushort* __restrict__ h,
                        const ushort* __restrict__ Wo, const ushort* __restrict__ bo,
                        float* __restrict__ stats){
    __shared__ __align__(16) ushort As[64 * 72];
    __shared__ __align__(16) ushort Ws[64 * 72];
    __shared__ float sb[128];
    int t = threadIdx.x;
    int row0 = blockIdx.x * 64;
    for (int i = t; i < 2048; i += 256){
        int r = i >> 5, u = i & 31;
        ((uint*)(As + r * 72))[u] = ((const uint*)(o + (size_t)row0 * 64))[i];
        ((uint*)(Ws + r * 72))[u] = ((const uint*)Wo)[i];
    }
    if (t < 128) sb[t] = 0.f;
    __syncthreads();
    int w = t >> 6, l = t & 63, m = l & 15, q4 = l >> 4;
    const ushort* ap = As + (16 * w + m) * 72 + q4 * 8;
    short8 a0 = ldf(ap), a1 = ldf(ap + 32);
    #pragma unroll
    for (int nt = 0; nt < 4; ++nt){
        const ushort* bp = Ws + (nt * 16 + m) * 72 + q4 * 8;
        floatx4 c = {0.f, 0.f, 0.f, 0.f};
        c = mfma16(a0, ldf(bp), c);
        c = mfma16(a1, ldf(bp + 32), c);
        float bv = bf2f(bo[nt * 16 + m]);
        float vs = 0.f, vss = 0.f;
        #pragma unroll
        for (int r = 0; r < 4; ++r){
            size_t gi = (size_t)(row0 + 16 * w + q4 * 4 + r) * 64 + nt * 16 + m;
            float val = c[r] + bv + bf2f(h[gi]);
            o[gi] = f2bf(val);
            vs += val; vss += val * val;
        }
        vs  += __shfl_xor(vs, 16, 64);  vs  += __shfl_xor(vs, 32, 64);
        vss += __shfl_xor(vss, 16, 64); vss += __shfl_xor(vss, 32, 64);
        if (q4 == 0){
            atomicAdd(&sb[nt * 16 + m], vs);
            atomicAdd(&sb[64 + nt * 16 + m], vss);
        }
    }
    __syncthreads();
    if (t < 64){
        atomicAdd(&stats[t], sb[t]);
        atomicAdd(&stats[64 + t], sb[64 + t]);
    }
}

__global__ void comb_k(ushort* __restrict__ hlpre, const ushort* __restrict__ hapre,
                       const float* __restrict__ fin1, const float* __restrict__ fin2,
                       const ushort* __restrict__ W1, const ushort* __restrict__ b1,
                       const ushort* __restrict__ W2, const ushort* __restrict__ b2,
                       float* __restrict__ stats){
    __shared__ __align__(16) ushort Ob[64 * 72];
    __shared__ float Of[64 * 64];
    __shared__ __align__(16) ushort W1s[128 * 72];
    __shared__ __align__(16) ushort Hs[64 * 136];
    __shared__ __align__(16) ushort W2s[64 * 136];
    __shared__ float sb[128];
    int t = threadIdx.x;
    int row0 = blockIdx.x * 64;
    for (int i = t; i < 2048; i += 256){
        int r = i >> 5, u = i & 31;
        size_t gi = (size_t)(row0 + r) * 32 + u;
        uint wl = ((const uint*)hlpre)[gi], wa = ((const uint*)hapre)[gi];
        int c0 = u * 2;
        float2 pl = bfp2(wl), pa = bfp2(wa);
        float v0 = pl.x * fin1[c0] + fin1[64 + c0] + pa.x * fin2[c0] + fin2[64 + c0];
        float v1 = pl.y * fin1[c0 + 1] + fin1[64 + c0 + 1] + pa.y * fin2[c0 + 1] + fin2[64 + c0 + 1];
        ((uint*)(Ob + r * 72))[u] = (uint)f2bf(v0) | ((uint)f2bf(v1) << 16);
        Of[r * 64 + c0] = v0; Of[r * 64 + c0 + 1] = v1;
    }
    for (int i = t; i < 4096; i += 256){
        int r = i >> 5, u = i & 31;
        ((uint*)(W1s + r * 72))[u] = ((const uint*)W1)[i];
        int r2 = i >> 6, u2 = i & 63;
        ((uint*)(W2s + r2 * 136))[u2] = ((const uint*)W2)[i];
    }
    if (t < 128) sb[t] = 0.f;
    __syncthreads();
    int w = t >> 6, l = t & 63, m = l & 15, q4 = l >> 4;
    const ushort* ap = Ob + (16 * w + m) * 72 + q4 * 8;
    short8 a0 = ldf(ap), a1 = ldf(ap + 32);
    #pragma unroll
    for (int nt = 0; nt < 8; ++nt){
        const ushort* bp = W1s + (nt * 16 + m) * 72 + q4 * 8;
        floatx4 c = {0.f, 0.f, 0.f, 0.f};
        c = mfma16(a0, ldf(bp), c);
        c = mfma16(a1, ldf(bp + 32), c);
        float bv = bf2f(b1[nt * 16 + m]);
        #pragma unroll
        for (int r = 0; r < 4; ++r)
            Hs[(16 * w + q4 * 4 + r) * 136 + nt * 16 + m] = f2bf(fmaxf(c[r] + bv, 0.f));
    }
    const ushort* ap2 = Hs + (16 * w + m) * 136 + q4 * 8;
    short8 h0 = ldf(ap2), h1 = ldf(ap2 + 32), h2 = ldf(ap2 + 64), h3 = ldf(ap2 + 96);
    #pragma unroll
    for (int nt = 0; nt < 4; ++nt){
        const ushort* bp = W2s + (nt * 16 + m) * 136 + q4 * 8;
        floatx4 c = {0.f, 0.f, 0.f, 0.f};
        c = mfma16(h0, ldf(bp), c);
        c = mfma16(h1, ldf(bp + 32), c);
        c = mfma16(h2, ldf(bp + 64), c);
        c = mfma16(h3, ldf(bp + 96), c);
        float bv = bf2f(b2[nt * 16 + m]);
        float vs = 0.f, vss = 0.f;
        #pragma unroll
        for (int r = 0; r < 4; ++r){
            int lr = 16 * w + q4 * 4 + r;
            float val = c[r] + bv + Of[lr * 64 + nt * 16 + m];
            hlpre[(size_t)(row0 + lr) * 64 + nt * 16 + m] = f2bf(val);
            vs += val; vss += val * val;
        }
        vs  += __shfl_xor(vs, 16, 64);  vs  += __shfl_xor(vs, 32, 64);
        vss += __shfl_xor(vss, 16, 64); vss += __shfl_xor(vss, 32, 64);
        if (q4 == 0){
            atomicAdd(&sb[nt * 16 + m], vs);
            atomicAdd(&sb[64 + nt * 16 + m], vss);
        }
    }
    __syncthreads();
    if (t < 64){
        atomicAdd(&stats[t], sb[t]);
        atomicAdd(&stats[64 + t], sb[64 + t]);
    }
}

__global__ void bnapply_k(const ushort* __restrict__ in, const float* __restrict__ fin,
                          ushort* __restrict__ out){
    int stride = gridDim.x * blockDim.x;
    const uint* in2 = (const uint*)in;
    uint* out2 = (uint*)out;
    for (int i = blockIdx.x * blockDim.x + threadIdx.x; i < NTOT * CH / 2; i += stride){
        uint w = in2[i];
        float2 p = bfp2(w);
        int cu = (i & 31) * 2;
        float a = p.x * fin[cu] + fin[64 + cu];
        float b = p.y * fin[cu + 1] + fin[64 + cu + 1];
        out2[i] = (uint)f2bf(a) | ((uint)f2bf(b) << 16);
    }
}

__global__ void pool_head_k(const ushort* __restrict__ h, const ushort* __restrict__ Wh,
                            const ushort* __restrict__ bh, const int* __restrict__ flag,
                            void* __restrict__ out){
    __shared__ float red[256];
    __shared__ float pooled[64];
    int t = threadIdx.x, g = blockIdx.x;
    int c = t & 63, rb = t >> 6;
    float s = 0.f;
    for (int ii = 0; ii < 128; ++ii){
        int r = rb + 4 * ii;
        s += bf2f(h[(size_t)(g * 512 + r) * 64 + c]);
    }
    red[t] = s; __syncthreads();
    if (t < 64) pooled[t] = (red[t] + red[64 + t] + red[128 + t] + red[192 + t]) * (1.f / 512.f);
    __syncthreads();
    if (t < 128){
        float a = bf2f(bh[t]);
        #pragma unroll
        for (int k = 0; k < 64; ++k) a += pooled[k] * bf2f(Wh[t * 64 + k]);
        if (*flag) ((ushort*)out)[(size_t)g * 128 + t] = f2bf(a);
        else       ((float*)out)[(size_t)g * 128 + t] = a;
    }
}

extern "C" void kernel_launch(void* const* d_in, const int* in_sizes, int n_in,
                              void* d_out, int out_size, void* d_ws, size_t ws_size,
                              hipStream_t stream){
    const void* x  = d_in[0];
    const void* pe = d_in[1];
    const int* eidx = (const int*)d_in[2];

    char* ws = (char*)d_ws;
    const size_t MB = 1024 * 1024;
    const size_t KB = 1024;
    ushort* h_buf = (ushort*)(ws);
    ushort* z_buf = (ushort*)(ws + 8 * MB);
    ushort* q_buf = (ushort*)(ws + 16 * MB);
    ushort* k_buf = (ushort*)(ws + 24 * MB);
    ushort* v_buf = (ushort*)(ws + 32 * MB);
    int* csr   = (int*)(ws + 40 * MB);
    int* offs  = (int*)(ws + 44 * MB);
    int* cnt   = (int*)(ws + 44 * MB + 384 * KB);
    int* cur   = (int*)(ws + 44 * MB + 640 * KB);
    float* stats = (float*)(ws + 44 * MB + 896 * KB);
    float* fin   = (float*)(ws + 44 * MB + 904 * KB);
    int*   flag  = (int*)(ws + 44 * MB + 912 * KB);
    ushort* wsa  = (ushort*)(ws + 45 * MB);

    hipMemsetAsync(stats, 0, 13 * 128 * sizeof(float), stream);
    hipMemsetAsync(cnt, 0, 65536 * sizeof(int), stream);

    detect_k<<<1, 64, 0, stream>>>((const uint*)x, flag);

    WPtrs wp;
    for (int i = 0; i < 30; ++i) wp.p[i] = d_in[3 + i];
    convall_k<<<(TOTW + 255) / 256, 256, 0, stream>>>(wp, wsa, flag);

    pe_stats_k<<<256, 256, 0, stream>>>(pe, flag, stats);
    fin_k<<<1, 64, 0, stream>>>(stats, wsa + OG_PEN, wsa + OB_PEN, fin, 16);
    embed_k<<<1024, 256, 0, stream>>>(x, pe, flag, wsa, fin, h_buf);
    hist_k<<<1024, 256, 0, stream>>>(eidx + NEDGE, cnt);
    scan_k<<<1, 1024, 0, stream>>>(cnt, offs, cur);
    scatter_k<<<1024, 256, 0, stream>>>(eidx, eidx + NEDGE, cur, csr);

    for (int l = 0; l < NLAYER; ++l){
        float* st1 = stats + (1 + 3 * l) * 128; float* fi1 = fin + (1 + 3 * l) * 128;
        float* st2 = stats + (2 + 3 * l) * 128; float* fi2 = fin + (2 + 3 * l) * 128;
        float* st3 = stats + (3 + 3 * l) * 128; float* fi3 = fin + (3 + 3 * l) * 128;

        agg_k<<<16384, 256, 0, stream>>>(h_buf, offs, csr, z_buf);
        gin_k<<<1024, 256, 0, stream>>>(z_buf, h_buf, wsa + OW_G1 + l * 4096, wsa + OB_G1 + l * 64,
                                        wsa + OW_G2 + l * 4096, wsa + OB_G2 + l * 64, z_buf, st1);
        qkv_k<<<1024, 256, 0, stream>>>(h_buf,
                                        wsa + OW_Q + l * 4096, wsa + OB_Q + l * 64,
                                        wsa + OW_K + l * 4096, wsa + OB_K + l * 64,
                                        wsa + OW_V + l * 4096, wsa + OB_V + l * 64,
                                        q_buf, k_buf, v_buf);
        attn_k<<<512, 256, 0, stream>>>(q_buf, k_buf, v_buf);
        oproj_k<<<1024, 256, 0, stream>>>(q_buf, h_buf, wsa + OW_O + l * 4096, wsa + OB_O + l * 64, st2);
        fin2_k<<<1, 128, 0, stream>>>(st1, wsa + ON1G + l * 64, wsa + ON1B + l * 64, fi1,
                                      st2, wsa + ON2G + l * 64, wsa + ON2B + l * 64, fi2);
        comb_k<<<1024, 256, 0, stream>>>(z_buf, q_buf, fi1, fi2,
                                         wsa + OW_M1 + l * 8192, wsa + OB_M1 + l * 128,
                                         wsa + OW_M2 + l * 8192, wsa + OB_M2 + l * 64, st3);
        fin_k<<<1, 64, 0, stream>>>(st3, wsa + ON3G + l * 64, wsa + ON3B + l * 64, fi3, 64);
        bnapply_k<<<2048, 256, 0, stream>>>(z_buf, fi3, h_buf);
    }
    pool_head_k<<<128, 256, 0, stream>>>(h_buf, wsa + OW_H, wsa + OB_H, flag, d_out);
}

// Round 7
// 1269.156 us; speedup vs baseline: 12.1046x; 1.2261x over previous
//
#include <hip/hip_runtime.h>

typedef unsigned short ushort;
typedef unsigned int uint;
typedef __attribute__((ext_vector_type(8))) short short8;
typedef __attribute__((ext_vector_type(4))) float floatx4;

#define NTOT   65536
#define CH     64
#define NLAYER 4
#define NEDGE  1048576
#define EPSV   1e-5f

// staged-weight arena element offsets (order = d_in[3..32]); 2-D weights stored TRANSPOSED [n][k]
#define OW_EMB 0
#define OB_EMB 3072
#define OW_PE  3120
#define OB_PE  3376
#define OG_PEN 3392
#define OB_PEN 3408
#define OW_G1  3424
#define OB_G1  19808
#define OW_G2  20064
#define OB_G2  36448
#define OW_Q   36704
#define OB_Q   53088
#define OW_K   53344
#define OB_K   69728
#define OW_V   69984
#define OB_V   86368
#define OW_O   86624
#define OB_O   103008
#define ON1G   103264
#define ON1B   103520
#define ON2G   103776
#define ON2B   104032
#define ON3G   104288
#define ON3B   104544
#define OW_M1  104800
#define OB_M1  137568
#define OW_M2  138080
#define OB_M2  170848
#define OW_H   171104
#define OB_H   179296
#define TOTW   179424

__device__ __forceinline__ float bf2f(ushort u){ return __uint_as_float(((uint)u) << 16); }
__device__ __forceinline__ ushort f2bf(float f){
    uint u = __float_as_uint(f);
    uint r = (u + 0x7fffu + ((u >> 16) & 1u)) >> 16;
    return (ushort)r;
}
__device__ __forceinline__ float2 bfp2(uint w){
    return make_float2(__uint_as_float(w << 16), __uint_as_float(w & 0xffff0000u));
}
__device__ __forceinline__ short8 ldf(const ushort* p){ return *(const short8*)p; }
__device__ __forceinline__ floatx4 mfma16(short8 a, short8 b, floatx4 c){
    return __builtin_amdgcn_mfma_f32_16x16x32_bf16(a, b, c, 0, 0, 0);
}

// ---------------- dtype probe: 1=bf16 inputs, 0=fp32 inputs ----------------
__global__ void detect_k(const uint* __restrict__ x, int* __restrict__ flag){
    int lane = threadIdx.x;
    uint w = x[lane];
    uint e = (w >> 7) & 0xffu;
    int ok = (e >= 100u && e <= 140u) ? 1 : 0;
    unsigned long long m = __ballot(ok);
    if (lane == 0) flag[0] = (__popcll(m) >= 48) ? 1 : 0;
}

// ---------------- convert/copy weights into bf16 arena (2-D weights transposed) ----------------
struct WPtrs { const void* p[30]; };

__global__ void convall_k(WPtrs ptrs, ushort* __restrict__ dst, const int* __restrict__ flag){
    const int offs[31] = {0,3072,3120,3376,3392,3408,3424,19808,20064,36448,36704,
                          53088,53344,69728,69984,86368,86624,103008,103264,103520,
                          103776,104032,104288,104544,104800,137568,138080,170848,
                          171104,179296,179424};
    const int kdt[30] = {64,0,16,0,0,0, 64,0,64,0, 64,0,64,0,64,0,64,0,
                         0,0,0,0,0,0, 64,0,128,0, 64,0};
    const int ndt[30] = {48,0,16,0,0,0, 64,0,64,0, 64,0,64,0,64,0,64,0,
                         0,0,0,0,0,0, 128,0,64,0, 128,0};
    int i = blockIdx.x * blockDim.x + threadIdx.x;
    if (i >= TOTW) return;
    int s = 0;
    while (s < 29 && i >= offs[s + 1]) ++s;
    int j = i - offs[s];
    int srcj = j;
    int K = kdt[s];
    if (K > 0){
        int N = ndt[s], KN = K * N;
        int l = j / KN, r = j - l * KN;
        int n = r / K, k2 = r - n * K;
        srcj = l * KN + k2 * N + n;
    }
    if (*flag) dst[i] = ((const ushort*)ptrs.p[s])[srcj];
    else       dst[i] = f2bf(((const float*)ptrs.p[s])[srcj]);
}

// ---------------- BN stats over pe ----------------
__global__ void pe_stats_k(const void* __restrict__ peraw, const int* __restrict__ flag,
                           float* __restrict__ stats){
    int bf = *flag;
    int t = threadIdx.x;
    int c = t & 15, rb = t >> 4;
    int row0 = blockIdx.x * 256;
    float s = 0.f, ss = 0.f;
    for (int i = 0; i < 16; ++i){
        int r = row0 + rb + 16 * i;
        size_t idx = (size_t)r * 16 + c;
        float v = bf ? bf2f(((const ushort*)peraw)[idx]) : ((const float*)peraw)[idx];
        s += v; ss += v * v;
    }
    __shared__ float red[256];
    red[t] = s; __syncthreads();
    if (t < 16){ float tot = 0.f; for (int j = 0; j < 16; ++j) tot += red[t + 16 * j]; atomicAdd(&stats[t], tot); }
    __syncthreads();
    red[t] = ss; __syncthreads();
    if (t < 16){ float tot = 0.f; for (int j = 0; j < 16; ++j) tot += red[t + 16 * j]; atomicAdd(&stats[64 + t], tot); }
}

__global__ void fin_k(const float* __restrict__ stats, const ushort* __restrict__ g,
                      const ushort* __restrict__ b, float* __restrict__ fin, int nch){
    int c = threadIdx.x;
    if (c >= nch) return;
    float mu  = stats[c] * (1.f / NTOT);
    float var = stats[64 + c] * (1.f / NTOT) - mu * mu;
    float a = rsqrtf(var + EPSV) * bf2f(g[c]);
    fin[c] = a;
    fin[64 + c] = bf2f(b[c]) - mu * a;
}

// ---------------- embedding, MFMA version ----------------
// out cols 0-47 = x@Wemb (K=64), cols 48-63 = pe_n@Wpe (K=16, zero-frag quads 2-3)
__global__ void embed_k(const void* __restrict__ xraw, const void* __restrict__ peraw,
                        const int* __restrict__ flag, const ushort* __restrict__ wsa,
                        const float* __restrict__ finpe, ushort* __restrict__ hout){
    __shared__ __align__(16) ushort xb[64 * 72];
    __shared__ __align__(16) ushort pen[64 * 24];
    __shared__ __align__(16) ushort Wes[48 * 72];
    __shared__ __align__(16) ushort Wps[16 * 24];
    int bf = *flag;
    int t = threadIdx.x;
    int row0 = blockIdx.x * 64;
    if (bf){
        const uint* xsrc = (const uint*)((const ushort*)xraw + (size_t)row0 * 64);
        for (int i = t; i < 2048; i += 256){
            int r = i >> 5, u = i & 31;
            ((uint*)(xb + r * 72))[u] = xsrc[i];
        }
    } else {
        const float4* xsrc = (const float4*)((const float*)xraw + (size_t)row0 * 64);
        for (int i = t; i < 1024; i += 256){
            int r = i >> 4, u = i & 15;
            float4 f = xsrc[i];
            ((uint*)(xb + r * 72))[2 * u]     = (uint)f2bf(f.x) | ((uint)f2bf(f.y) << 16);
            ((uint*)(xb + r * 72))[2 * u + 1] = (uint)f2bf(f.z) | ((uint)f2bf(f.w) << 16);
        }
    }
    for (int i = t; i < 1024; i += 256){
        int r = i >> 4, k = i & 15;
        size_t idx = (size_t)(row0 + r) * 16 + k;
        float v = bf ? bf2f(((const ushort*)peraw)[idx]) : ((const float*)peraw)[idx];
        pen[r * 24 + k] = f2bf(v * finpe[k] + finpe[64 + k]);
    }
    for (int i = t; i < 1536; i += 256){
        int r = i >> 5, u = i & 31;
        ((uint*)(Wes + r * 72))[u] = ((const uint*)(wsa + OW_EMB))[i];
    }
    {
        int r = t >> 4, k = t & 15;
        Wps[r * 24 + k] = wsa[OW_PE + t];
    }
    __syncthreads();
    int w = t >> 6, l = t & 63, m = l & 15, quad = l >> 4;
    const short8 zero8 = {0, 0, 0, 0, 0, 0, 0, 0};
    const floatx4 zf4 = {0.f, 0.f, 0.f, 0.f};
    const ushort* ap = xb + (16 * w + m) * 72 + quad * 8;
    short8 a0 = ldf(ap), a1 = ldf(ap + 32);
    short8 ape = (quad < 2) ? ldf(pen + (16 * w + m) * 24 + quad * 8) : zero8;
    #pragma unroll
    for (int nt = 0; nt < 4; ++nt){
        floatx4 c = zf4;
        float bias;
        if (nt < 3){
            const ushort* bp = Wes + (nt * 16 + m) * 72 + quad * 8;
            c = mfma16(a0, ldf(bp), c);
            c = mfma16(a1, ldf(bp + 32), c);
            bias = bf2f(wsa[OB_EMB + nt * 16 + m]);
        } else {
            short8 bpe = (quad < 2) ? ldf(Wps + m * 24 + quad * 8) : zero8;
            c = mfma16(ape, bpe, c);
            bias = bf2f(wsa[OB_PE + m]);
        }
        #pragma unroll
        for (int r = 0; r < 4; ++r)
            hout[(size_t)(row0 + 16 * w + quad * 4 + r) * 64 + nt * 16 + m] = f2bf(c[r] + bias);
    }
}

// ---------------- CSR build ----------------
__global__ void hist_k(const int* __restrict__ dst, int* __restrict__ cnt){
    int stride = gridDim.x * blockDim.x;
    for (int e = blockIdx.x * blockDim.x + threadIdx.x; e < NEDGE; e += stride)
        atomicAdd(&cnt[dst[e]], 1);
}

__global__ void scan_k(const int* __restrict__ cnt, int* __restrict__ offs, int* __restrict__ cur){
    int t = threadIdx.x;
    int base0 = t * 64;
    int s = 0;
    for (int i = 0; i < 64; ++i) s += cnt[base0 + i];
    __shared__ int pref[1024];
    pref[t] = s; __syncthreads();
    for (int off = 1; off < 1024; off <<= 1){
        int v = (t >= off) ? pref[t - off] : 0;
        __syncthreads();
        pref[t] += v;
        __syncthreads();
    }
    int run = pref[t] - s;
    for (int i = 0; i < 64; ++i){
        offs[base0 + i] = run;
        cur[base0 + i]  = run;
        run += cnt[base0 + i];
    }
    if (t == 1023) offs[65536] = run;
}

__global__ void scatter_k(const int* __restrict__ src, const int* __restrict__ dst,
                          int* __restrict__ cur, int* __restrict__ csr){
    int stride = gridDim.x * blockDim.x;
    for (int e = blockIdx.x * blockDim.x + threadIdx.x; e < NEDGE; e += stride){
        int p = atomicAdd(&cur[dst[e]], 1);
        csr[p] = src[e];
    }
}

// ---------------- GIN aggregate: 2 nodes/wave, uint (2-channel) lanes ----------------
__global__ void agg_k(const ushort* __restrict__ h, const int* __restrict__ offs,
                      const int* __restrict__ csr, ushort* __restrict__ z){
    int w = threadIdx.x >> 6, l = threadIdx.x & 63;
    int node = blockIdx.x * 8 + w * 2 + (l >> 5);
    int c2 = l & 31;
    const uint* hp = (const uint*)h;
    int beg = offs[node], end = offs[node + 1];
    float2 s = bfp2(hp[(size_t)node * 32 + c2]);
    for (int i = beg; i < end; ++i){
        int sn = csr[i];
        float2 p = bfp2(hp[(size_t)sn * 32 + c2]);
        s.x += p.x; s.y += p.y;
    }
    ((uint*)z)[(size_t)node * 32 + c2] = (uint)f2bf(s.x) | ((uint)f2bf(s.y) << 16);
}

// ======== fused GIN-MLP + QKV (shared h-tile), 64-row tiles, 4 waves ========
__global__ void ginqkv_k(const ushort* __restrict__ z, const ushort* __restrict__ h,
                         const ushort* __restrict__ W1, const ushort* __restrict__ b1,
                         const ushort* __restrict__ W2, const ushort* __restrict__ b2,
                         const ushort* __restrict__ Wq, const ushort* __restrict__ bq,
                         const ushort* __restrict__ Wk, const ushort* __restrict__ bk,
                         const ushort* __restrict__ Wv, const ushort* __restrict__ bv,
                         ushort* __restrict__ zout, ushort* __restrict__ qo,
                         ushort* __restrict__ ko, ushort* __restrict__ vo,
                         float* __restrict__ stats){
    __shared__ __align__(16) ushort As[64 * 72];   // z tile; relu(T) overwrites wave-local rows
    __shared__ __align__(16) ushort Hs[64 * 72];
    __shared__ __align__(16) ushort W1s[64 * 72];
    __shared__ __align__(16) ushort W2s[64 * 72];
    __shared__ __align__(16) ushort Wqs[64 * 72];
    __shared__ __align__(16) ushort Wks[64 * 72];
    __shared__ __align__(16) ushort Wvs[64 * 72];
    __shared__ float sb[128];
    int t = threadIdx.x;
    int row0 = blockIdx.x * 64;
    for (int i = t; i < 2048; i += 256){
        int r = i >> 5, u = i & 31;
        ((uint*)(As  + r * 72))[u] = ((const uint*)(z + (size_t)row0 * 64))[i];
        ((uint*)(Hs  + r * 72))[u] = ((const uint*)(h + (size_t)row0 * 64))[i];
        ((uint*)(W1s + r * 72))[u] = ((const uint*)W1)[i];
        ((uint*)(W2s + r * 72))[u] = ((const uint*)W2)[i];
        ((uint*)(Wqs + r * 72))[u] = ((const uint*)Wq)[i];
        ((uint*)(Wks + r * 72))[u] = ((const uint*)Wk)[i];
        ((uint*)(Wvs + r * 72))[u] = ((const uint*)Wv)[i];
    }
    if (t < 128) sb[t] = 0.f;
    __syncthreads();
    int w = t >> 6, l = t & 63, m = l & 15, q4 = l >> 4;
    const ushort* ap = As + (16 * w + m) * 72 + q4 * 8;
    short8 a0 = ldf(ap), a1 = ldf(ap + 32);
    const ushort* hpp = Hs + (16 * w + m) * 72 + q4 * 8;
    short8 h0 = ldf(hpp), h1 = ldf(hpp + 32);
    floatx4 acc[4];
    // GIN stage 1
    #pragma unroll
    for (int nt = 0; nt < 4; ++nt){
        const ushort* bp = W1s + (nt * 16 + m) * 72 + q4 * 8;
        floatx4 c = {0.f, 0.f, 0.f, 0.f};
        c = mfma16(a0, ldf(bp), c);
        c = mfma16(a1, ldf(bp + 32), c);
        acc[nt] = c;
    }
    #pragma unroll
    for (int nt = 0; nt < 4; ++nt){
        float bv = bf2f(b1[nt * 16 + m]);
        #pragma unroll
        for (int r = 0; r < 4; ++r)
            As[(16 * w + q4 * 4 + r) * 72 + nt * 16 + m] = f2bf(fmaxf(acc[nt][r] + bv, 0.f));
    }
    // GIN stage 2 (wave-local rows of As)
    const ushort* ap2 = As + (16 * w + m) * 72 + q4 * 8;
    short8 t0 = ldf(ap2), t1 = ldf(ap2 + 32);
    #pragma unroll
    for (int nt = 0; nt < 4; ++nt){
        const ushort* bp = W2s + (nt * 16 + m) * 72 + q4 * 8;
        floatx4 c = {0.f, 0.f, 0.f, 0.f};
        c = mfma16(t0, ldf(bp), c);
        c = mfma16(t1, ldf(bp + 32), c);
        float bv = bf2f(b2[nt * 16 + m]);
        float vs = 0.f, vss = 0.f;
        #pragma unroll
        for (int r = 0; r < 4; ++r){
            int lr = 16 * w + q4 * 4 + r;
            float val = c[r] + bv + bf2f(Hs[lr * 72 + nt * 16 + m]);
            zout[(size_t)(row0 + lr) * 64 + nt * 16 + m] = f2bf(val);
            vs += val; vss += val * val;
        }
        vs  += __shfl_xor(vs, 16, 64);  vs  += __shfl_xor(vs, 32, 64);
        vss += __shfl_xor(vss, 16, 64); vss += __shfl_xor(vss, 32, 64);
        if (q4 == 0){
            atomicAdd(&sb[nt * 16 + m], vs);
            atomicAdd(&sb[64 + nt * 16 + m], vss);
        }
    }
    // QKV from h fragments
    ushort* outs[3] = {qo, ko, vo};
    const ushort* bias[3] = {bq, bk, bv};
    const ushort* wmats[3] = {Wqs, Wks, Wvs};
    #pragma unroll
    for (int o = 0; o < 3; ++o){
        #pragma unroll
        for (int nt = 0; nt < 4; ++nt){
            const ushort* bp = wmats[o] + (nt * 16 + m) * 72 + q4 * 8;
            floatx4 c = {0.f, 0.f, 0.f, 0.f};
            c = mfma16(h0, ldf(bp), c);
            c = mfma16(h1, ldf(bp + 32), c);
            float bv2 = bf2f(bias[o][nt * 16 + m]);
            #pragma unroll
            for (int r = 0; r < 4; ++r)
                outs[o][(size_t)(row0 + 16 * w + q4 * 4 + r) * 64 + nt * 16 + m] = f2bf(c[r] + bv2);
        }
    }
    __syncthreads();
    if (t < 64){
        atomicAdd(&stats[t], sb[t]);
        atomicAdd(&stats[64 + t], sb[64 + t]);
    }
}

// ---------------- MFMA flash attention (unchanged) ----------------
__global__ void attn_k(ushort* __restrict__ q, const ushort* __restrict__ k,
                       const ushort* __restrict__ v){
    __shared__ __align__(16) ushort Ks[512 * 24];
    __shared__ __align__(16) ushort Vt[16 * 536];
    int t = threadIdx.x;
    int g = blockIdx.x >> 2, head = blockIdx.x & 3;
    int base = g * 512;
    for (int i = t; i < 4096; i += 256){
        int n = i >> 3, u = i & 7;
        uint kw = ((const uint*)(k + (size_t)(base + n) * 64 + head * 16))[u];
        uint vw = ((const uint*)(v + (size_t)(base + n) * 64 + head * 16))[u];
        float2 kf = bfp2(kw);
        Ks[n * 24 + 2 * u]     = f2bf(kf.x * 0.25f);
        Ks[n * 24 + 2 * u + 1] = f2bf(kf.y * 0.25f);
        Vt[(2 * u) * 536 + n]     = (ushort)(vw & 0xffffu);
        Vt[(2 * u + 1) * 536 + n] = (ushort)(vw >> 16);
    }
    __syncthreads();
    int w = t >> 6, l = t & 63, m16 = l & 15, quad = l >> 4;
    const short8 zero8 = {0, 0, 0, 0, 0, 0, 0, 0};
    const floatx4 zf4 = {0.f, 0.f, 0.f, 0.f};
    int key1 = ((m16 >> 2) << 3) + (m16 & 3);

    for (int qi = 0; qi < 8; ++qi){
        int qt = w * 8 + qi;
        int qrow = base + qt * 16 + m16;
        short8 qf = zero8;
        if (quad < 2) qf = ldf(q + (size_t)qrow * 64 + head * 16 + quad * 8);
        floatx4 O = zf4;
        float mm = -1e30f, ll = 0.f;
        for (int kg = 0; kg < 16; ++kg){
            int kb = kg * 32;
            short8 af1 = zero8, af2 = zero8;
            if (quad < 2){
                const ushort* kp = Ks + (kb + key1) * 24 + quad * 8;
                af1 = ldf(kp);
                af2 = ldf(kp + 96);
            }
            floatx4 s1 = mfma16(af1, qf, zf4);
            floatx4 s2 = mfma16(af2, qf, zf4);
            float tm = fmaxf(fmaxf(fmaxf(s1[0], s1[1]), fmaxf(s1[2], s1[3])),
                             fmaxf(fmaxf(s2[0], s2[1]), fmaxf(s2[2], s2[3])));
            tm = fmaxf(tm, __shfl_xor(tm, 16, 64));
            tm = fmaxf(tm, __shfl_xor(tm, 32, 64));
            float mn = fmaxf(mm, tm);
            float c = __expf(mm - mn);
            float p0 = __expf(s1[0] - mn), p1 = __expf(s1[1] - mn);
            float p2 = __expf(s1[2] - mn), p3 = __expf(s1[3] - mn);
            float p4 = __expf(s2[0] - mn), p5 = __expf(s2[1] - mn);
            float p6 = __expf(s2[2] - mn), p7 = __expf(s2[3] - mn);
            float ts = ((p0 + p1) + (p2 + p3)) + ((p4 + p5) + (p6 + p7));
            ts += __shfl_xor(ts, 16, 64);
            ts += __shfl_xor(ts, 32, 64);
            ll = ll * c + ts;
            mm = mn;
            short8 pf;
            pf[0] = (short)f2bf(p0); pf[1] = (short)f2bf(p1);
            pf[2] = (short)f2bf(p2); pf[3] = (short)f2bf(p3);
            pf[4] = (short)f2bf(p4); pf[5] = (short)f2bf(p5);
            pf[6] = (short)f2bf(p6); pf[7] = (short)f2bf(p7);
            short8 vf = ldf(Vt + m16 * 536 + kb + quad * 8);
            O[0] *= c; O[1] *= c; O[2] *= c; O[3] *= c;
            O = mfma16(vf, pf, O);
        }
        float inv = 1.f / ll;
        uint lo = (uint)f2bf(O[0] * inv) | ((uint)f2bf(O[1] * inv) << 16);
        uint hi = (uint)f2bf(O[2] * inv) | ((uint)f2bf(O[3] * inv) << 16);
        uint2 st = {lo, hi};
        *(uint2*)(q + (size_t)qrow * 64 + head * 16 + quad * 4) = st;
    }
}

__global__ void oproj_k(ushort* __restrict__ o, const ushort* __restrict__ h,
                        const ushort* __restrict__ Wo, const ushort* __restrict__ bo,
                        float* __restrict__ stats){
    __shared__ __align__(16) ushort As[64 * 72];
    __shared__ __align__(16) ushort Ws[64 * 72];
    __shared__ float sb[128];
    int t = threadIdx.x;
    int row0 = blockIdx.x * 64;
    for (int i = t; i < 2048; i += 256){
        int r = i >> 5, u = i & 31;
        ((uint*)(As + r * 72))[u] = ((const uint*)(o + (size_t)row0 * 64))[i];
        ((uint*)(Ws + r * 72))[u] = ((const uint*)Wo)[i];
    }
    if (t < 128) sb[t] = 0.f;
    __syncthreads();
    int w = t >> 6, l = t & 63, m = l & 15, q4 = l >> 4;
    const ushort* ap = As + (16 * w + m) * 72 + q4 * 8;
    short8 a0 = ldf(ap), a1 = ldf(ap + 32);
    #pragma unroll
    for (int nt = 0; nt < 4; ++nt){
        const ushort* bp = Ws + (nt * 16 + m) * 72 + q4 * 8;
        floatx4 c = {0.f, 0.f, 0.f, 0.f};
        c = mfma16(a0, ldf(bp), c);
        c = mfma16(a1, ldf(bp + 32), c);
        float bv = bf2f(bo[nt * 16 + m]);
        float vs = 0.f, vss = 0.f;
        #pragma unroll
        for (int r = 0; r < 4; ++r){
            size_t gi = (size_t)(row0 + 16 * w + q4 * 4 + r) * 64 + nt * 16 + m;
            float val = c[r] + bv + bf2f(h[gi]);
            o[gi] = f2bf(val);
            vs += val; vss += val * val;
        }
        vs  += __shfl_xor(vs, 16, 64);  vs  += __shfl_xor(vs, 32, 64);
        vss += __shfl_xor(vss, 16, 64); vss += __shfl_xor(vss, 32, 64);
        if (q4 == 0){
            atomicAdd(&sb[nt * 16 + m], vs);
            atomicAdd(&sb[64 + nt * 16 + m], vss);
        }
    }
    __syncthreads();
    if (t < 64){
        atomicAdd(&stats[t], sb[t]);
        atomicAdd(&stats[64 + t], sb[64 + t]);
    }
}

// ---------------- comb: folds fin(BN1)+fin(BN2) into prologue ----------------
__global__ void comb_k(ushort* __restrict__ hlpre, const ushort* __restrict__ hapre,
                       const float* __restrict__ st1, const ushort* __restrict__ n1g,
                       const ushort* __restrict__ n1b,
                       const float* __restrict__ st2, const ushort* __restrict__ n2g,
                       const ushort* __restrict__ n2b,
                       const ushort* __restrict__ W1, const ushort* __restrict__ b1,
                       const ushort* __restrict__ W2, const ushort* __restrict__ b2,
                       float* __restrict__ stats){
    __shared__ __align__(16) ushort Ob[64 * 72];
    __shared__ float Of[64 * 64];
    __shared__ __align__(16) ushort W1s[128 * 72];
    __shared__ __align__(16) ushort Hs[64 * 136];
    __shared__ __align__(16) ushort W2s[64 * 136];
    __shared__ float sb[128];
    __shared__ float sf1[128], sf2[128];
    int t = threadIdx.x;
    int row0 = blockIdx.x * 64;
    if (t < 128){
        const float* st = (t < 64) ? st1 : st2;
        const ushort* g = (t < 64) ? n1g : n2g;
        const ushort* b = (t < 64) ? n1b : n2b;
        float* f = (t < 64) ? sf1 : sf2;
        int c = t & 63;
        float mu  = st[c] * (1.f / NTOT);
        float var = st[64 + c] * (1.f / NTOT) - mu * mu;
        float a = rsqrtf(var + EPSV) * bf2f(g[c]);
        f[c] = a;
        f[64 + c] = bf2f(b[c]) - mu * a;
        sb[t] = 0.f;
    }
    __syncthreads();
    for (int i = t; i < 2048; i += 256){
        int r = i >> 5, u = i & 31;
        size_t gi = (size_t)(row0 + r) * 32 + u;
        uint wl = ((const uint*)hlpre)[gi], wa = ((const uint*)hapre)[gi];
        int c0 = u * 2;
        float2 pl = bfp2(wl), pa = bfp2(wa);
        float v0 = pl.x * sf1[c0] + sf1[64 + c0] + pa.x * sf2[c0] + sf2[64 + c0];
        float v1 = pl.y * sf1[c0 + 1] + sf1[64 + c0 + 1] + pa.y * sf2[c0 + 1] + sf2[64 + c0 + 1];
        ((uint*)(Ob + r * 72))[u] = (uint)f2bf(v0) | ((uint)f2bf(v1) << 16);
        Of[r * 64 + c0] = v0; Of[r * 64 + c0 + 1] = v1;
    }
    for (int i = t; i < 4096; i += 256){
        int r = i >> 5, u = i & 31;
        ((uint*)(W1s + r * 72))[u] = ((const uint*)W1)[i];
        int r2 = i >> 6, u2 = i & 63;
        ((uint*)(W2s + r2 * 136))[u2] = ((const uint*)W2)[i];
    }
    __syncthreads();
    int w = t >> 6, l = t & 63, m = l & 15, q4 = l >> 4;
    const ushort* ap = Ob + (16 * w + m) * 72 + q4 * 8;
    short8 a0 = ldf(ap), a1 = ldf(ap + 32);
    #pragma unroll
    for (int nt = 0; nt < 8; ++nt){
        const ushort* bp = W1s + (nt * 16 + m) * 72 + q4 * 8;
        floatx4 c = {0.f, 0.f, 0.f, 0.f};
        c = mfma16(a0, ldf(bp), c);
        c = mfma16(a1, ldf(bp + 32), c);
        float bv = bf2f(b1[nt * 16 + m]);
        #pragma unroll
        for (int r = 0; r < 4; ++r)
            Hs[(16 * w + q4 * 4 + r) * 136 + nt * 16 + m] = f2bf(fmaxf(c[r] + bv, 0.f));
    }
    const ushort* ap2 = Hs + (16 * w + m) * 136 + q4 * 8;
    short8 h0 = ldf(ap2), h1 = ldf(ap2 + 32), h2 = ldf(ap2 + 64), h3 = ldf(ap2 + 96);
    #pragma unroll
    for (int nt = 0; nt < 4; ++nt){
        const ushort* bp = W2s + (nt * 16 + m) * 136 + q4 * 8;
        floatx4 c = {0.f, 0.f, 0.f, 0.f};
        c = mfma16(h0, ldf(bp), c);
        c = mfma16(h1, ldf(bp + 32), c);
        c = mfma16(h2, ldf(bp + 64), c);
        c = mfma16(h3, ldf(bp + 96), c);
        float bv = bf2f(b2[nt * 16 + m]);
        float vs = 0.f, vss = 0.f;
        #pragma unroll
        for (int r = 0; r < 4; ++r){
            int lr = 16 * w + q4 * 4 + r;
            float val = c[r] + bv + Of[lr * 64 + nt * 16 + m];
            hlpre[(size_t)(row0 + lr) * 64 + nt * 16 + m] = f2bf(val);
            vs += val; vss += val * val;
        }
        vs  += __shfl_xor(vs, 16, 64);  vs  += __shfl_xor(vs, 32, 64);
        vss += __shfl_xor(vss, 16, 64); vss += __shfl_xor(vss, 32, 64);
        if (q4 == 0){
            atomicAdd(&sb[nt * 16 + m], vs);
            atomicAdd(&sb[64 + nt * 16 + m], vss);
        }
    }
    __syncthreads();
    if (t < 64){
        atomicAdd(&stats[t], sb[t]);
        atomicAdd(&stats[64 + t], sb[64 + t]);
    }
}

// ---------------- BN3 apply: folds fin(BN3) into prologue ----------------
__global__ void bnapply_k(const ushort* __restrict__ in, const float* __restrict__ st3,
                          const ushort* __restrict__ g3, const ushort* __restrict__ b3,
                          ushort* __restrict__ out){
    __shared__ float sf[128];
    int t = threadIdx.x;
    if (t < 64){
        float mu  = st3[t] * (1.f / NTOT);
        float var = st3[64 + t] * (1.f / NTOT) - mu * mu;
        float a = rsqrtf(var + EPSV) * bf2f(g3[t]);
        sf[t] = a;
        sf[64 + t] = bf2f(b3[t]) - mu * a;
    }
    __syncthreads();
    int stride = gridDim.x * blockDim.x;
    const uint* in2 = (const uint*)in;
    uint* out2 = (uint*)out;
    for (int i = blockIdx.x * blockDim.x + t; i < NTOT * CH / 2; i += stride){
        uint w = in2[i];
        float2 p = bfp2(w);
        int cu = (i & 31) * 2;
        float a = p.x * sf[cu] + sf[64 + cu];
        float b = p.y * sf[cu + 1] + sf[64 + cu + 1];
        out2[i] = (uint)f2bf(a) | ((uint)f2bf(b) << 16);
    }
}

__global__ void pool_head_k(const ushort* __restrict__ h, const ushort* __restrict__ Wh,
                            const ushort* __restrict__ bh, const int* __restrict__ flag,
                            void* __restrict__ out){
    __shared__ float red[256];
    __shared__ float pooled[64];
    int t = threadIdx.x, g = blockIdx.x;
    int c = t & 63, rb = t >> 6;
    float s = 0.f;
    for (int ii = 0; ii < 128; ++ii){
        int r = rb + 4 * ii;
        s += bf2f(h[(size_t)(g * 512 + r) * 64 + c]);
    }
    red[t] = s; __syncthreads();
    if (t < 64) pooled[t] = (red[t] + red[64 + t] + red[128 + t] + red[192 + t]) * (1.f / 512.f);
    __syncthreads();
    if (t < 128){
        float a = bf2f(bh[t]);
        #pragma unroll
        for (int k = 0; k < 64; ++k) a += pooled[k] * bf2f(Wh[t * 64 + k]);
        if (*flag) ((ushort*)out)[(size_t)g * 128 + t] = f2bf(a);
        else       ((float*)out)[(size_t)g * 128 + t] = a;
    }
}

extern "C" void kernel_launch(void* const* d_in, const int* in_sizes, int n_in,
                              void* d_out, int out_size, void* d_ws, size_t ws_size,
                              hipStream_t stream){
    const void* x  = d_in[0];
    const void* pe = d_in[1];
    const int* eidx = (const int*)d_in[2];

    char* ws = (char*)d_ws;
    const size_t MB = 1024 * 1024;
    const size_t KB = 1024;
    ushort* h_buf = (ushort*)(ws);
    ushort* z_buf = (ushort*)(ws + 8 * MB);
    ushort* q_buf = (ushort*)(ws + 16 * MB);
    ushort* k_buf = (ushort*)(ws + 24 * MB);
    ushort* v_buf = (ushort*)(ws + 32 * MB);
    int* csr   = (int*)(ws + 40 * MB);
    int* offs  = (int*)(ws + 44 * MB);
    int* cnt   = (int*)(ws + 44 * MB + 384 * KB);
    int* cur   = (int*)(ws + 44 * MB + 640 * KB);
    float* stats = (float*)(ws + 44 * MB + 896 * KB);
    float* fin   = (float*)(ws + 44 * MB + 904 * KB);
    int*   flag  = (int*)(ws + 44 * MB + 912 * KB);
    ushort* wsa  = (ushort*)(ws + 45 * MB);

    hipMemsetAsync(stats, 0, 13 * 128 * sizeof(float), stream);
    hipMemsetAsync(cnt, 0, 65536 * sizeof(int), stream);

    detect_k<<<1, 64, 0, stream>>>((const uint*)x, flag);

    WPtrs wp;
    for (int i = 0; i < 30; ++i) wp.p[i] = d_in[3 + i];
    convall_k<<<(TOTW + 255) / 256, 256, 0, stream>>>(wp, wsa, flag);

    pe_stats_k<<<256, 256, 0, stream>>>(pe, flag, stats);
    fin_k<<<1, 64, 0, stream>>>(stats, wsa + OG_PEN, wsa + OB_PEN, fin, 16);
    embed_k<<<1024, 256, 0, stream>>>(x, pe, flag, wsa, fin, h_buf);
    hist_k<<<1024, 256, 0, stream>>>(eidx + NEDGE, cnt);
    scan_k<<<1, 1024, 0, stream>>>(cnt, offs, cur);
    scatter_k<<<1024, 256, 0, stream>>>(eidx, eidx + NEDGE, cur, csr);

    for (int l = 0; l < NLAYER; ++l){
        float* st1 = stats + (1 + 3 * l) * 128;
        float* st2 = stats + (2 + 3 * l) * 128;
        float* st3 = stats + (3 + 3 * l) * 128;

        agg_k<<<8192, 256, 0, stream>>>(h_buf, offs, csr, z_buf);
        ginqkv_k<<<1024, 256, 0, stream>>>(z_buf, h_buf,
                                           wsa + OW_G1 + l * 4096, wsa + OB_G1 + l * 64,
                                           wsa + OW_G2 + l * 4096, wsa + OB_G2 + l * 64,
                                           wsa + OW_Q + l * 4096, wsa + OB_Q + l * 64,
                                           wsa + OW_K + l * 4096, wsa + OB_K + l * 64,
                                           wsa + OW_V + l * 4096, wsa + OB_V + l * 64,
                                           z_buf, q_buf, k_buf, v_buf, st1);
        attn_k<<<512, 256, 0, stream>>>(q_buf, k_buf, v_buf);
        oproj_k<<<1024, 256, 0, stream>>>(q_buf, h_buf, wsa + OW_O + l * 4096,
                                          wsa + OB_O + l * 64, st2);
        comb_k<<<1024, 256, 0, stream>>>(z_buf, q_buf,
                                         st1, wsa + ON1G + l * 64, wsa + ON1B + l * 64,
                                         st2, wsa + ON2G + l * 64, wsa + ON2B + l * 64,
                                         wsa + OW_M1 + l * 8192, wsa + OB_M1 + l * 128,
                                         wsa + OW_M2 + l * 8192, wsa + OB_M2 + l * 64, st3);
        bnapply_k<<<2048, 256, 0, stream>>>(z_buf, st3, wsa + ON3G + l * 64,
                                            wsa + ON3B + l * 64, h_buf);
    }
    pool_head_k<<<128, 256, 0, stream>>>(h_buf, wsa + OW_H, wsa + OB_H, flag, d_out);
}

// Round 8
// 1249.141 us; speedup vs baseline: 12.2986x; 1.0160x over previous
//
#include <hip/hip_runtime.h>

typedef unsigned short ushort;
typedef unsigned int uint;
typedef __attribute__((ext_vector_type(8))) short short8;
typedef __attribute__((ext_vector_type(4))) float floatx4;

#define NTOT   65536
#define CH     64
#define NLAYER 4
#define NEDGE  1048576
#define EPSV   1e-5f

// staged-weight arena element offsets (order = d_in[3..32]); 2-D weights stored TRANSPOSED [n][k]
#define OW_EMB 0
#define OB_EMB 3072
#define OW_PE  3120
#define OB_PE  3376
#define OG_PEN 3392
#define OB_PEN 3408
#define OW_G1  3424
#define OB_G1  19808
#define OW_G2  20064
#define OB_G2  36448
#define OW_Q   36704
#define OB_Q   53088
#define OW_K   53344
#define OB_K   69728
#define OW_V   69984
#define OB_V   86368
#define OW_O   86624
#define OB_O   103008
#define ON1G   103264
#define ON1B   103520
#define ON2G   103776
#define ON2B   104032
#define ON3G   104288
#define ON3B   104544
#define OW_M1  104800
#define OB_M1  137568
#define OW_M2  138080
#define OB_M2  170848
#define OW_H   171104
#define OB_H   179296
#define TOTW   179424

__device__ __forceinline__ float bf2f(ushort u){ return __uint_as_float(((uint)u) << 16); }
__device__ __forceinline__ ushort f2bf(float f){
    uint u = __float_as_uint(f);
    uint r = (u + 0x7fffu + ((u >> 16) & 1u)) >> 16;
    return (ushort)r;
}
__device__ __forceinline__ float2 bfp2(uint w){
    return make_float2(__uint_as_float(w << 16), __uint_as_float(w & 0xffff0000u));
}
__device__ __forceinline__ short8 ldf(const ushort* p){ return *(const short8*)p; }
__device__ __forceinline__ floatx4 mfma16(short8 a, short8 b, floatx4 c){
    return __builtin_amdgcn_mfma_f32_16x16x32_bf16(a, b, c, 0, 0, 0);
}
// compute per-channel BN (a,b) into sf[128]; ident=1 -> identity
__device__ __forceinline__ void bnfin(float* sf, const float* st, const ushort* g,
                                      const ushort* b, int ident, int t){
    if (t < 64){
        float a, bb;
        if (ident){ a = 1.f; bb = 0.f; }
        else {
            float mu  = st[t] * (1.f / NTOT);
            float var = st[64 + t] * (1.f / NTOT) - mu * mu;
            a = rsqrtf(var + EPSV) * bf2f(g[t]);
            bb = bf2f(b[t]) - mu * a;
        }
        sf[t] = a; sf[64 + t] = bb;
    }
}

// ---------------- dtype probe: 1=bf16 inputs, 0=fp32 inputs ----------------
__global__ void detect_k(const uint* __restrict__ x, int* __restrict__ flag){
    int lane = threadIdx.x;
    uint w = x[lane];
    uint e = (w >> 7) & 0xffu;
    int ok = (e >= 100u && e <= 140u) ? 1 : 0;
    unsigned long long m = __ballot(ok);
    if (lane == 0) flag[0] = (__popcll(m) >= 48) ? 1 : 0;
}

// ---------------- convert/copy weights into bf16 arena (2-D weights transposed) ----------------
struct WPtrs { const void* p[30]; };

__global__ void convall_k(WPtrs ptrs, ushort* __restrict__ dst, const int* __restrict__ flag){
    const int offs[31] = {0,3072,3120,3376,3392,3408,3424,19808,20064,36448,36704,
                          53088,53344,69728,69984,86368,86624,103008,103264,103520,
                          103776,104032,104288,104544,104800,137568,138080,170848,
                          171104,179296,179424};
    const int kdt[30] = {64,0,16,0,0,0, 64,0,64,0, 64,0,64,0,64,0,64,0,
                         0,0,0,0,0,0, 64,0,128,0, 64,0};
    const int ndt[30] = {48,0,16,0,0,0, 64,0,64,0, 64,0,64,0,64,0,64,0,
                         0,0,0,0,0,0, 128,0,64,0, 128,0};
    int i = blockIdx.x * blockDim.x + threadIdx.x;
    if (i >= TOTW) return;
    int s = 0;
    while (s < 29 && i >= offs[s + 1]) ++s;
    int j = i - offs[s];
    int srcj = j;
    int K = kdt[s];
    if (K > 0){
        int N = ndt[s], KN = K * N;
        int l = j / KN, r = j - l * KN;
        int n = r / K, k2 = r - n * K;
        srcj = l * KN + k2 * N + n;
    }
    if (*flag) dst[i] = ((const ushort*)ptrs.p[s])[srcj];
    else       dst[i] = f2bf(((const float*)ptrs.p[s])[srcj]);
}

// ---------------- BN stats over pe ----------------
__global__ void pe_stats_k(const void* __restrict__ peraw, const int* __restrict__ flag,
                           float* __restrict__ stats){
    int bf = *flag;
    int t = threadIdx.x;
    int c = t & 15, rb = t >> 4;
    int row0 = blockIdx.x * 256;
    float s = 0.f, ss = 0.f;
    for (int i = 0; i < 16; ++i){
        int r = row0 + rb + 16 * i;
        size_t idx = (size_t)r * 16 + c;
        float v = bf ? bf2f(((const ushort*)peraw)[idx]) : ((const float*)peraw)[idx];
        s += v; ss += v * v;
    }
    __shared__ float red[256];
    red[t] = s; __syncthreads();
    if (t < 16){ float tot = 0.f; for (int j = 0; j < 16; ++j) tot += red[t + 16 * j]; atomicAdd(&stats[t], tot); }
    __syncthreads();
    red[t] = ss; __syncthreads();
    if (t < 16){ float tot = 0.f; for (int j = 0; j < 16; ++j) tot += red[t + 16 * j]; atomicAdd(&stats[64 + t], tot); }
}

__global__ void fin_k(const float* __restrict__ stats, const ushort* __restrict__ g,
                      const ushort* __restrict__ b, float* __restrict__ fin, int nch){
    int c = threadIdx.x;
    if (c >= nch) return;
    float mu  = stats[c] * (1.f / NTOT);
    float var = stats[64 + c] * (1.f / NTOT) - mu * mu;
    float a = rsqrtf(var + EPSV) * bf2f(g[c]);
    fin[c] = a;
    fin[64 + c] = bf2f(b[c]) - mu * a;
}

// ---------------- embedding, MFMA version ----------------
__global__ void embed_k(const void* __restrict__ xraw, const void* __restrict__ peraw,
                        const int* __restrict__ flag, const ushort* __restrict__ wsa,
                        const float* __restrict__ finpe, ushort* __restrict__ hout){
    __shared__ __align__(16) ushort xb[64 * 72];
    __shared__ __align__(16) ushort pen[64 * 24];
    __shared__ __align__(16) ushort Wes[48 * 72];
    __shared__ __align__(16) ushort Wps[16 * 24];
    int bf = *flag;
    int t = threadIdx.x;
    int row0 = blockIdx.x * 64;
    if (bf){
        const uint* xsrc = (const uint*)((const ushort*)xraw + (size_t)row0 * 64);
        for (int i = t; i < 2048; i += 256){
            int r = i >> 5, u = i & 31;
            ((uint*)(xb + r * 72))[u] = xsrc[i];
        }
    } else {
        const float4* xsrc = (const float4*)((const float*)xraw + (size_t)row0 * 64);
        for (int i = t; i < 1024; i += 256){
            int r = i >> 4, u = i & 15;
            float4 f = xsrc[i];
            ((uint*)(xb + r * 72))[2 * u]     = (uint)f2bf(f.x) | ((uint)f2bf(f.y) << 16);
            ((uint*)(xb + r * 72))[2 * u + 1] = (uint)f2bf(f.z) | ((uint)f2bf(f.w) << 16);
        }
    }
    for (int i = t; i < 1024; i += 256){
        int r = i >> 4, k = i & 15;
        size_t idx = (size_t)(row0 + r) * 16 + k;
        float v = bf ? bf2f(((const ushort*)peraw)[idx]) : ((const float*)peraw)[idx];
        pen[r * 24 + k] = f2bf(v * finpe[k] + finpe[64 + k]);
    }
    for (int i = t; i < 1536; i += 256){
        int r = i >> 5, u = i & 31;
        ((uint*)(Wes + r * 72))[u] = ((const uint*)(wsa + OW_EMB))[i];
    }
    {
        int r = t >> 4, k = t & 15;
        Wps[r * 24 + k] = wsa[OW_PE + t];
    }
    __syncthreads();
    int w = t >> 6, l = t & 63, m = l & 15, quad = l >> 4;
    const short8 zero8 = {0, 0, 0, 0, 0, 0, 0, 0};
    const floatx4 zf4 = {0.f, 0.f, 0.f, 0.f};
    const ushort* ap = xb + (16 * w + m) * 72 + quad * 8;
    short8 a0 = ldf(ap), a1 = ldf(ap + 32);
    short8 ape = (quad < 2) ? ldf(pen + (16 * w + m) * 24 + quad * 8) : zero8;
    #pragma unroll
    for (int nt = 0; nt < 4; ++nt){
        floatx4 c = zf4;
        float bias;
        if (nt < 3){
            const ushort* bp = Wes + (nt * 16 + m) * 72 + quad * 8;
            c = mfma16(a0, ldf(bp), c);
            c = mfma16(a1, ldf(bp + 32), c);
            bias = bf2f(wsa[OB_EMB + nt * 16 + m]);
        } else {
            short8 bpe = (quad < 2) ? ldf(Wps + m * 24 + quad * 8) : zero8;
            c = mfma16(ape, bpe, c);
            bias = bf2f(wsa[OB_PE + m]);
        }
        #pragma unroll
        for (int r = 0; r < 4; ++r)
            hout[(size_t)(row0 + 16 * w + quad * 4 + r) * 64 + nt * 16 + m] = f2bf(c[r] + bias);
    }
}

// ---------------- CSR build ----------------
__global__ void hist_k(const int* __restrict__ dst, int* __restrict__ cnt){
    int stride = gridDim.x * blockDim.x;
    for (int e = blockIdx.x * blockDim.x + threadIdx.x; e < NEDGE; e += stride)
        atomicAdd(&cnt[dst[e]], 1);
}

__global__ void scan_k(const int* __restrict__ cnt, int* __restrict__ offs, int* __restrict__ cur){
    int t = threadIdx.x;
    int base0 = t * 64;
    int s = 0;
    for (int i = 0; i < 64; ++i) s += cnt[base0 + i];
    __shared__ int pref[1024];
    pref[t] = s; __syncthreads();
    for (int off = 1; off < 1024; off <<= 1){
        int v = (t >= off) ? pref[t - off] : 0;
        __syncthreads();
        pref[t] += v;
        __syncthreads();
    }
    int run = pref[t] - s;
    for (int i = 0; i < 64; ++i){
        offs[base0 + i] = run;
        cur[base0 + i]  = run;
        run += cnt[base0 + i];
    }
    if (t == 1023) offs[65536] = run;
}

// csr write via atomicExch: atomics allocate in L2, killing the 18x partial-line
// write amplification plain stores showed (WRITE_SIZE 72 MB for a 4 MB payload).
__global__ void scatter_k(const int* __restrict__ src, const int* __restrict__ dst,
                          int* __restrict__ cur, int* __restrict__ csr){
    int stride = gridDim.x * blockDim.x;
    for (int e = blockIdx.x * blockDim.x + threadIdx.x; e < NEDGE; e += stride){
        int p = atomicAdd(&cur[dst[e]], 1);
        atomicExch(&csr[p], src[e]);
    }
}

// ---------------- GIN aggregate with BN-on-read: z = bn(h)[node] + sum bn(h)[src] ----------------
__global__ void agg_k(const ushort* __restrict__ h, const int* __restrict__ offs,
                      const int* __restrict__ csr, ushort* __restrict__ z,
                      const float* __restrict__ st, const ushort* __restrict__ g,
                      const ushort* __restrict__ b, int ident){
    __shared__ float sf[128];
    int t = threadIdx.x;
    bnfin(sf, st, g, b, ident, t);
    __syncthreads();
    int w = t >> 6, l = t & 63;
    int node = blockIdx.x * 8 + w * 2 + (l >> 5);
    int c2 = l & 31;
    const uint* hp = (const uint*)h;
    int beg = offs[node], end = offs[node + 1];
    float2 s = bfp2(hp[(size_t)node * 32 + c2]);
    for (int i = beg; i < end; ++i){
        int sn = csr[i];
        float2 p = bfp2(hp[(size_t)sn * 32 + c2]);
        s.x += p.x; s.y += p.y;
    }
    float n = (float)(1 + end - beg);
    int c0 = c2 * 2;
    float o0 = sf[c0] * s.x + n * sf[64 + c0];
    float o1 = sf[c0 + 1] * s.y + n * sf[64 + c0 + 1];
    ((uint*)z)[(size_t)node * 32 + c2] = (uint)f2bf(o0) | ((uint)f2bf(o1) << 16);
}

// ======== fused GIN-MLP + QKV (shared h-tile, BN-on-stage), 64-row tiles, 4 waves ========
__global__ void ginqkv_k(const ushort* __restrict__ z, const ushort* __restrict__ h,
                         const float* __restrict__ st3, const ushort* __restrict__ g3,
                         const ushort* __restrict__ b3, int ident,
                         const ushort* __restrict__ W1, const ushort* __restrict__ b1,
                         const ushort* __restrict__ W2, const ushort* __restrict__ b2,
                         const ushort* __restrict__ Wq, const ushort* __restrict__ bq,
                         const ushort* __restrict__ Wk, const ushort* __restrict__ bk,
                         const ushort* __restrict__ Wv, const ushort* __restrict__ bv,
                         ushort* __restrict__ zout, ushort* __restrict__ qo,
                         ushort* __restrict__ ko, ushort* __restrict__ vo,
                         float* __restrict__ stats){
    __shared__ __align__(16) ushort As[64 * 72];
    __shared__ __align__(16) ushort Hs[64 * 72];
    __shared__ __align__(16) ushort W1s[64 * 72];
    __shared__ __align__(16) ushort W2s[64 * 72];
    __shared__ __align__(16) ushort Wqs[64 * 72];
    __shared__ __align__(16) ushort Wks[64 * 72];
    __shared__ __align__(16) ushort Wvs[64 * 72];
    __shared__ float sb[128];
    __shared__ float sf[128];
    int t = threadIdx.x;
    int row0 = blockIdx.x * 64;
    bnfin(sf, st3, g3, b3, ident, t);
    if (t < 128) sb[t] = 0.f;
    __syncthreads();
    for (int i = t; i < 2048; i += 256){
        int r = i >> 5, u = i & 31;
        ((uint*)(As  + r * 72))[u] = ((const uint*)(z + (size_t)row0 * 64))[i];
        uint hv = ((const uint*)(h + (size_t)row0 * 64))[i];
        int c0 = u * 2;
        float2 p = bfp2(hv);
        ((uint*)(Hs + r * 72))[u] = (uint)f2bf(p.x * sf[c0] + sf[64 + c0])
                                  | ((uint)f2bf(p.y * sf[c0 + 1] + sf[64 + c0 + 1]) << 16);
        ((uint*)(W1s + r * 72))[u] = ((const uint*)W1)[i];
        ((uint*)(W2s + r * 72))[u] = ((const uint*)W2)[i];
        ((uint*)(Wqs + r * 72))[u] = ((const uint*)Wq)[i];
        ((uint*)(Wks + r * 72))[u] = ((const uint*)Wk)[i];
        ((uint*)(Wvs + r * 72))[u] = ((const uint*)Wv)[i];
    }
    __syncthreads();
    int w = t >> 6, l = t & 63, m = l & 15, q4 = l >> 4;
    const ushort* ap = As + (16 * w + m) * 72 + q4 * 8;
    short8 a0 = ldf(ap), a1 = ldf(ap + 32);
    const ushort* hpp = Hs + (16 * w + m) * 72 + q4 * 8;
    short8 h0 = ldf(hpp), h1 = ldf(hpp + 32);
    floatx4 acc[4];
    #pragma unroll
    for (int nt = 0; nt < 4; ++nt){
        const ushort* bp = W1s + (nt * 16 + m) * 72 + q4 * 8;
        floatx4 c = {0.f, 0.f, 0.f, 0.f};
        c = mfma16(a0, ldf(bp), c);
        c = mfma16(a1, ldf(bp + 32), c);
        acc[nt] = c;
    }
    #pragma unroll
    for (int nt = 0; nt < 4; ++nt){
        float bv = bf2f(b1[nt * 16 + m]);
        #pragma unroll
        for (int r = 0; r < 4; ++r)
            As[(16 * w + q4 * 4 + r) * 72 + nt * 16 + m] = f2bf(fmaxf(acc[nt][r] + bv, 0.f));
    }
    const ushort* ap2 = As + (16 * w + m) * 72 + q4 * 8;
    short8 t0 = ldf(ap2), t1 = ldf(ap2 + 32);
    #pragma unroll
    for (int nt = 0; nt < 4; ++nt){
        const ushort* bp = W2s + (nt * 16 + m) * 72 + q4 * 8;
        floatx4 c = {0.f, 0.f, 0.f, 0.f};
        c = mfma16(t0, ldf(bp), c);
        c = mfma16(t1, ldf(bp + 32), c);
        float bv = bf2f(b2[nt * 16 + m]);
        float vs = 0.f, vss = 0.f;
        #pragma unroll
        for (int r = 0; r < 4; ++r){
            int lr = 16 * w + q4 * 4 + r;
            float val = c[r] + bv + bf2f(Hs[lr * 72 + nt * 16 + m]);
            zout[(size_t)(row0 + lr) * 64 + nt * 16 + m] = f2bf(val);
            vs += val; vss += val * val;
        }
        vs  += __shfl_xor(vs, 16, 64);  vs  += __shfl_xor(vs, 32, 64);
        vss += __shfl_xor(vss, 16, 64); vss += __shfl_xor(vss, 32, 64);
        if (q4 == 0){
            atomicAdd(&sb[nt * 16 + m], vs);
            atomicAdd(&sb[64 + nt * 16 + m], vss);
        }
    }
    ushort* outs[3] = {qo, ko, vo};
    const ushort* bias[3] = {bq, bk, bv};
    const ushort* wmats[3] = {Wqs, Wks, Wvs};
    #pragma unroll
    for (int o = 0; o < 3; ++o){
        #pragma unroll
        for (int nt = 0; nt < 4; ++nt){
            const ushort* bp = wmats[o] + (nt * 16 + m) * 72 + q4 * 8;
            floatx4 c = {0.f, 0.f, 0.f, 0.f};
            c = mfma16(h0, ldf(bp), c);
            c = mfma16(h1, ldf(bp + 32), c);
            float bv2 = bf2f(bias[o][nt * 16 + m]);
            #pragma unroll
            for (int r = 0; r < 4; ++r)
                outs[o][(size_t)(row0 + 16 * w + q4 * 4 + r) * 64 + nt * 16 + m] = f2bf(c[r] + bv2);
        }
    }
    __syncthreads();
    if (t < 64){
        atomicAdd(&stats[t], sb[t]);
        atomicAdd(&stats[64 + t], sb[64 + t]);
    }
}

// ---------------- MFMA flash attention ----------------
__global__ void attn_k(ushort* __restrict__ q, const ushort* __restrict__ k,
                       const ushort* __restrict__ v){
    __shared__ __align__(16) ushort Ks[512 * 24];
    __shared__ __align__(16) ushort Vt[16 * 536];
    int t = threadIdx.x;
    int g = blockIdx.x >> 2, head = blockIdx.x & 3;
    int base = g * 512;
    for (int i = t; i < 4096; i += 256){
        int n = i >> 3, u = i & 7;
        uint kw = ((const uint*)(k + (size_t)(base + n) * 64 + head * 16))[u];
        uint vw = ((const uint*)(v + (size_t)(base + n) * 64 + head * 16))[u];
        float2 kf = bfp2(kw);
        Ks[n * 24 + 2 * u]     = f2bf(kf.x * 0.25f);
        Ks[n * 24 + 2 * u + 1] = f2bf(kf.y * 0.25f);
        Vt[(2 * u) * 536 + n]     = (ushort)(vw & 0xffffu);
        Vt[(2 * u + 1) * 536 + n] = (ushort)(vw >> 16);
    }
    __syncthreads();
    int w = t >> 6, l = t & 63, m16 = l & 15, quad = l >> 4;
    const short8 zero8 = {0, 0, 0, 0, 0, 0, 0, 0};
    const floatx4 zf4 = {0.f, 0.f, 0.f, 0.f};
    int key1 = ((m16 >> 2) << 3) + (m16 & 3);

    for (int qi = 0; qi < 8; ++qi){
        int qt = w * 8 + qi;
        int qrow = base + qt * 16 + m16;
        short8 qf = zero8;
        if (quad < 2) qf = ldf(q + (size_t)qrow * 64 + head * 16 + quad * 8);
        floatx4 O = zf4;
        float mm = -1e30f, ll = 0.f;
        for (int kg = 0; kg < 16; ++kg){
            int kb = kg * 32;
            short8 af1 = zero8, af2 = zero8;
            if (quad < 2){
                const ushort* kp = Ks + (kb + key1) * 24 + quad * 8;
                af1 = ldf(kp);
                af2 = ldf(kp + 96);
            }
            floatx4 s1 = mfma16(af1, qf, zf4);
            floatx4 s2 = mfma16(af2, qf, zf4);
            float tm = fmaxf(fmaxf(fmaxf(s1[0], s1[1]), fmaxf(s1[2], s1[3])),
                             fmaxf(fmaxf(s2[0], s2[1]), fmaxf(s2[2], s2[3])));
            tm = fmaxf(tm, __shfl_xor(tm, 16, 64));
            tm = fmaxf(tm, __shfl_xor(tm, 32, 64));
            float mn = fmaxf(mm, tm);
            float c = __expf(mm - mn);
            float p0 = __expf(s1[0] - mn), p1 = __expf(s1[1] - mn);
            float p2 = __expf(s1[2] - mn), p3 = __expf(s1[3] - mn);
            float p4 = __expf(s2[0] - mn), p5 = __expf(s2[1] - mn);
            float p6 = __expf(s2[2] - mn), p7 = __expf(s2[3] - mn);
            float ts = ((p0 + p1) + (p2 + p3)) + ((p4 + p5) + (p6 + p7));
            ts += __shfl_xor(ts, 16, 64);
            ts += __shfl_xor(ts, 32, 64);
            ll = ll * c + ts;
            mm = mn;
            short8 pf;
            pf[0] = (short)f2bf(p0); pf[1] = (short)f2bf(p1);
            pf[2] = (short)f2bf(p2); pf[3] = (short)f2bf(p3);
            pf[4] = (short)f2bf(p4); pf[5] = (short)f2bf(p5);
            pf[6] = (short)f2bf(p6); pf[7] = (short)f2bf(p7);
            short8 vf = ldf(Vt + m16 * 536 + kb + quad * 8);
            O[0] *= c; O[1] *= c; O[2] *= c; O[3] *= c;
            O = mfma16(vf, pf, O);
        }
        float inv = 1.f / ll;
        uint lo = (uint)f2bf(O[0] * inv) | ((uint)f2bf(O[1] * inv) << 16);
        uint hi = (uint)f2bf(O[2] * inv) | ((uint)f2bf(O[3] * inv) << 16);
        uint2 st = {lo, hi};
        *(uint2*)(q + (size_t)qrow * 64 + head * 16 + quad * 4) = st;
    }
}

// ---------------- O-projection + bn(h) residual + BN2 stats (in-place on o) ----------------
__global__ void oproj_k(ushort* __restrict__ o, const ushort* __restrict__ h,
                        const float* __restrict__ st3, const ushort* __restrict__ g3,
                        const ushort* __restrict__ b3, int ident,
                        const ushort* __restrict__ Wo, const ushort* __restrict__ bo,
                        float* __restrict__ stats){
    __shared__ __align__(16) ushort As[64 * 72];
    __shared__ __align__(16) ushort Ws[64 * 72];
    __shared__ float sb[128];
    __shared__ float sf[128];
    int t = threadIdx.x;
    int row0 = blockIdx.x * 64;
    bnfin(sf, st3, g3, b3, ident, t);
    if (t < 128) sb[t] = 0.f;
    __syncthreads();
    for (int i = t; i < 2048; i += 256){
        int r = i >> 5, u = i & 31;
        ((uint*)(As + r * 72))[u] = ((const uint*)(o + (size_t)row0 * 64))[i];
        ((uint*)(Ws + r * 72))[u] = ((const uint*)Wo)[i];
    }
    __syncthreads();
    int w = t >> 6, l = t & 63, m = l & 15, q4 = l >> 4;
    const ushort* ap = As + (16 * w + m) * 72 + q4 * 8;
    short8 a0 = ldf(ap), a1 = ldf(ap + 32);
    #pragma unroll
    for (int nt = 0; nt < 4; ++nt){
        const ushort* bp = Ws + (nt * 16 + m) * 72 + q4 * 8;
        floatx4 c = {0.f, 0.f, 0.f, 0.f};
        c = mfma16(a0, ldf(bp), c);
        c = mfma16(a1, ldf(bp + 32), c);
        int ch = nt * 16 + m;
        float bv = bf2f(bo[ch]);
        float ba = sf[ch], bb = sf[64 + ch];
        float vs = 0.f, vss = 0.f;
        #pragma unroll
        for (int r = 0; r < 4; ++r){
            size_t gi = (size_t)(row0 + 16 * w + q4 * 4 + r) * 64 + ch;
            float val = c[r] + bv + ba * bf2f(h[gi]) + bb;
            o[gi] = f2bf(val);
            vs += val; vss += val * val;
        }
        vs  += __shfl_xor(vs, 16, 64);  vs  += __shfl_xor(vs, 32, 64);
        vss += __shfl_xor(vss, 16, 64); vss += __shfl_xor(vss, 32, 64);
        if (q4 == 0){
            atomicAdd(&sb[ch], vs);
            atomicAdd(&sb[64 + ch], vss);
        }
    }
    __syncthreads();
    if (t < 64){
        atomicAdd(&stats[t], sb[t]);
        atomicAdd(&stats[64 + t], sb[64 + t]);
    }
}

// ---------------- comb: outb = bn1(hl)+bn2(ha); hout = outb + MLP(outb); BN3 stats ----------------
__global__ void comb_k(const ushort* __restrict__ hlpre, const ushort* __restrict__ hapre,
                       const float* __restrict__ st1, const ushort* __restrict__ n1g,
                       const ushort* __restrict__ n1b,
                       const float* __restrict__ st2, const ushort* __restrict__ n2g,
                       const ushort* __restrict__ n2b,
                       const ushort* __restrict__ W1, const ushort* __restrict__ b1,
                       const ushort* __restrict__ W2, const ushort* __restrict__ b2,
                       ushort* __restrict__ hout, float* __restrict__ stats){
    __shared__ __align__(16) ushort Ob[64 * 72];
    __shared__ float Of[64 * 64];
    __shared__ __align__(16) ushort W1s[128 * 72];
    __shared__ __align__(16) ushort Hs[64 * 136];
    __shared__ __align__(16) ushort W2s[64 * 136];
    __shared__ float sb[128];
    __shared__ float sf1[128], sf2[128];
    int t = threadIdx.x;
    int row0 = blockIdx.x * 64;
    if (t < 128){
        const float* st = (t < 64) ? st1 : st2;
        const ushort* g = (t < 64) ? n1g : n2g;
        const ushort* b = (t < 64) ? n1b : n2b;
        float* f = (t < 64) ? sf1 : sf2;
        int c = t & 63;
        float mu  = st[c] * (1.f / NTOT);
        float var = st[64 + c] * (1.f / NTOT) - mu * mu;
        float a = rsqrtf(var + EPSV) * bf2f(g[c]);
        f[c] = a;
        f[64 + c] = bf2f(b[c]) - mu * a;
        sb[t] = 0.f;
    }
    __syncthreads();
    for (int i = t; i < 2048; i += 256){
        int r = i >> 5, u = i & 31;
        size_t gi = (size_t)(row0 + r) * 32 + u;
        uint wl = ((const uint*)hlpre)[gi], wa = ((const uint*)hapre)[gi];
        int c0 = u * 2;
        float2 pl = bfp2(wl), pa = bfp2(wa);
        float v0 = pl.x * sf1[c0] + sf1[64 + c0] + pa.x * sf2[c0] + sf2[64 + c0];
        float v1 = pl.y * sf1[c0 + 1] + sf1[64 + c0 + 1] + pa.y * sf2[c0 + 1] + sf2[64 + c0 + 1];
        ((uint*)(Ob + r * 72))[u] = (uint)f2bf(v0) | ((uint)f2bf(v1) << 16);
        Of[r * 64 + c0] = v0; Of[r * 64 + c0 + 1] = v1;
    }
    for (int i = t; i < 4096; i += 256){
        int r = i >> 5, u = i & 31;
        ((uint*)(W1s + r * 72))[u] = ((const uint*)W1)[i];
        int r2 = i >> 6, u2 = i & 63;
        ((uint*)(W2s + r2 * 136))[u2] = ((const uint*)W2)[i];
    }
    __syncthreads();
    int w = t >> 6, l = t & 63, m = l & 15, q4 = l >> 4;
    const ushort* ap = Ob + (16 * w + m) * 72 + q4 * 8;
    short8 a0 = ldf(ap), a1 = ldf(ap + 32);
    #pragma unroll
    for (int nt = 0; nt < 8; ++nt){
        const ushort* bp = W1s + (nt * 16 + m) * 72 + q4 * 8;
        floatx4 c = {0.f, 0.f, 0.f, 0.f};
        c = mfma16(a0, ldf(bp), c);
        c = mfma16(a1, ldf(bp + 32), c);
        float bv = bf2f(b1[nt * 16 + m]);
        #pragma unroll
        for (int r = 0; r < 4; ++r)
            Hs[(16 * w + q4 * 4 + r) * 136 + nt * 16 + m] = f2bf(fmaxf(c[r] + bv, 0.f));
    }
    const ushort* ap2 = Hs + (16 * w + m) * 136 + q4 * 8;
    short8 h0 = ldf(ap2), h1 = ldf(ap2 + 32), h2 = ldf(ap2 + 64), h3 = ldf(ap2 + 96);
    #pragma unroll
    for (int nt = 0; nt < 4; ++nt){
        const ushort* bp = W2s + (nt * 16 + m) * 136 + q4 * 8;
        floatx4 c = {0.f, 0.f, 0.f, 0.f};
        c = mfma16(h0, ldf(bp), c);
        c = mfma16(h1, ldf(bp + 32), c);
        c = mfma16(h2, ldf(bp + 64), c);
        c = mfma16(h3, ldf(bp + 96), c);
        float bv = bf2f(b2[nt * 16 + m]);
        float vs = 0.f, vss = 0.f;
        #pragma unroll
        for (int r = 0; r < 4; ++r){
            int lr = 16 * w + q4 * 4 + r;
            float val = c[r] + bv + Of[lr * 64 + nt * 16 + m];
            hout[(size_t)(row0 + lr) * 64 + nt * 16 + m] = f2bf(val);
            vs += val; vss += val * val;
        }
        vs  += __shfl_xor(vs, 16, 64);  vs  += __shfl_xor(vs, 32, 64);
        vss += __shfl_xor(vss, 16, 64); vss += __shfl_xor(vss, 32, 64);
        if (q4 == 0){
            atomicAdd(&sb[nt * 16 + m], vs);
            atomicAdd(&sb[64 + nt * 16 + m], vss);
        }
    }
    __syncthreads();
    if (t < 64){
        atomicAdd(&stats[t], sb[t]);
        atomicAdd(&stats[64 + t], sb[64 + t]);
    }
}

// ---------------- mean pool (pre-BN h + affine post) + head GEMM ----------------
__global__ void pool_head_k(const ushort* __restrict__ h, const float* __restrict__ st3,
                            const ushort* __restrict__ g3, const ushort* __restrict__ b3,
                            const ushort* __restrict__ Wh, const ushort* __restrict__ bh,
                            const int* __restrict__ flag, void* __restrict__ out){
    __shared__ float red[256];
    __shared__ float pooled[64];
    __shared__ float sf[128];
    int t = threadIdx.x, g = blockIdx.x;
    bnfin(sf, st3, g3, b3, 0, t);
    int c = t & 63, rb = t >> 6;
    float s = 0.f;
    for (int ii = 0; ii < 128; ++ii){
        int r = rb + 4 * ii;
        s += bf2f(h[(size_t)(g * 512 + r) * 64 + c]);
    }
    red[t] = s; __syncthreads();
    if (t < 64)
        pooled[t] = sf[t] * ((red[t] + red[64 + t] + red[128 + t] + red[192 + t]) * (1.f / 512.f))
                  + sf[64 + t];
    __syncthreads();
    if (t < 128){
        float a = bf2f(bh[t]);
        #pragma unroll
        for (int k = 0; k < 64; ++k) a += pooled[k] * bf2f(Wh[t * 64 + k]);
        if (*flag) ((ushort*)out)[(size_t)g * 128 + t] = f2bf(a);
        else       ((float*)out)[(size_t)g * 128 + t] = a;
    }
}

extern "C" void kernel_launch(void* const* d_in, const int* in_sizes, int n_in,
                              void* d_out, int out_size, void* d_ws, size_t ws_size,
                              hipStream_t stream){
    const void* x  = d_in[0];
    const void* pe = d_in[1];
    const int* eidx = (const int*)d_in[2];

    char* ws = (char*)d_ws;
    const size_t MB = 1024 * 1024;
    const size_t KB = 1024;
    ushort* h_buf = (ushort*)(ws);          // pre-BN h (embed out / comb out)
    ushort* z_buf = (ushort*)(ws + 8 * MB); // agg out -> gin out (in place)
    ushort* q_buf = (ushort*)(ws + 16 * MB);
    ushort* k_buf = (ushort*)(ws + 24 * MB);
    ushort* v_buf = (ushort*)(ws + 32 * MB);
    int* csr   = (int*)(ws + 40 * MB);
    int* offs  = (int*)(ws + 44 * MB);
    int* cnt   = (int*)(ws + 44 * MB + 384 * KB);
    int* cur   = (int*)(ws + 44 * MB + 640 * KB);
    float* stats = (float*)(ws + 44 * MB + 896 * KB);
    float* fin   = (float*)(ws + 44 * MB + 904 * KB);
    int*   flag  = (int*)(ws + 44 * MB + 912 * KB);
    ushort* wsa  = (ushort*)(ws + 45 * MB);

    hipMemsetAsync(stats, 0, 13 * 128 * sizeof(float), stream);
    hipMemsetAsync(cnt, 0, 65536 * sizeof(int), stream);

    detect_k<<<1, 64, 0, stream>>>((const uint*)x, flag);

    WPtrs wp;
    for (int i = 0; i < 30; ++i) wp.p[i] = d_in[3 + i];
    convall_k<<<(TOTW + 255) / 256, 256, 0, stream>>>(wp, wsa, flag);

    pe_stats_k<<<256, 256, 0, stream>>>(pe, flag, stats);
    fin_k<<<1, 64, 0, stream>>>(stats, wsa + OG_PEN, wsa + OB_PEN, fin, 16);
    embed_k<<<1024, 256, 0, stream>>>(x, pe, flag, wsa, fin, h_buf);
    hist_k<<<1024, 256, 0, stream>>>(eidx + NEDGE, cnt);
    scan_k<<<1, 1024, 0, stream>>>(cnt, offs, cur);
    scatter_k<<<1024, 256, 0, stream>>>(eidx, eidx + NEDGE, cur, csr);

    for (int l = 0; l < NLAYER; ++l){
        float* st1 = stats + (1 + 3 * l) * 128;
        float* st2 = stats + (2 + 3 * l) * 128;
        float* st3 = stats + (3 + 3 * l) * 128;
        // BN pending on h_buf (from previous layer's comb); identity for layer 0
        int ident = (l == 0) ? 1 : 0;
        const float* stp = (l == 0) ? stats : stats + (3 * l) * 128;  // prev layer's st3
        const ushort* gp = wsa + ON3G + (l ? (l - 1) : 0) * 64;
        const ushort* bp = wsa + ON3B + (l ? (l - 1) : 0) * 64;

        agg_k<<<8192, 256, 0, stream>>>(h_buf, offs, csr, z_buf, stp, gp, bp, ident);
        ginqkv_k<<<1024, 256, 0, stream>>>(z_buf, h_buf, stp, gp, bp, ident,
                                           wsa + OW_G1 + l * 4096, wsa + OB_G1 + l * 64,
                                           wsa + OW_G2 + l * 4096, wsa + OB_G2 + l * 64,
                                           wsa + OW_Q + l * 4096, wsa + OB_Q + l * 64,
                                           wsa + OW_K + l * 4096, wsa + OB_K + l * 64,
                                           wsa + OW_V + l * 4096, wsa + OB_V + l * 64,
                                           z_buf, q_buf, k_buf, v_buf, st1);
        attn_k<<<512, 256, 0, stream>>>(q_buf, k_buf, v_buf);
        oproj_k<<<1024, 256, 0, stream>>>(q_buf, h_buf, stp, gp, bp, ident,
                                          wsa + OW_O + l * 4096, wsa + OB_O + l * 64, st2);
        comb_k<<<1024, 256, 0, stream>>>(z_buf, q_buf,
                                         st1, wsa + ON1G + l * 64, wsa + ON1B + l * 64,
                                         st2, wsa + ON2G + l * 64, wsa + ON2B + l * 64,
                                         wsa + OW_M1 + l * 8192, wsa + OB_M1 + l * 128,
                                         wsa + OW_M2 + l * 8192, wsa + OB_M2 + l * 64,
                                         h_buf, st3);
    }
    pool_head_k<<<128, 256, 0, stream>>>(h_buf, stats + 12 * 128,
                                         wsa + ON3G + 3 * 64, wsa + ON3B + 3 * 64,
                                         wsa + OW_H, wsa + OB_H, flag, d_out);
}